// Round 1
// baseline (906.050 us; speedup 1.0000x reference)
//
#include <hip/hip_runtime.h>
#include <math.h>

// Problem constants (fixed by reference)
#define KD 128      // K dim of every GEMM (IN = HC = 128)
#define HC 128      // H*C for layers 0/1
#define NF2 188     // H*OUT for layer 2
#define OUTC 47

// ---------------------------------------------------------------------------
// CSR build
// ---------------------------------------------------------------------------
__global__ void init_deg_kernel(int* deg, int n) {
    int i = blockIdx.x * blockDim.x + threadIdx.x;
    if (i < n) deg[i] = 1;  // self-loop contributes 1
}

__global__ void count_kernel(const int* __restrict__ dst, int* deg, int e) {
    int i = blockIdx.x * blockDim.x + threadIdx.x;
    if (i < e) atomicAdd(&deg[dst[i]], 1);
}

// single block of 1024 threads: exclusive scan of deg[n] -> row_ptr, fill
__global__ void scan_kernel(const int* __restrict__ deg, int* row_ptr, int* fill, int n) {
    __shared__ int sums[1024];
    int t = threadIdx.x;
    int chunk = (n + 1023) / 1024;
    int begin = t * chunk;
    int stop = begin + chunk; if (stop > n) stop = n;
    int s = 0;
    for (int i = begin; i < stop; ++i) s += deg[i];
    sums[t] = s;
    __syncthreads();
    for (int off = 1; off < 1024; off <<= 1) {
        int v = (t >= off) ? sums[t - off] : 0;
        __syncthreads();
        sums[t] += v;
        __syncthreads();
    }
    int running = (t == 0) ? 0 : sums[t - 1];
    for (int i = begin; i < stop; ++i) {
        row_ptr[i] = running;
        fill[i] = running;
        running += deg[i];
    }
    if (t == 1023) row_ptr[n] = sums[1023];
}

__global__ void fill_kernel(const int* __restrict__ ei, int* fill, int* col, int e, int n) {
    int i = blockIdx.x * blockDim.x + threadIdx.x;
    if (i < e) {
        int d = ei[e + i];                 // dst
        int pos = atomicAdd(&fill[d], 1);
        col[pos] = ei[i];                  // src
    } else if (i < e + n) {
        int node = i - e;                  // self loop
        int pos = atomicAdd(&fill[node], 1);
        col[pos] = node;
    }
}

// ---------------------------------------------------------------------------
// fp32 GEMM: C[M,N] = A[M,128] @ B[128,N] (+ bias). 64x64 tile, 4x4/thread.
// ---------------------------------------------------------------------------
__global__ __launch_bounds__(256) void sgemm_kernel(
    const float* __restrict__ A, const float* __restrict__ B,
    const float* __restrict__ bias, float* __restrict__ C, int M, int N) {
    __shared__ float As[32][68];   // [k][m], padded: 68*4=272B stride, 16B-aligned float4 rows
    __shared__ float Bs[32][68];   // [k][n]
    int tid = threadIdx.x;
    int m0 = blockIdx.x * 64;
    int n0 = blockIdx.y * 64;
    int tx = tid & 15, ty = tid >> 4;
    float acc[4][4] = {};

    for (int ko = 0; ko < KD; ko += 32) {
        // A tile: 64 rows x 32 k, float4 loads (A stride 128 -> aligned)
#pragma unroll
        for (int rep = 0; rep < 2; ++rep) {
            int idx = tid + rep * 256;          // 0..511
            int row = idx >> 3, q = idx & 7;    // row 0..63, q 0..7
            float4 v = make_float4(0.f, 0.f, 0.f, 0.f);
            if (m0 + row < M) v = *(const float4*)(A + (long)(m0 + row) * KD + ko + q * 4);
            As[q * 4 + 0][row] = v.x;
            As[q * 4 + 1][row] = v.y;
            As[q * 4 + 2][row] = v.z;
            As[q * 4 + 3][row] = v.w;
        }
        // B tile: 32 k x 64 n, scalar loads (N=47 rows are unaligned)
#pragma unroll
        for (int rep = 0; rep < 8; ++rep) {
            int idx = tid + rep * 256;          // 0..2047
            int k = idx >> 6, nn = idx & 63;
            float v = 0.f;
            if (n0 + nn < N) v = B[(long)(ko + k) * N + n0 + nn];
            Bs[k][nn] = v;
        }
        __syncthreads();
#pragma unroll
        for (int k = 0; k < 32; ++k) {
            float a0 = As[k][ty * 4 + 0], a1 = As[k][ty * 4 + 1];
            float a2 = As[k][ty * 4 + 2], a3 = As[k][ty * 4 + 3];
            float b0 = Bs[k][tx * 4 + 0], b1 = Bs[k][tx * 4 + 1];
            float b2 = Bs[k][tx * 4 + 2], b3 = Bs[k][tx * 4 + 3];
            acc[0][0] += a0 * b0; acc[0][1] += a0 * b1; acc[0][2] += a0 * b2; acc[0][3] += a0 * b3;
            acc[1][0] += a1 * b0; acc[1][1] += a1 * b1; acc[1][2] += a1 * b2; acc[1][3] += a1 * b3;
            acc[2][0] += a2 * b0; acc[2][1] += a2 * b1; acc[2][2] += a2 * b2; acc[2][3] += a2 * b3;
            acc[3][0] += a3 * b0; acc[3][1] += a3 * b1; acc[3][2] += a3 * b2; acc[3][3] += a3 * b3;
        }
        __syncthreads();
    }
#pragma unroll
    for (int i = 0; i < 4; ++i) {
        int row = m0 + ty * 4 + i;
        if (row < M) {
#pragma unroll
            for (int j = 0; j < 4; ++j) {
                int cn = n0 + tx * 4 + j;
                if (cn < N) {
                    float v = acc[i][j];
                    if (bias) v += bias[cn];
                    C[(long)row * N + cn] = v;
                }
            }
        }
    }
}

// ---------------------------------------------------------------------------
// a_src[n,h] = sum_c xh[n,h*C+c]*att_s[h*C+c]; same for a_dst. One wave/node.
// ---------------------------------------------------------------------------
template <int NF, int C>
__global__ __launch_bounds__(256) void att_kernel(
    const float* __restrict__ xh, const float* __restrict__ att_s,
    const float* __restrict__ att_d, float* __restrict__ a_src,
    float* __restrict__ a_dst, int n) {
    int node = (blockIdx.x * blockDim.x + threadIdx.x) >> 6;
    int lane = threadIdx.x & 63;
    if (node >= n) return;
    constexpr int NR = (NF + 63) / 64;
    float hs[4] = {0.f, 0.f, 0.f, 0.f};
    float hd[4] = {0.f, 0.f, 0.f, 0.f};
#pragma unroll
    for (int r = 0; r < NR; ++r) {
        int f = lane + 64 * r;
        if (f < NF) {
            float x = xh[(long)node * NF + f];
            float ps = x * att_s[f];
            float pd = x * att_d[f];
            int h = f / C;
            if (h == 0)      { hs[0] += ps; hd[0] += pd; }
            else if (h == 1) { hs[1] += ps; hd[1] += pd; }
            else if (h == 2) { hs[2] += ps; hd[2] += pd; }
            else             { hs[3] += ps; hd[3] += pd; }
        }
    }
#pragma unroll
    for (int off = 32; off >= 1; off >>= 1) {
#pragma unroll
        for (int h = 0; h < 4; ++h) {
            hs[h] += __shfl_xor(hs[h], off, 64);
            hd[h] += __shfl_xor(hd[h], off, 64);
        }
    }
    if (lane == 0) {
        *(float4*)(a_src + 4 * (long)node) = make_float4(hs[0], hs[1], hs[2], hs[3]);
        *(float4*)(a_dst + 4 * (long)node) = make_float4(hd[0], hd[1], hd[2], hd[3]);
    }
}

// ---------------------------------------------------------------------------
// Aggregation: one wave per destination node. Online softmax stats, then
// weighted gather of xh[src]. MODE 0: concat + bias + skip + ELU (NF=128).
// MODE 1: head-mean + bias + skip (NF=188, C=47).
// ---------------------------------------------------------------------------
template <int NF, int C, int MODE>
__global__ __launch_bounds__(256) void agg_kernel(
    const float* __restrict__ xh, const float* __restrict__ a_src,
    const float* __restrict__ a_dst, const float* __restrict__ skip,
    const float* __restrict__ bias, const int* __restrict__ row_ptr,
    const int* __restrict__ col, float* __restrict__ out, int n) {
    int node = (blockIdx.x * blockDim.x + threadIdx.x) >> 6;
    int lane = threadIdx.x & 63;
    if (node >= n) return;
    int start = row_ptr[node];
    int end = row_ptr[node + 1];
    float4 ad4 = *(const float4*)(a_dst + 4 * (long)node);
    float adh[4] = {ad4.x, ad4.y, ad4.z, ad4.w};

    // pass A: online max/sum per head, lanes strided over edges
    float m[4] = {-1e30f, -1e30f, -1e30f, -1e30f};
    float s[4] = {0.f, 0.f, 0.f, 0.f};
    for (int e = start + lane; e < end; e += 64) {
        int j = col[e];
        float4 as4 = *(const float4*)(a_src + 4 * (long)j);
        float ev[4] = {as4.x + adh[0], as4.y + adh[1], as4.z + adh[2], as4.w + adh[3]};
#pragma unroll
        for (int h = 0; h < 4; ++h) {
            float v = ev[h] > 0.f ? ev[h] : 0.2f * ev[h];
            float M = fmaxf(m[h], v);
            s[h] = s[h] * __expf(m[h] - M) + __expf(v - M);
            m[h] = M;
        }
    }
#pragma unroll
    for (int off = 32; off >= 1; off >>= 1) {
#pragma unroll
        for (int h = 0; h < 4; ++h) {
            float m2 = __shfl_xor(m[h], off, 64);
            float s2 = __shfl_xor(s[h], off, 64);
            float M = fmaxf(m[h], m2);
            s[h] = s[h] * __expf(m[h] - M) + s2 * __expf(m2 - M);
            m[h] = M;
        }
    }
    float inv[4];
#pragma unroll
    for (int h = 0; h < 4; ++h) inv[h] = 1.f / (s[h] + 1e-16f);

    // pass B: whole wave cooperates per edge; lane owns feature f = lane+64r
    constexpr int NR = (NF + 63) / 64;
    float acc[NR];
    float mh[NR], invh[NR], adr[NR];
    int fr[NR], hr[NR];
    bool valid[NR];
#pragma unroll
    for (int r = 0; r < NR; ++r) {
        acc[r] = 0.f;
        int f = lane + 64 * r;
        fr[r] = f;
        valid[r] = (f < NF);
        int h = valid[r] ? (f / C) : 0;
        hr[r] = h;
        mh[r]   = (h == 0) ? m[0]   : (h == 1) ? m[1]   : (h == 2) ? m[2]   : m[3];
        invh[r] = (h == 0) ? inv[0] : (h == 1) ? inv[1] : (h == 2) ? inv[2] : inv[3];
        adr[r]  = (h == 0) ? adh[0] : (h == 1) ? adh[1] : (h == 2) ? adh[2] : adh[3];
    }
    for (int base = start; base < end; base += 64) {
        int e = base + lane;
        int jv = (e < end) ? col[e] : 0;
        int cnt = end - base; if (cnt > 64) cnt = 64;
        for (int t = 0; t < cnt; ++t) {
            int j = __shfl(jv, t, 64);
            float4 as4 = *(const float4*)(a_src + 4 * (long)j);
            const float* xr = xh + (long)j * NF;
#pragma unroll
            for (int r = 0; r < NR; ++r) {
                if (valid[r]) {
                    float asv = (hr[r] == 0) ? as4.x : (hr[r] == 1) ? as4.y
                              : (hr[r] == 2) ? as4.z : as4.w;
                    float ev = asv + adr[r];
                    ev = ev > 0.f ? ev : 0.2f * ev;
                    float alpha = __expf(ev - mh[r]) * invh[r];
                    acc[r] += alpha * xr[fr[r]];
                }
            }
        }
    }

    if constexpr (MODE == 0) {
#pragma unroll
        for (int r = 0; r < NR; ++r) {
            int f = fr[r];
            float v = acc[r] + bias[f] + skip[(long)node * NF + f];
            v = v > 0.f ? v : (__expf(v) - 1.f);   // ELU
            out[(long)node * NF + f] = v;
        }
    } else {
        // head mean: out[c] = (A[c] + A[c+47] + A[c+94] + A[c+141]) / 4
        int c = lane;
        float v1 = acc[0];
        float s0 = __shfl(acc[0], (c + 47) & 63, 64);
        float s1 = __shfl(acc[1], (c - 17) & 63, 64);
        float v2 = (c < 17) ? s0 : s1;
        float s2 = __shfl(acc[1], (c + 30) & 63, 64);
        float s3 = __shfl(acc[2], (c - 34) & 63, 64);
        float v3 = (c < 34) ? s2 : s3;
        float v4 = __shfl(acc[2], (c + 13) & 63, 64);
        if (c < OUTC) {
            float v = (v1 + v2 + v3 + v4) * 0.25f + bias[c] + skip[(long)node * OUTC + c];
            out[(long)node * OUTC + c] = v;
        }
    }
}

// ---------------------------------------------------------------------------
extern "C" void kernel_launch(void* const* d_in, const int* in_sizes, int n_in,
                              void* d_out, int out_size, void* d_ws, size_t ws_size,
                              hipStream_t stream) {
    const float* x        = (const float*)d_in[0];
    const int*   ei       = (const int*)d_in[1];
    const float* lin_w0   = (const float*)d_in[2];
    const float* att_src0 = (const float*)d_in[3];
    const float* att_dst0 = (const float*)d_in[4];
    const float* bias0    = (const float*)d_in[5];
    const float* skip_w0  = (const float*)d_in[6];
    const float* skip_b0  = (const float*)d_in[7];
    const float* lin_w1   = (const float*)d_in[8];
    const float* att_src1 = (const float*)d_in[9];
    const float* att_dst1 = (const float*)d_in[10];
    const float* bias1    = (const float*)d_in[11];
    const float* skip_w1  = (const float*)d_in[12];
    const float* skip_b1  = (const float*)d_in[13];
    const float* lin_w2   = (const float*)d_in[14];
    const float* att_src2 = (const float*)d_in[15];
    const float* att_dst2 = (const float*)d_in[16];
    const float* bias2    = (const float*)d_in[17];
    const float* skip_w2  = (const float*)d_in[18];
    const float* skip_b2  = (const float*)d_in[19];
    float* out = (float*)d_out;

    const int N = in_sizes[0] / KD;       // 50000
    const int E = in_sizes[1] / 2;        // 800000
    const int ET_ = E + N;                // with self loops

    char* ws = (char*)d_ws;
    size_t off = 0;
    auto alloc = [&](size_t bytes) -> void* {
        void* p = ws + off;
        off = (off + bytes + 255) & ~(size_t)255;
        return p;
    };
    float* buf_x  = (float*)alloc((size_t)N * HC * 4);     // layer outputs / next input
    float* xh     = (float*)alloc((size_t)N * NF2 * 4);    // GAT linear output
    float* skip   = (float*)alloc((size_t)N * HC * 4);     // skip linear output
    float* a_src  = (float*)alloc((size_t)N * 4 * 4);
    float* a_dst  = (float*)alloc((size_t)N * 4 * 4);
    int* deg      = (int*)alloc((size_t)N * 4);
    int* row_ptr  = (int*)alloc((size_t)(N + 1) * 4);
    int* fill     = (int*)alloc((size_t)N * 4);
    int* col      = (int*)alloc((size_t)ET_ * 4);

    // ---- CSR build (dst-sorted adjacency, self-loops included) ----
    init_deg_kernel<<<(N + 255) / 256, 256, 0, stream>>>(deg, N);
    count_kernel<<<(E + 255) / 256, 256, 0, stream>>>(ei + E, deg, E);
    scan_kernel<<<1, 1024, 0, stream>>>(deg, row_ptr, fill, N);
    fill_kernel<<<(ET_ + 255) / 256, 256, 0, stream>>>(ei, fill, col, E, N);

    dim3 blk(256);
    dim3 g128((N + 63) / 64, 2);   // N-out = 128
    dim3 g188((N + 63) / 64, 3);   // N-out = 188
    dim3 g47((N + 63) / 64, 1);    // N-out = 47
    int wave_blocks = (N + 3) / 4; // one wave per node, 4 waves/block

    // ---- layer 0 ----
    sgemm_kernel<<<g128, blk, 0, stream>>>(x, lin_w0, nullptr, xh, N, HC);
    sgemm_kernel<<<g128, blk, 0, stream>>>(x, skip_w0, skip_b0, skip, N, HC);
    att_kernel<HC, 32><<<wave_blocks, blk, 0, stream>>>(xh, att_src0, att_dst0, a_src, a_dst, N);
    agg_kernel<HC, 32, 0><<<wave_blocks, blk, 0, stream>>>(xh, a_src, a_dst, skip, bias0,
                                                           row_ptr, col, buf_x, N);
    // ---- layer 1 ----
    sgemm_kernel<<<g128, blk, 0, stream>>>(buf_x, lin_w1, nullptr, xh, N, HC);
    sgemm_kernel<<<g128, blk, 0, stream>>>(buf_x, skip_w1, skip_b1, skip, N, HC);
    att_kernel<HC, 32><<<wave_blocks, blk, 0, stream>>>(xh, att_src1, att_dst1, a_src, a_dst, N);
    agg_kernel<HC, 32, 0><<<wave_blocks, blk, 0, stream>>>(xh, a_src, a_dst, skip, bias1,
                                                           row_ptr, col, buf_x, N);
    // ---- layer 2 ----
    sgemm_kernel<<<g188, blk, 0, stream>>>(buf_x, lin_w2, nullptr, xh, N, NF2);
    sgemm_kernel<<<g47, blk, 0, stream>>>(buf_x, skip_w2, skip_b2, skip, N, OUTC);
    att_kernel<NF2, OUTC><<<wave_blocks, blk, 0, stream>>>(xh, att_src2, att_dst2, a_src, a_dst, N);
    agg_kernel<NF2, OUTC, 1><<<wave_blocks, blk, 0, stream>>>(xh, a_src, a_dst, skip, bias2,
                                                              row_ptr, col, out, N);
}

// Round 2
// 780.050 us; speedup vs baseline: 1.1615x; 1.1615x over previous
//
#include <hip/hip_runtime.h>
#include <math.h>

// Problem constants (fixed by reference)
#define KD 128      // K dim of every GEMM (IN = HC = 128)
#define HC 128      // H*C for layers 0/1
#define NF2 188     // H*OUT for layer 2
#define OUTC 47

typedef __attribute__((ext_vector_type(8))) __bf16 bf16x8;
typedef __attribute__((ext_vector_type(4))) float f32x4;

__device__ inline float bfhi_to_f(unsigned int u) {
    union { unsigned int u; float f; } c; c.u = u & 0xFFFF0000u; return c.f;
}
__device__ inline float bflo_to_f(unsigned int u) {
    union { unsigned int u; float f; } c; c.u = u << 16; return c.f;
}
__device__ inline unsigned short f_to_bfu(float f) {
    return __builtin_bit_cast(unsigned short, (__bf16)f);
}

// ---------------------------------------------------------------------------
// CSR build
// ---------------------------------------------------------------------------
__global__ void init_deg_kernel(int* deg, int n) {
    int i = blockIdx.x * blockDim.x + threadIdx.x;
    if (i < n) deg[i] = 1;  // self-loop contributes 1
}

__global__ void count_kernel(const int* __restrict__ dst, int* deg, int e) {
    int i = blockIdx.x * blockDim.x + threadIdx.x;
    if (i < e) atomicAdd(&deg[dst[i]], 1);
}

// single block of 1024 threads: exclusive scan of deg[n] -> row_ptr, fill
__global__ void scan_kernel(const int* __restrict__ deg, int* row_ptr, int* fill, int n) {
    __shared__ int sums[1024];
    int t = threadIdx.x;
    int chunk = (n + 1023) / 1024;
    int begin = t * chunk;
    int stop = begin + chunk; if (stop > n) stop = n;
    int s = 0;
    for (int i = begin; i < stop; ++i) s += deg[i];
    sums[t] = s;
    __syncthreads();
    for (int off = 1; off < 1024; off <<= 1) {
        int v = (t >= off) ? sums[t - off] : 0;
        __syncthreads();
        sums[t] += v;
        __syncthreads();
    }
    int running = (t == 0) ? 0 : sums[t - 1];
    for (int i = begin; i < stop; ++i) {
        row_ptr[i] = running;
        fill[i] = running;
        running += deg[i];
    }
    if (t == 1023) row_ptr[n] = sums[1023];
}

__global__ void fill_kernel(const int* __restrict__ ei, int* fill, int* col, int e, int n) {
    int i = blockIdx.x * blockDim.x + threadIdx.x;
    if (i < e) {
        int d = ei[e + i];                 // dst
        int pos = atomicAdd(&fill[d], 1);
        col[pos] = ei[i];                  // src
    } else if (i < e + n) {
        int node = i - e;                  // self loop
        int pos = atomicAdd(&fill[node], 1);
        col[pos] = node;
    }
}

// ---------------------------------------------------------------------------
// fp32 -> bf16 conversion (n divisible by 4)
// ---------------------------------------------------------------------------
__global__ void f2bf_kernel(const float* __restrict__ in, unsigned short* __restrict__ out, int n4) {
    int i = blockIdx.x * blockDim.x + threadIdx.x;
    if (i < n4) {
        float4 v = *(const float4*)(in + 4 * (long)i);
        ushort4 o;
        o.x = f_to_bfu(v.x); o.y = f_to_bfu(v.y); o.z = f_to_bfu(v.z); o.w = f_to_bfu(v.w);
        *(ushort4*)(out + 4 * (long)i) = o;
    }
}

// ---------------------------------------------------------------------------
// bf16 MFMA GEMM: C[M,N] = A[M,128] @ B[128,N] (+bias). A bf16, B fp32 (tiny,
// converted during staging). BM=128, BN=64, full K=128 staged. 256 thr = 4 waves.
// MFMA 16x16x32 bf16; layouts per m89-verified mapping.
// ---------------------------------------------------------------------------
template <bool STORE_BF16>
__global__ __launch_bounds__(256) void gemm_bf16_kernel(
    const __bf16* __restrict__ A, const float* __restrict__ B,
    const float* __restrict__ bias, void* __restrict__ Cout, int M, int N) {
    __shared__ __bf16 As[128][136];   // [m][k], +8 pad -> 2-way bank alias (free)
    __shared__ __bf16 Bs[64][136];    // [n][k] (transposed)
    int tid = threadIdx.x;
    int m0 = blockIdx.x * 128;
    int n0 = blockIdx.y * 64;

    // stage A: 128 rows x 128 bf16, 16B vector loads
#pragma unroll
    for (int rep = 0; rep < 8; ++rep) {
        int idx = tid + rep * 256;          // 0..2047
        int row = idx >> 4, seg = idx & 15; // 16B segment within row
        int gm = m0 + row;
        bf16x8 v = {};
        if (gm < M) v = *(const bf16x8*)(A + (long)gm * KD + seg * 8);
        *(bf16x8*)&As[row][seg * 8] = v;
    }
    // stage B transposed: Bs[n][k] = bf16(B[k][n0+n])
#pragma unroll
    for (int rep = 0; rep < 32; ++rep) {
        int idx = tid + rep * 256;          // 0..8191
        int k = idx >> 6, n = idx & 63;
        float v = 0.f;
        if (n0 + n < N) v = B[(long)k * N + n0 + n];
        Bs[n][k] = (__bf16)v;
    }
    __syncthreads();

    int w = tid >> 6, lane = tid & 63;
    int lr = lane & 15, quad = lane >> 4;
    f32x4 acc[2][4] = {};
#pragma unroll
    for (int kc = 0; kc < 128; kc += 32) {
        bf16x8 a0 = *(const bf16x8*)&As[w * 32 + lr][kc + quad * 8];
        bf16x8 a1 = *(const bf16x8*)&As[w * 32 + 16 + lr][kc + quad * 8];
        bf16x8 b0 = *(const bf16x8*)&Bs[lr][kc + quad * 8];
        bf16x8 b1 = *(const bf16x8*)&Bs[16 + lr][kc + quad * 8];
        bf16x8 b2 = *(const bf16x8*)&Bs[32 + lr][kc + quad * 8];
        bf16x8 b3 = *(const bf16x8*)&Bs[48 + lr][kc + quad * 8];
        acc[0][0] = __builtin_amdgcn_mfma_f32_16x16x32_bf16(a0, b0, acc[0][0], 0, 0, 0);
        acc[0][1] = __builtin_amdgcn_mfma_f32_16x16x32_bf16(a0, b1, acc[0][1], 0, 0, 0);
        acc[0][2] = __builtin_amdgcn_mfma_f32_16x16x32_bf16(a0, b2, acc[0][2], 0, 0, 0);
        acc[0][3] = __builtin_amdgcn_mfma_f32_16x16x32_bf16(a0, b3, acc[0][3], 0, 0, 0);
        acc[1][0] = __builtin_amdgcn_mfma_f32_16x16x32_bf16(a1, b0, acc[1][0], 0, 0, 0);
        acc[1][1] = __builtin_amdgcn_mfma_f32_16x16x32_bf16(a1, b1, acc[1][1], 0, 0, 0);
        acc[1][2] = __builtin_amdgcn_mfma_f32_16x16x32_bf16(a1, b2, acc[1][2], 0, 0, 0);
        acc[1][3] = __builtin_amdgcn_mfma_f32_16x16x32_bf16(a1, b3, acc[1][3], 0, 0, 0);
    }
    // epilogue: C/D layout col=lane&15, row=quad*4+reg
#pragma unroll
    for (int r = 0; r < 2; ++r) {
#pragma unroll
        for (int c = 0; c < 4; ++c) {
#pragma unroll
            for (int reg = 0; reg < 4; ++reg) {
                int row = m0 + w * 32 + r * 16 + quad * 4 + reg;
                int colg = n0 + c * 16 + lr;
                if (row < M && colg < N) {
                    float v = acc[r][c][reg];
                    if (bias) v += bias[colg];
                    if (STORE_BF16)
                        ((__bf16*)Cout)[(long)row * N + colg] = (__bf16)v;
                    else
                        ((float*)Cout)[(long)row * N + colg] = v;
                }
            }
        }
    }
}

// ---------------------------------------------------------------------------
// a_src[n,h] = sum_c xh[n,h*C+c]*att_s[h*C+c]; same for a_dst. One wave/node.
// xh is bf16.
// ---------------------------------------------------------------------------
template <int NF, int C>
__global__ __launch_bounds__(256) void att_kernel(
    const __bf16* __restrict__ xh, const float* __restrict__ att_s,
    const float* __restrict__ att_d, float* __restrict__ a_src,
    float* __restrict__ a_dst, int n) {
    int node = (blockIdx.x * blockDim.x + threadIdx.x) >> 6;
    int lane = threadIdx.x & 63;
    if (node >= n) return;
    constexpr int NR = (NF + 63) / 64;
    float hs[4] = {0.f, 0.f, 0.f, 0.f};
    float hd[4] = {0.f, 0.f, 0.f, 0.f};
#pragma unroll
    for (int r = 0; r < NR; ++r) {
        int f = lane + 64 * r;
        if (f < NF) {
            float x = (float)xh[(long)node * NF + f];
            float ps = x * att_s[f];
            float pd = x * att_d[f];
            int h = f / C;
            if (h == 0)      { hs[0] += ps; hd[0] += pd; }
            else if (h == 1) { hs[1] += ps; hd[1] += pd; }
            else if (h == 2) { hs[2] += ps; hd[2] += pd; }
            else             { hs[3] += ps; hd[3] += pd; }
        }
    }
#pragma unroll
    for (int off = 32; off >= 1; off >>= 1) {
#pragma unroll
        for (int h = 0; h < 4; ++h) {
            hs[h] += __shfl_xor(hs[h], off, 64);
            hd[h] += __shfl_xor(hd[h], off, 64);
        }
    }
    if (lane == 0) {
        *(float4*)(a_src + 4 * (long)node) = make_float4(hs[0], hs[1], hs[2], hs[3]);
        *(float4*)(a_dst + 4 * (long)node) = make_float4(hd[0], hd[1], hd[2], hd[3]);
    }
}

// ---------------------------------------------------------------------------
// Aggregation: one wave per destination node. Pass A: online softmax stats.
// Pass B: per-chunk, owner lane computes its edge's 4 head-alphas once (4 exps)
// -> LDS; whole wave gathers xh[src] (bf16) with alphas read by broadcast.
// MODE 0: paired features f=2*lane(+1), out bf16 with bias+skip+ELU (NF=128).
// MODE 1: r-stride features, head-mean + bias + skip, out fp32 (NF=188,C=47).
// ---------------------------------------------------------------------------
template <int NF, int C, int MODE>
__global__ __launch_bounds__(256) void agg_kernel(
    const __bf16* __restrict__ xh, const float* __restrict__ a_src,
    const float* __restrict__ a_dst, const float* __restrict__ skip,
    const float* __restrict__ bias, const int* __restrict__ row_ptr,
    const int* __restrict__ col, void* __restrict__ outp, int n) {
    __shared__ float s_alpha[4][64][4];
    __shared__ int s_j[4][64];
    int w = threadIdx.x >> 6;
    int node = (blockIdx.x * blockDim.x + threadIdx.x) >> 6;
    int lane = threadIdx.x & 63;
    if (node >= n) return;
    int start = row_ptr[node];
    int end = row_ptr[node + 1];
    float4 ad4 = *(const float4*)(a_dst + 4 * (long)node);
    float adh[4] = {ad4.x, ad4.y, ad4.z, ad4.w};

    // pass A: online max/sum per head, lanes strided over edges
    float m[4] = {-1e30f, -1e30f, -1e30f, -1e30f};
    float s[4] = {0.f, 0.f, 0.f, 0.f};
    for (int e = start + lane; e < end; e += 64) {
        int j = col[e];
        float4 as4 = *(const float4*)(a_src + 4 * (long)j);
        float ev[4] = {as4.x + adh[0], as4.y + adh[1], as4.z + adh[2], as4.w + adh[3]};
#pragma unroll
        for (int h = 0; h < 4; ++h) {
            float v = ev[h] > 0.f ? ev[h] : 0.2f * ev[h];
            float M = fmaxf(m[h], v);
            s[h] = s[h] * __expf(m[h] - M) + __expf(v - M);
            m[h] = M;
        }
    }
#pragma unroll
    for (int off = 32; off >= 1; off >>= 1) {
#pragma unroll
        for (int h = 0; h < 4; ++h) {
            float m2 = __shfl_xor(m[h], off, 64);
            float s2 = __shfl_xor(s[h], off, 64);
            float M = fmaxf(m[h], m2);
            s[h] = s[h] * __expf(m[h] - M) + s2 * __expf(m2 - M);
            m[h] = M;
        }
    }
    float inv[4];
#pragma unroll
    for (int h = 0; h < 4; ++h) inv[h] = 1.f / (s[h] + 1e-16f);

    // per-lane feature bookkeeping
    constexpr int NR = (NF + 63) / 64;
    float acc[NR];
    int fr[NR], hr[NR];
    bool valid[NR];
#pragma unroll
    for (int r = 0; r < NR; ++r) {
        acc[r] = 0.f;
        fr[r] = lane + 64 * r;
        valid[r] = (fr[r] < NF);
        hr[r] = valid[r] ? (fr[r] / C) : 0;
    }
    int myh = lane >> 4;  // MODE 0 paired layout: h = (2*lane)/32 = lane>>4

    for (int base = start; base < end; base += 64) {
        int e = base + lane;
        bool ok = (e < end);
        int jv = ok ? col[e] : 0;
        float4 as4 = *(const float4*)(a_src + 4 * (long)jv);
        float asv[4] = {as4.x, as4.y, as4.z, as4.w};
        float al[4];
#pragma unroll
        for (int h = 0; h < 4; ++h) {
            float ev = asv[h] + adh[h];
            ev = ev > 0.f ? ev : 0.2f * ev;
            al[h] = ok ? __expf(ev - m[h]) * inv[h] : 0.f;
        }
        s_j[w][lane] = jv;
        *(float4*)&s_alpha[w][lane][0] = make_float4(al[0], al[1], al[2], al[3]);
        int cnt = end - base; if (cnt > 64) cnt = 64;
        if (MODE == 0) {
            const unsigned int* xb = (const unsigned int*)xh;
            for (int t = 0; t < cnt; ++t) {
                int j = s_j[w][t];
                float a = s_alpha[w][t][myh];
                unsigned int p = xb[(long)j * (NF / 2) + lane];  // 2 bf16: f=2*lane, 2*lane+1
                acc[0] += a * bflo_to_f(p);
                acc[1] += a * bfhi_to_f(p);
            }
        } else {
            const unsigned short* xu = (const unsigned short*)xh;
            for (int t = 0; t < cnt; ++t) {
                int j = s_j[w][t];
                const unsigned short* xr = xu + (long)j * NF;
#pragma unroll
                for (int r = 0; r < NR; ++r) {
                    if (valid[r]) {
                        float a = s_alpha[w][t][hr[r]];
                        acc[r] += a * bflo_to_f((unsigned int)xr[fr[r]]);
                    }
                }
            }
        }
    }

    if constexpr (MODE == 0) {
        float2 bb = *(const float2*)(bias + 2 * lane);
        float2 sk = *(const float2*)(skip + (long)node * NF + 2 * lane);
        float v0 = acc[0] + bb.x + sk.x;
        float v1 = acc[1] + bb.y + sk.y;
        v0 = v0 > 0.f ? v0 : (__expf(v0) - 1.f);   // ELU
        v1 = v1 > 0.f ? v1 : (__expf(v1) - 1.f);
        unsigned int packed = (unsigned int)f_to_bfu(v0) | ((unsigned int)f_to_bfu(v1) << 16);
        ((unsigned int*)outp)[(long)node * (NF / 2) + lane] = packed;
    } else {
        // head mean: out[c] = (A[c] + A[c+47] + A[c+94] + A[c+141]) / 4
        float* out = (float*)outp;
        int c = lane;
        float v1 = acc[0];
        float s0 = __shfl(acc[0], (c + 47) & 63, 64);
        float s1 = __shfl(acc[1], (c - 17) & 63, 64);
        float v2 = (c < 17) ? s0 : s1;
        float s2 = __shfl(acc[1], (c + 30) & 63, 64);
        float s3 = __shfl(acc[2], (c - 34) & 63, 64);
        float v3 = (c < 34) ? s2 : s3;
        float v4 = __shfl(acc[2], (c + 13) & 63, 64);
        if (c < OUTC) {
            float v = (v1 + v2 + v3 + v4) * 0.25f + bias[c] + skip[(long)node * OUTC + c];
            out[(long)node * OUTC + c] = v;
        }
    }
}

// ---------------------------------------------------------------------------
extern "C" void kernel_launch(void* const* d_in, const int* in_sizes, int n_in,
                              void* d_out, int out_size, void* d_ws, size_t ws_size,
                              hipStream_t stream) {
    const float* x        = (const float*)d_in[0];
    const int*   ei       = (const int*)d_in[1];
    const float* lin_w0   = (const float*)d_in[2];
    const float* att_src0 = (const float*)d_in[3];
    const float* att_dst0 = (const float*)d_in[4];
    const float* bias0    = (const float*)d_in[5];
    const float* skip_w0  = (const float*)d_in[6];
    const float* skip_b0  = (const float*)d_in[7];
    const float* lin_w1   = (const float*)d_in[8];
    const float* att_src1 = (const float*)d_in[9];
    const float* att_dst1 = (const float*)d_in[10];
    const float* bias1    = (const float*)d_in[11];
    const float* skip_w1  = (const float*)d_in[12];
    const float* skip_b1  = (const float*)d_in[13];
    const float* lin_w2   = (const float*)d_in[14];
    const float* att_src2 = (const float*)d_in[15];
    const float* att_dst2 = (const float*)d_in[16];
    const float* bias2    = (const float*)d_in[17];
    const float* skip_w2  = (const float*)d_in[18];
    const float* skip_b2  = (const float*)d_in[19];
    float* out = (float*)d_out;

    const int N = in_sizes[0] / KD;       // 50000
    const int E = in_sizes[1] / 2;        // 800000
    const int ET_ = E + N;                // with self loops

    char* ws = (char*)d_ws;
    size_t off = 0;
    auto alloc = [&](size_t bytes) -> void* {
        void* p = ws + off;
        off = (off + bytes + 255) & ~(size_t)255;
        return p;
    };
    __bf16* xb     = (__bf16*)alloc((size_t)N * KD * 2);    // layer-0 A input (bf16)
    __bf16* xh     = (__bf16*)alloc((size_t)N * NF2 * 2);   // GAT linear output (bf16)
    __bf16* buf_bf = (__bf16*)alloc((size_t)N * HC * 2);    // ELU layer output (bf16)
    float* skip    = (float*)alloc((size_t)N * HC * 4);     // skip linear output (fp32)
    float* a_src   = (float*)alloc((size_t)N * 4 * 4);
    float* a_dst   = (float*)alloc((size_t)N * 4 * 4);
    int* deg       = (int*)alloc((size_t)N * 4);
    int* row_ptr   = (int*)alloc((size_t)(N + 1) * 4);
    int* fill      = (int*)alloc((size_t)N * 4);
    int* col       = (int*)alloc((size_t)ET_ * 4);

    // ---- CSR build (dst-sorted adjacency, self-loops included) ----
    init_deg_kernel<<<(N + 255) / 256, 256, 0, stream>>>(deg, N);
    count_kernel<<<(E + 255) / 256, 256, 0, stream>>>(ei + E, deg, E);
    scan_kernel<<<1, 1024, 0, stream>>>(deg, row_ptr, fill, N);
    fill_kernel<<<(ET_ + 255) / 256, 256, 0, stream>>>(ei, fill, col, E, N);

    dim3 blk(256);
    int mblocks = (N + 127) / 128;
    dim3 g128(mblocks, 2);   // N-out = 128
    dim3 g188(mblocks, 3);   // N-out = 188
    dim3 g47(mblocks, 1);    // N-out = 47
    int wave_blocks = (N + 3) / 4; // one wave per node, 4 waves/block

    // ---- layer 0 ----
    f2bf_kernel<<<(N * KD / 4 + 255) / 256, 256, 0, stream>>>(x, (unsigned short*)xb, N * KD / 4);
    gemm_bf16_kernel<true><<<g128, blk, 0, stream>>>(xb, lin_w0, nullptr, xh, N, HC);
    gemm_bf16_kernel<false><<<g128, blk, 0, stream>>>(xb, skip_w0, skip_b0, skip, N, HC);
    att_kernel<HC, 32><<<wave_blocks, blk, 0, stream>>>(xh, att_src0, att_dst0, a_src, a_dst, N);
    agg_kernel<HC, 32, 0><<<wave_blocks, blk, 0, stream>>>(xh, a_src, a_dst, skip, bias0,
                                                           row_ptr, col, buf_bf, N);
    // ---- layer 1 ----
    gemm_bf16_kernel<true><<<g128, blk, 0, stream>>>(buf_bf, lin_w1, nullptr, xh, N, HC);
    gemm_bf16_kernel<false><<<g128, blk, 0, stream>>>(buf_bf, skip_w1, skip_b1, skip, N, HC);
    att_kernel<HC, 32><<<wave_blocks, blk, 0, stream>>>(xh, att_src1, att_dst1, a_src, a_dst, N);
    agg_kernel<HC, 32, 0><<<wave_blocks, blk, 0, stream>>>(xh, a_src, a_dst, skip, bias1,
                                                           row_ptr, col, buf_bf, N);
    // ---- layer 2 ----
    gemm_bf16_kernel<true><<<g188, blk, 0, stream>>>(buf_bf, lin_w2, nullptr, xh, N, NF2);
    gemm_bf16_kernel<false><<<g47, blk, 0, stream>>>(buf_bf, skip_w2, skip_b2, skip, N, OUTC);
    att_kernel<NF2, OUTC><<<wave_blocks, blk, 0, stream>>>(xh, att_src2, att_dst2, a_src, a_dst, N);
    agg_kernel<NF2, OUTC, 1><<<wave_blocks, blk, 0, stream>>>(xh, a_src, a_dst, skip, bias2,
                                                              row_ptr, col, out, N);
}

// Round 3
// 695.443 us; speedup vs baseline: 1.3028x; 1.1217x over previous
//
#include <hip/hip_runtime.h>
#include <math.h>

// Problem constants (fixed by reference)
#define KD 128      // K dim of every GEMM (IN = HC = 128)
#define HC 128      // H*C for layers 0/1
#define NF2 188     // H*OUT for layer 2
#define OUTC 47

typedef __attribute__((ext_vector_type(8))) __bf16 bf16x8;
typedef __attribute__((ext_vector_type(4))) float f32x4;

__device__ inline float bfhi_to_f(unsigned int u) {
    union { unsigned int u; float f; } c; c.u = u & 0xFFFF0000u; return c.f;
}
__device__ inline float bflo_to_f(unsigned int u) {
    union { unsigned int u; float f; } c; c.u = u << 16; return c.f;
}
__device__ inline unsigned short f_to_bfu(float f) {
    return __builtin_bit_cast(unsigned short, (__bf16)f);
}

// ---------------------------------------------------------------------------
// CSR build
// ---------------------------------------------------------------------------
__global__ void init_deg_kernel(int* deg, int n) {
    int i = blockIdx.x * blockDim.x + threadIdx.x;
    if (i < n) deg[i] = 1;  // self-loop contributes 1
}

__global__ void count_kernel(const int* __restrict__ dst, int* deg, int e) {
    int i = blockIdx.x * blockDim.x + threadIdx.x;
    if (i < e) atomicAdd(&deg[dst[i]], 1);
}

// single block of 1024 threads: exclusive scan of deg[n] -> row_ptr, fill
__global__ void scan_kernel(const int* __restrict__ deg, int* row_ptr, int* fill, int n) {
    __shared__ int sums[1024];
    int t = threadIdx.x;
    int chunk = (n + 1023) / 1024;
    int begin = t * chunk;
    int stop = begin + chunk; if (stop > n) stop = n;
    int s = 0;
    for (int i = begin; i < stop; ++i) s += deg[i];
    sums[t] = s;
    __syncthreads();
    for (int off = 1; off < 1024; off <<= 1) {
        int v = (t >= off) ? sums[t - off] : 0;
        __syncthreads();
        sums[t] += v;
        __syncthreads();
    }
    int running = (t == 0) ? 0 : sums[t - 1];
    for (int i = begin; i < stop; ++i) {
        row_ptr[i] = running;
        fill[i] = running;
        running += deg[i];
    }
    if (t == 1023) row_ptr[n] = sums[1023];
}

__global__ void fill_kernel(const int* __restrict__ ei, int* fill, int* col, int e, int n) {
    int i = blockIdx.x * blockDim.x + threadIdx.x;
    if (i < e) {
        int d = ei[e + i];                 // dst
        int pos = atomicAdd(&fill[d], 1);
        col[pos] = ei[i];                  // src
    } else if (i < e + n) {
        int node = i - e;                  // self loop
        int pos = atomicAdd(&fill[node], 1);
        col[pos] = node;
    }
}

// ---------------------------------------------------------------------------
// fp32 -> bf16 conversion (n divisible by 4)
// ---------------------------------------------------------------------------
__global__ void f2bf_kernel(const float* __restrict__ in, unsigned short* __restrict__ out, int n4) {
    int i = blockIdx.x * blockDim.x + threadIdx.x;
    if (i < n4) {
        float4 v = *(const float4*)(in + 4 * (long)i);
        ushort4 o;
        o.x = f_to_bfu(v.x); o.y = f_to_bfu(v.y); o.z = f_to_bfu(v.z); o.w = f_to_bfu(v.w);
        *(ushort4*)(out + 4 * (long)i) = o;
    }
}

// ---------------------------------------------------------------------------
// Dual bf16 MFMA GEMM: from one A[M,128] (bf16) compute
//   out0 = A @ B0            (bf16 store, no bias)   -- lin path
//   out1 = A @ B1 + bias1    (fp32 store)            -- skip path
// grid.y: [0, nb0) -> part 0, [nb0, nb0+nb1) -> part 1. BM=128, BN=64, K=128.
// MFMA 16x16x32 bf16; m89-verified layouts.
// ---------------------------------------------------------------------------
__global__ __launch_bounds__(256) void gemm_dual_kernel(
    const __bf16* __restrict__ A,
    const float* __restrict__ B0, __bf16* __restrict__ out0, int N0, int nb0,
    const float* __restrict__ B1, const float* __restrict__ bias1,
    float* __restrict__ out1, int N1, int M) {
    __shared__ __bf16 As[128][136];   // [m][k], +8 pad -> 2-way bank alias (free)
    __shared__ __bf16 Bs[64][136];    // [n][k] (transposed)
    int tid = threadIdx.x;
    int m0 = blockIdx.x * 128;
    bool second = (int)blockIdx.y >= nb0;
    const float* B = second ? B1 : B0;
    int N = second ? N1 : N0;
    int n0 = (second ? (blockIdx.y - nb0) : blockIdx.y) * 64;

    // stage A: 128 rows x 128 bf16, 16B vector loads
#pragma unroll
    for (int rep = 0; rep < 8; ++rep) {
        int idx = tid + rep * 256;          // 0..2047
        int row = idx >> 4, seg = idx & 15; // 16B segment within row
        int gm = m0 + row;
        bf16x8 v = {};
        if (gm < M) v = *(const bf16x8*)(A + (long)gm * KD + seg * 8);
        *(bf16x8*)&As[row][seg * 8] = v;
    }
    // stage B transposed: Bs[n][k] = bf16(B[k][n0+n])
#pragma unroll
    for (int rep = 0; rep < 32; ++rep) {
        int idx = tid + rep * 256;          // 0..8191
        int k = idx >> 6, n = idx & 63;
        float v = 0.f;
        if (n0 + n < N) v = B[(long)k * N + n0 + n];
        Bs[n][k] = (__bf16)v;
    }
    __syncthreads();

    int w = tid >> 6, lane = tid & 63;
    int lr = lane & 15, quad = lane >> 4;
    f32x4 acc[2][4] = {};
#pragma unroll
    for (int kc = 0; kc < 128; kc += 32) {
        bf16x8 a0 = *(const bf16x8*)&As[w * 32 + lr][kc + quad * 8];
        bf16x8 a1 = *(const bf16x8*)&As[w * 32 + 16 + lr][kc + quad * 8];
        bf16x8 b0 = *(const bf16x8*)&Bs[lr][kc + quad * 8];
        bf16x8 b1 = *(const bf16x8*)&Bs[16 + lr][kc + quad * 8];
        bf16x8 b2 = *(const bf16x8*)&Bs[32 + lr][kc + quad * 8];
        bf16x8 b3 = *(const bf16x8*)&Bs[48 + lr][kc + quad * 8];
        acc[0][0] = __builtin_amdgcn_mfma_f32_16x16x32_bf16(a0, b0, acc[0][0], 0, 0, 0);
        acc[0][1] = __builtin_amdgcn_mfma_f32_16x16x32_bf16(a0, b1, acc[0][1], 0, 0, 0);
        acc[0][2] = __builtin_amdgcn_mfma_f32_16x16x32_bf16(a0, b2, acc[0][2], 0, 0, 0);
        acc[0][3] = __builtin_amdgcn_mfma_f32_16x16x32_bf16(a0, b3, acc[0][3], 0, 0, 0);
        acc[1][0] = __builtin_amdgcn_mfma_f32_16x16x32_bf16(a1, b0, acc[1][0], 0, 0, 0);
        acc[1][1] = __builtin_amdgcn_mfma_f32_16x16x32_bf16(a1, b1, acc[1][1], 0, 0, 0);
        acc[1][2] = __builtin_amdgcn_mfma_f32_16x16x32_bf16(a1, b2, acc[1][2], 0, 0, 0);
        acc[1][3] = __builtin_amdgcn_mfma_f32_16x16x32_bf16(a1, b3, acc[1][3], 0, 0, 0);
    }
    // epilogue: C/D layout col=lane&15, row=quad*4+reg
#pragma unroll
    for (int r = 0; r < 2; ++r) {
#pragma unroll
        for (int c = 0; c < 4; ++c) {
#pragma unroll
            for (int reg = 0; reg < 4; ++reg) {
                int row = m0 + w * 32 + r * 16 + quad * 4 + reg;
                int colg = n0 + c * 16 + lr;
                if (row < M && colg < N) {
                    float v = acc[r][c][reg];
                    if (second) {
                        if (bias1) v += bias1[colg];
                        out1[(long)row * N + colg] = v;
                    } else {
                        out0[(long)row * N + colg] = (__bf16)v;
                    }
                }
            }
        }
    }
}

// ---------------------------------------------------------------------------
// a_src[n,h] = sum_c xh[n,h*C+c]*att_s[h*C+c]; same for a_dst. One wave/node.
// xh is bf16.
// ---------------------------------------------------------------------------
template <int NF, int C>
__global__ __launch_bounds__(256) void att_kernel(
    const __bf16* __restrict__ xh, const float* __restrict__ att_s,
    const float* __restrict__ att_d, float* __restrict__ a_src,
    float* __restrict__ a_dst, int n) {
    int node = (blockIdx.x * blockDim.x + threadIdx.x) >> 6;
    int lane = threadIdx.x & 63;
    if (node >= n) return;
    constexpr int NR = (NF + 63) / 64;
    float hs[4] = {0.f, 0.f, 0.f, 0.f};
    float hd[4] = {0.f, 0.f, 0.f, 0.f};
#pragma unroll
    for (int r = 0; r < NR; ++r) {
        int f = lane + 64 * r;
        if (f < NF) {
            float x = (float)xh[(long)node * NF + f];
            float ps = x * att_s[f];
            float pd = x * att_d[f];
            int h = f / C;
            if (h == 0)      { hs[0] += ps; hd[0] += pd; }
            else if (h == 1) { hs[1] += ps; hd[1] += pd; }
            else if (h == 2) { hs[2] += ps; hd[2] += pd; }
            else             { hs[3] += ps; hd[3] += pd; }
        }
    }
#pragma unroll
    for (int off = 32; off >= 1; off >>= 1) {
#pragma unroll
        for (int h = 0; h < 4; ++h) {
            hs[h] += __shfl_xor(hs[h], off, 64);
            hd[h] += __shfl_xor(hd[h], off, 64);
        }
    }
    if (lane == 0) {
        *(float4*)(a_src + 4 * (long)node) = make_float4(hs[0], hs[1], hs[2], hs[3]);
        *(float4*)(a_dst + 4 * (long)node) = make_float4(hd[0], hd[1], hd[2], hd[3]);
    }
}

// ---------------------------------------------------------------------------
// Aggregation: one wave per destination node.
// Pass A computes online softmax stats AND captures chunk-0 edge logits so
// pass B's first (usually only) chunk needs no col/a_src reload.
// Pass B: owner lane publishes its edge's 4 head-alphas + src idx to LDS; the
// wave gathers xh rows as packed uint pairs, unrolled x4 for MLP.
// MODE 0: f=2*lane(+1), out bf16 with bias+skip+ELU (NF=128).
// MODE 1: pairs p=lane and p=64+lane (lane<30), head-mean via LDS, out fp32.
// ---------------------------------------------------------------------------
template <int NF, int MODE>
__global__ __launch_bounds__(256) void agg_kernel(
    const __bf16* __restrict__ xh, const float* __restrict__ a_src,
    const float* __restrict__ a_dst, const float* __restrict__ skip,
    const float* __restrict__ bias, const int* __restrict__ row_ptr,
    const int* __restrict__ col, void* __restrict__ outp, int n) {
    __shared__ float s_alpha[4][64][4];
    __shared__ int s_j[4][64];
    __shared__ float s_acc[4][192];    // MODE 1 head-mean staging
    int w = threadIdx.x >> 6;
    int lane = threadIdx.x & 63;
    int node = (blockIdx.x << 2) + w;
    bool active = node < n;
    int node_c = active ? node : 0;
    int start = row_ptr[node_c];
    int end = active ? row_ptr[node_c + 1] : start;
    float4 ad4 = *(const float4*)(a_dst + 4 * (long)node_c);
    float adh[4] = {ad4.x, ad4.y, ad4.z, ad4.w};

    // ---- pass A (+ chunk-0 capture) ----
    int e0 = start + lane;
    bool ok0 = e0 < end;
    int jcap = ok0 ? col[e0] : 0;
    float evc[4];
    {
        float4 as4 = *(const float4*)(a_src + 4 * (long)jcap);
        float v0 = as4.x + adh[0]; evc[0] = v0 > 0.f ? v0 : 0.2f * v0;
        float v1 = as4.y + adh[1]; evc[1] = v1 > 0.f ? v1 : 0.2f * v1;
        float v2 = as4.z + adh[2]; evc[2] = v2 > 0.f ? v2 : 0.2f * v2;
        float v3 = as4.w + adh[3]; evc[3] = v3 > 0.f ? v3 : 0.2f * v3;
    }
    float m[4], s[4];
#pragma unroll
    for (int h = 0; h < 4; ++h) {
        m[h] = ok0 ? evc[h] : -1e30f;
        s[h] = ok0 ? 1.f : 0.f;
    }
    for (int e = e0 + 64; e < end; e += 64) {
        int j = col[e];
        float4 as4 = *(const float4*)(a_src + 4 * (long)j);
        float ev[4] = {as4.x + adh[0], as4.y + adh[1], as4.z + adh[2], as4.w + adh[3]};
#pragma unroll
        for (int h = 0; h < 4; ++h) {
            float v = ev[h] > 0.f ? ev[h] : 0.2f * ev[h];
            float M = fmaxf(m[h], v);
            s[h] = s[h] * __expf(m[h] - M) + __expf(v - M);
            m[h] = M;
        }
    }
#pragma unroll
    for (int off = 32; off >= 1; off >>= 1) {
#pragma unroll
        for (int h = 0; h < 4; ++h) {
            float m2 = __shfl_xor(m[h], off, 64);
            float s2 = __shfl_xor(s[h], off, 64);
            float M = fmaxf(m[h], m2);
            s[h] = s[h] * __expf(m[h] - M) + s2 * __expf(m2 - M);
            m[h] = M;
        }
    }
    float inv[4];
#pragma unroll
    for (int h = 0; h < 4; ++h) inv[h] = 1.f / (s[h] + 1e-16f);

    // ---- pass B ----
    const unsigned int* xb = (const unsigned int*)xh;
    constexpr int P = NF / 2;          // packed pairs per row
    int myh = lane >> 4;               // MODE 0: h = (2*lane)/32
    // MODE 1 per-lane head bookkeeping (pairs p=lane, p=64+lane)
    int h00 = (2 * lane) / 47, h01 = (2 * lane + 1) / 47;
    int h10 = (128 + 2 * lane) / 47; if (h10 > 3) h10 = 3;
    int h11 = (129 + 2 * lane) / 47; if (h11 > 3) h11 = 3;
    bool has2 = lane < 30;
    float accA0 = 0.f, accA1 = 0.f, accB0 = 0.f, accB1 = 0.f;  // MODE0 dual-accum
    float acc00 = 0.f, acc01 = 0.f, acc10 = 0.f, acc11 = 0.f;  // MODE1

    auto run_chunk = [&](int cnt) {
        int t = 0;
        if (MODE == 0) {
            for (; t + 3 < cnt; t += 4) {
                int j0 = s_j[w][t], j1 = s_j[w][t + 1], j2 = s_j[w][t + 2], j3 = s_j[w][t + 3];
                unsigned int q0 = xb[(long)j0 * P + lane];
                unsigned int q1 = xb[(long)j1 * P + lane];
                unsigned int q2 = xb[(long)j2 * P + lane];
                unsigned int q3 = xb[(long)j3 * P + lane];
                float a0 = s_alpha[w][t][myh], a1 = s_alpha[w][t + 1][myh];
                float a2 = s_alpha[w][t + 2][myh], a3 = s_alpha[w][t + 3][myh];
                accA0 += a0 * bflo_to_f(q0); accA1 += a0 * bfhi_to_f(q0);
                accB0 += a1 * bflo_to_f(q1); accB1 += a1 * bfhi_to_f(q1);
                accA0 += a2 * bflo_to_f(q2); accA1 += a2 * bfhi_to_f(q2);
                accB0 += a3 * bflo_to_f(q3); accB1 += a3 * bfhi_to_f(q3);
            }
            for (; t < cnt; ++t) {
                int j = s_j[w][t];
                unsigned int q = xb[(long)j * P + lane];
                float a = s_alpha[w][t][myh];
                accA0 += a * bflo_to_f(q); accA1 += a * bfhi_to_f(q);
            }
        } else {
            for (; t + 3 < cnt; t += 4) {
                int j0 = s_j[w][t], j1 = s_j[w][t + 1], j2 = s_j[w][t + 2], j3 = s_j[w][t + 3];
                unsigned int q00 = xb[(long)j0 * P + lane];
                unsigned int q10 = xb[(long)j1 * P + lane];
                unsigned int q20 = xb[(long)j2 * P + lane];
                unsigned int q30 = xb[(long)j3 * P + lane];
                unsigned int q01 = has2 ? xb[(long)j0 * P + 64 + lane] : 0u;
                unsigned int q11 = has2 ? xb[(long)j1 * P + 64 + lane] : 0u;
                unsigned int q21 = has2 ? xb[(long)j2 * P + 64 + lane] : 0u;
                unsigned int q31 = has2 ? xb[(long)j3 * P + 64 + lane] : 0u;
#pragma unroll
                for (int u = 0; u < 4; ++u) {
                    unsigned int qa = (u == 0) ? q00 : (u == 1) ? q10 : (u == 2) ? q20 : q30;
                    unsigned int qb = (u == 0) ? q01 : (u == 1) ? q11 : (u == 2) ? q21 : q31;
                    acc00 += s_alpha[w][t + u][h00] * bflo_to_f(qa);
                    acc01 += s_alpha[w][t + u][h01] * bfhi_to_f(qa);
                    acc10 += s_alpha[w][t + u][h10] * bflo_to_f(qb);
                    acc11 += s_alpha[w][t + u][h11] * bfhi_to_f(qb);
                }
            }
            for (; t < cnt; ++t) {
                int j = s_j[w][t];
                unsigned int qa = xb[(long)j * P + lane];
                unsigned int qb = has2 ? xb[(long)j * P + 64 + lane] : 0u;
                acc00 += s_alpha[w][t][h00] * bflo_to_f(qa);
                acc01 += s_alpha[w][t][h01] * bfhi_to_f(qa);
                acc10 += s_alpha[w][t][h10] * bflo_to_f(qb);
                acc11 += s_alpha[w][t][h11] * bfhi_to_f(qb);
            }
        }
    };

    // chunk 0: reuse captured logits, no col/a_src reload
    {
        float al[4];
#pragma unroll
        for (int h = 0; h < 4; ++h)
            al[h] = ok0 ? __expf(evc[h] - m[h]) * inv[h] : 0.f;
        s_j[w][lane] = jcap;
        *(float4*)&s_alpha[w][lane][0] = make_float4(al[0], al[1], al[2], al[3]);
        int cnt = end - start; if (cnt > 64) cnt = 64;
        run_chunk(cnt);
    }
    // remaining chunks (deg > 64: rare)
    for (int base = start + 64; base < end; base += 64) {
        int e = base + lane;
        bool ok = e < end;
        int jv = ok ? col[e] : 0;
        float4 as4 = *(const float4*)(a_src + 4 * (long)jv);
        float asv[4] = {as4.x, as4.y, as4.z, as4.w};
        float al[4];
#pragma unroll
        for (int h = 0; h < 4; ++h) {
            float ev = asv[h] + adh[h];
            ev = ev > 0.f ? ev : 0.2f * ev;
            al[h] = ok ? __expf(ev - m[h]) * inv[h] : 0.f;
        }
        s_j[w][lane] = jv;
        *(float4*)&s_alpha[w][lane][0] = make_float4(al[0], al[1], al[2], al[3]);
        int cnt = end - base; if (cnt > 64) cnt = 64;
        run_chunk(cnt);
    }

    if constexpr (MODE == 0) {
        float acc0 = accA0 + accB0, acc1 = accA1 + accB1;
        if (active) {
            float2 bb = *(const float2*)(bias + 2 * lane);
            float2 sk = *(const float2*)(skip + (long)node * NF + 2 * lane);
            float v0 = acc0 + bb.x + sk.x;
            float v1 = acc1 + bb.y + sk.y;
            v0 = v0 > 0.f ? v0 : (__expf(v0) - 1.f);   // ELU
            v1 = v1 > 0.f ? v1 : (__expf(v1) - 1.f);
            unsigned int packed = (unsigned int)f_to_bfu(v0) | ((unsigned int)f_to_bfu(v1) << 16);
            ((unsigned int*)outp)[(long)node * P + lane] = packed;
        }
    } else {
        // head-mean via per-wave LDS staging
        s_acc[w][2 * lane] = acc00;
        s_acc[w][2 * lane + 1] = acc01;
        if (has2) {
            s_acc[w][128 + 2 * lane] = acc10;
            s_acc[w][129 + 2 * lane] = acc11;
        }
        __syncthreads();
        if (active && lane < OUTC) {
            float v = (s_acc[w][lane] + s_acc[w][lane + 47] + s_acc[w][lane + 94] +
                       s_acc[w][lane + 141]) * 0.25f +
                      bias[lane] + skip[(long)node * OUTC + lane];
            ((float*)outp)[(long)node * OUTC + lane] = v;
        }
    }
}

// ---------------------------------------------------------------------------
extern "C" void kernel_launch(void* const* d_in, const int* in_sizes, int n_in,
                              void* d_out, int out_size, void* d_ws, size_t ws_size,
                              hipStream_t stream) {
    const float* x        = (const float*)d_in[0];
    const int*   ei       = (const int*)d_in[1];
    const float* lin_w0   = (const float*)d_in[2];
    const float* att_src0 = (const float*)d_in[3];
    const float* att_dst0 = (const float*)d_in[4];
    const float* bias0    = (const float*)d_in[5];
    const float* skip_w0  = (const float*)d_in[6];
    const float* skip_b0  = (const float*)d_in[7];
    const float* lin_w1   = (const float*)d_in[8];
    const float* att_src1 = (const float*)d_in[9];
    const float* att_dst1 = (const float*)d_in[10];
    const float* bias1    = (const float*)d_in[11];
    const float* skip_w1  = (const float*)d_in[12];
    const float* skip_b1  = (const float*)d_in[13];
    const float* lin_w2   = (const float*)d_in[14];
    const float* att_src2 = (const float*)d_in[15];
    const float* att_dst2 = (const float*)d_in[16];
    const float* bias2    = (const float*)d_in[17];
    const float* skip_w2  = (const float*)d_in[18];
    const float* skip_b2  = (const float*)d_in[19];
    float* out = (float*)d_out;

    const int N = in_sizes[0] / KD;       // 50000
    const int E = in_sizes[1] / 2;        // 800000
    const int ET_ = E + N;                // with self loops

    char* ws = (char*)d_ws;
    size_t off = 0;
    auto alloc = [&](size_t bytes) -> void* {
        void* p = ws + off;
        off = (off + bytes + 255) & ~(size_t)255;
        return p;
    };
    __bf16* xb     = (__bf16*)alloc((size_t)N * KD * 2);    // layer-0 A input (bf16)
    __bf16* xh     = (__bf16*)alloc((size_t)N * NF2 * 2);   // GAT linear output (bf16)
    __bf16* buf_bf = (__bf16*)alloc((size_t)N * HC * 2);    // ELU layer output (bf16)
    float* skip    = (float*)alloc((size_t)N * HC * 4);     // skip linear output (fp32)
    float* a_src   = (float*)alloc((size_t)N * 4 * 4);
    float* a_dst   = (float*)alloc((size_t)N * 4 * 4);
    int* deg       = (int*)alloc((size_t)N * 4);
    int* row_ptr   = (int*)alloc((size_t)(N + 1) * 4);
    int* fill      = (int*)alloc((size_t)N * 4);
    int* col       = (int*)alloc((size_t)ET_ * 4);

    // ---- CSR build (dst-sorted adjacency, self-loops included) ----
    init_deg_kernel<<<(N + 255) / 256, 256, 0, stream>>>(deg, N);
    count_kernel<<<(E + 255) / 256, 256, 0, stream>>>(ei + E, deg, E);
    scan_kernel<<<1, 1024, 0, stream>>>(deg, row_ptr, fill, N);
    fill_kernel<<<(ET_ + 255) / 256, 256, 0, stream>>>(ei, fill, col, E, N);

    dim3 blk(256);
    int mblocks = (N + 127) / 128;
    dim3 g4(mblocks, 4);           // dual GEMM grids (2+2 or 3+1 column-blocks)
    int wave_blocks = (N + 3) / 4; // one wave per node, 4 waves/block

    // ---- layer 0 ----
    f2bf_kernel<<<(N * KD / 4 + 255) / 256, 256, 0, stream>>>(x, (unsigned short*)xb, N * KD / 4);
    gemm_dual_kernel<<<g4, blk, 0, stream>>>(xb, lin_w0, xh, HC, 2,
                                             skip_w0, skip_b0, skip, HC, N);
    att_kernel<HC, 32><<<wave_blocks, blk, 0, stream>>>(xh, att_src0, att_dst0, a_src, a_dst, N);
    agg_kernel<HC, 0><<<wave_blocks, blk, 0, stream>>>(xh, a_src, a_dst, skip, bias0,
                                                       row_ptr, col, buf_bf, N);
    // ---- layer 1 ----
    gemm_dual_kernel<<<g4, blk, 0, stream>>>(buf_bf, lin_w1, xh, HC, 2,
                                             skip_w1, skip_b1, skip, HC, N);
    att_kernel<HC, 32><<<wave_blocks, blk, 0, stream>>>(xh, att_src1, att_dst1, a_src, a_dst, N);
    agg_kernel<HC, 0><<<wave_blocks, blk, 0, stream>>>(xh, a_src, a_dst, skip, bias1,
                                                       row_ptr, col, buf_bf, N);
    // ---- layer 2 ----
    gemm_dual_kernel<<<g4, blk, 0, stream>>>(buf_bf, lin_w2, xh, NF2, 3,
                                             skip_w2, skip_b2, skip, OUTC, N);
    att_kernel<NF2, OUTC><<<wave_blocks, blk, 0, stream>>>(xh, att_src2, att_dst2, a_src, a_dst, N);
    agg_kernel<NF2, 1><<<wave_blocks, blk, 0, stream>>>(xh, a_src, a_dst, skip, bias2,
                                                        row_ptr, col, out, N);
}

// Round 4
// 589.966 us; speedup vs baseline: 1.5358x; 1.1788x over previous
//
#include <hip/hip_runtime.h>
#include <math.h>

// Problem constants (fixed by reference)
#define KD 128      // K dim of every GEMM (IN = HC = 128)
#define HC 128      // H*C for layers 0/1
#define NF2 188     // H*OUT for layer 2
#define OUTC 47

typedef __attribute__((ext_vector_type(8))) __bf16 bf16x8;
typedef __attribute__((ext_vector_type(4))) float f32x4;

__device__ inline float bfhi_to_f(unsigned int u) {
    union { unsigned int u; float f; } c; c.u = u & 0xFFFF0000u; return c.f;
}
__device__ inline float bflo_to_f(unsigned int u) {
    union { unsigned int u; float f; } c; c.u = u << 16; return c.f;
}
__device__ inline unsigned short f_to_bfu(float f) {
    return __builtin_bit_cast(unsigned short, (__bf16)f);
}

// ---------------------------------------------------------------------------
// CSR build
// ---------------------------------------------------------------------------
__global__ void init_deg_kernel(int* deg, int n) {
    int i = blockIdx.x * blockDim.x + threadIdx.x;
    if (i < n) deg[i] = 1;  // self-loop contributes 1
}

__global__ void count_kernel(const int* __restrict__ dst, int* deg, int e) {
    int i = blockIdx.x * blockDim.x + threadIdx.x;
    if (i < e) atomicAdd(&deg[dst[i]], 1);
}

// ---- two-level parallel exclusive scan of deg[n] -> row_ptr, fill ----
// A: per-block (256-elem) sums
__global__ __launch_bounds__(256) void block_sum_kernel(
    const int* __restrict__ deg, int* __restrict__ bsums, int n) {
    int i = blockIdx.x * 256 + threadIdx.x;
    int v = (i < n) ? deg[i] : 0;
#pragma unroll
    for (int off = 32; off >= 1; off >>= 1) v += __shfl_xor(v, off, 64);
    __shared__ int ws[4];
    if ((threadIdx.x & 63) == 0) ws[threadIdx.x >> 6] = v;
    __syncthreads();
    if (threadIdx.x == 0) bsums[blockIdx.x] = ws[0] + ws[1] + ws[2] + ws[3];
}

// B: single block, exclusive scan of nb block sums (nb <= 1024)
__global__ __launch_bounds__(1024) void scan_sums_kernel(int* bsums, int nb) {
    __shared__ int tmp[1024];
    int t = threadIdx.x;
    int v = (t < nb) ? bsums[t] : 0;
    tmp[t] = v;
    __syncthreads();
    for (int off = 1; off < 1024; off <<= 1) {
        int u = (t >= off) ? tmp[t - off] : 0;
        __syncthreads();
        tmp[t] += u;
        __syncthreads();
    }
    if (t < nb) bsums[t] = tmp[t] - v;  // exclusive
}

// C: per-block exclusive scan + block offset -> row_ptr, fill
__global__ __launch_bounds__(256) void write_ptr_kernel(
    const int* __restrict__ deg, const int* __restrict__ bsums,
    int* __restrict__ row_ptr, int* __restrict__ fill, int n) {
    int i = blockIdx.x * 256 + threadIdx.x;
    int v = (i < n) ? deg[i] : 0;
    int lane = threadIdx.x & 63, w = threadIdx.x >> 6;
    int incl = v;
#pragma unroll
    for (int off = 1; off < 64; off <<= 1) {
        int u = __shfl_up(incl, off, 64);
        if (lane >= off) incl += u;
    }
    __shared__ int wsum[4];
    if (lane == 63) wsum[w] = incl;
    __syncthreads();
    int woff = 0;
    for (int k = 0; k < w; ++k) woff += wsum[k];
    int excl = incl - v + woff + bsums[blockIdx.x];
    if (i < n) { row_ptr[i] = excl; fill[i] = excl; }
    if (i == n - 1) row_ptr[n] = excl + v;
}

__global__ void fill_kernel(const int* __restrict__ ei, int* fill, int* col, int e, int n) {
    int i = blockIdx.x * blockDim.x + threadIdx.x;
    if (i < e) {
        int d = ei[e + i];                 // dst
        int pos = atomicAdd(&fill[d], 1);
        col[pos] = ei[i];                  // src
    } else if (i < e + n) {
        int node = i - e;                  // self loop
        int pos = atomicAdd(&fill[node], 1);
        col[pos] = node;
    }
}

// ---------------------------------------------------------------------------
// fp32 -> bf16 conversion (n divisible by 4)
// ---------------------------------------------------------------------------
__global__ void f2bf_kernel(const float* __restrict__ in, unsigned short* __restrict__ out, int n4) {
    int i = blockIdx.x * blockDim.x + threadIdx.x;
    if (i < n4) {
        float4 v = *(const float4*)(in + 4 * (long)i);
        ushort4 o;
        o.x = f_to_bfu(v.x); o.y = f_to_bfu(v.y); o.z = f_to_bfu(v.z); o.w = f_to_bfu(v.w);
        *(ushort4*)(out + 4 * (long)i) = o;
    }
}

// ---------------------------------------------------------------------------
// Dual bf16 MFMA GEMM: from one A[M,128] (bf16) compute
//   out0 = A @ B0            (bf16 store, no bias)   -- lin path
//   out1 = A @ B1 + bias1    (fp32 store)            -- skip path
// grid.y: [0, nb0) -> part 0, [nb0, nb0+nb1) -> part 1. BM=128, BN=64, K=128.
// MFMA 16x16x32 bf16; m89-verified layouts.
// ---------------------------------------------------------------------------
__global__ __launch_bounds__(256) void gemm_dual_kernel(
    const __bf16* __restrict__ A,
    const float* __restrict__ B0, __bf16* __restrict__ out0, int N0, int nb0,
    const float* __restrict__ B1, const float* __restrict__ bias1,
    float* __restrict__ out1, int N1, int M) {
    __shared__ __bf16 As[128][136];   // [m][k], +8 pad -> 2-way bank alias (free)
    __shared__ __bf16 Bs[64][136];    // [n][k] (transposed)
    int tid = threadIdx.x;
    int m0 = blockIdx.x * 128;
    bool second = (int)blockIdx.y >= nb0;
    const float* B = second ? B1 : B0;
    int N = second ? N1 : N0;
    int n0 = (second ? (blockIdx.y - nb0) : blockIdx.y) * 64;

    // stage A: 128 rows x 128 bf16, 16B vector loads
#pragma unroll
    for (int rep = 0; rep < 8; ++rep) {
        int idx = tid + rep * 256;          // 0..2047
        int row = idx >> 4, seg = idx & 15; // 16B segment within row
        int gm = m0 + row;
        bf16x8 v = {};
        if (gm < M) v = *(const bf16x8*)(A + (long)gm * KD + seg * 8);
        *(bf16x8*)&As[row][seg * 8] = v;
    }
    // stage B transposed: Bs[n][k] = bf16(B[k][n0+n])
#pragma unroll
    for (int rep = 0; rep < 32; ++rep) {
        int idx = tid + rep * 256;          // 0..8191
        int k = idx >> 6, n = idx & 63;
        float v = 0.f;
        if (n0 + n < N) v = B[(long)k * N + n0 + n];
        Bs[n][k] = (__bf16)v;
    }
    __syncthreads();

    int w = tid >> 6, lane = tid & 63;
    int lr = lane & 15, quad = lane >> 4;
    f32x4 acc[2][4] = {};
#pragma unroll
    for (int kc = 0; kc < 128; kc += 32) {
        bf16x8 a0 = *(const bf16x8*)&As[w * 32 + lr][kc + quad * 8];
        bf16x8 a1 = *(const bf16x8*)&As[w * 32 + 16 + lr][kc + quad * 8];
        bf16x8 b0 = *(const bf16x8*)&Bs[lr][kc + quad * 8];
        bf16x8 b1 = *(const bf16x8*)&Bs[16 + lr][kc + quad * 8];
        bf16x8 b2 = *(const bf16x8*)&Bs[32 + lr][kc + quad * 8];
        bf16x8 b3 = *(const bf16x8*)&Bs[48 + lr][kc + quad * 8];
        acc[0][0] = __builtin_amdgcn_mfma_f32_16x16x32_bf16(a0, b0, acc[0][0], 0, 0, 0);
        acc[0][1] = __builtin_amdgcn_mfma_f32_16x16x32_bf16(a0, b1, acc[0][1], 0, 0, 0);
        acc[0][2] = __builtin_amdgcn_mfma_f32_16x16x32_bf16(a0, b2, acc[0][2], 0, 0, 0);
        acc[0][3] = __builtin_amdgcn_mfma_f32_16x16x32_bf16(a0, b3, acc[0][3], 0, 0, 0);
        acc[1][0] = __builtin_amdgcn_mfma_f32_16x16x32_bf16(a1, b0, acc[1][0], 0, 0, 0);
        acc[1][1] = __builtin_amdgcn_mfma_f32_16x16x32_bf16(a1, b1, acc[1][1], 0, 0, 0);
        acc[1][2] = __builtin_amdgcn_mfma_f32_16x16x32_bf16(a1, b2, acc[1][2], 0, 0, 0);
        acc[1][3] = __builtin_amdgcn_mfma_f32_16x16x32_bf16(a1, b3, acc[1][3], 0, 0, 0);
    }
    // epilogue: C/D layout col=lane&15, row=quad*4+reg
#pragma unroll
    for (int r = 0; r < 2; ++r) {
#pragma unroll
        for (int c = 0; c < 4; ++c) {
#pragma unroll
            for (int reg = 0; reg < 4; ++reg) {
                int row = m0 + w * 32 + r * 16 + quad * 4 + reg;
                int colg = n0 + c * 16 + lr;
                if (row < M && colg < N) {
                    float v = acc[r][c][reg];
                    if (second) {
                        if (bias1) v += bias1[colg];
                        out1[(long)row * N + colg] = v;
                    } else {
                        out0[(long)row * N + colg] = (__bf16)v;
                    }
                }
            }
        }
    }
}

// ---------------------------------------------------------------------------
// a_src[n,h] = sum_c xh[n,h*C+c]*att_s[h*C+c]; same for a_dst. One wave/node.
// xh is bf16.
// ---------------------------------------------------------------------------
template <int NF, int C>
__global__ __launch_bounds__(256) void att_kernel(
    const __bf16* __restrict__ xh, const float* __restrict__ att_s,
    const float* __restrict__ att_d, float* __restrict__ a_src,
    float* __restrict__ a_dst, int n) {
    int node = (blockIdx.x * blockDim.x + threadIdx.x) >> 6;
    int lane = threadIdx.x & 63;
    if (node >= n) return;
    constexpr int NR = (NF + 63) / 64;
    float hs[4] = {0.f, 0.f, 0.f, 0.f};
    float hd[4] = {0.f, 0.f, 0.f, 0.f};
#pragma unroll
    for (int r = 0; r < NR; ++r) {
        int f = lane + 64 * r;
        if (f < NF) {
            float x = (float)xh[(long)node * NF + f];
            float ps = x * att_s[f];
            float pd = x * att_d[f];
            int h = f / C;
            if (h == 0)      { hs[0] += ps; hd[0] += pd; }
            else if (h == 1) { hs[1] += ps; hd[1] += pd; }
            else if (h == 2) { hs[2] += ps; hd[2] += pd; }
            else             { hs[3] += ps; hd[3] += pd; }
        }
    }
#pragma unroll
    for (int off = 32; off >= 1; off >>= 1) {
#pragma unroll
        for (int h = 0; h < 4; ++h) {
            hs[h] += __shfl_xor(hs[h], off, 64);
            hd[h] += __shfl_xor(hd[h], off, 64);
        }
    }
    if (lane == 0) {
        *(float4*)(a_src + 4 * (long)node) = make_float4(hs[0], hs[1], hs[2], hs[3]);
        *(float4*)(a_dst + 4 * (long)node) = make_float4(hd[0], hd[1], hd[2], hd[3]);
    }
}

// ---------------------------------------------------------------------------
// Aggregation: one wave per destination node.
// Pass A computes online softmax stats AND captures chunk-0 edge logits so
// pass B's first (usually only) chunk needs no col/a_src reload.
// Pass B: owner lane publishes its edge's 4 head-alphas + src idx to LDS; the
// wave gathers xh rows as packed uint pairs, unrolled x4 for MLP.
// MODE 0: f=2*lane(+1), out bf16 with bias+skip+ELU (NF=128).
// MODE 1: pairs p=lane and p=64+lane (lane<30), head-mean via LDS, out fp32.
// ---------------------------------------------------------------------------
template <int NF, int MODE>
__global__ __launch_bounds__(256) void agg_kernel(
    const __bf16* __restrict__ xh, const float* __restrict__ a_src,
    const float* __restrict__ a_dst, const float* __restrict__ skip,
    const float* __restrict__ bias, const int* __restrict__ row_ptr,
    const int* __restrict__ col, void* __restrict__ outp, int n) {
    __shared__ float s_alpha[4][64][4];
    __shared__ int s_j[4][64];
    __shared__ float s_acc[4][192];    // MODE 1 head-mean staging
    int w = threadIdx.x >> 6;
    int lane = threadIdx.x & 63;
    int node = (blockIdx.x << 2) + w;
    bool active = node < n;
    int node_c = active ? node : 0;
    int start = row_ptr[node_c];
    int end = active ? row_ptr[node_c + 1] : start;
    float4 ad4 = *(const float4*)(a_dst + 4 * (long)node_c);
    float adh[4] = {ad4.x, ad4.y, ad4.z, ad4.w};

    // ---- pass A (+ chunk-0 capture) ----
    int e0 = start + lane;
    bool ok0 = e0 < end;
    int jcap = ok0 ? col[e0] : 0;
    float evc[4];
    {
        float4 as4 = *(const float4*)(a_src + 4 * (long)jcap);
        float v0 = as4.x + adh[0]; evc[0] = v0 > 0.f ? v0 : 0.2f * v0;
        float v1 = as4.y + adh[1]; evc[1] = v1 > 0.f ? v1 : 0.2f * v1;
        float v2 = as4.z + adh[2]; evc[2] = v2 > 0.f ? v2 : 0.2f * v2;
        float v3 = as4.w + adh[3]; evc[3] = v3 > 0.f ? v3 : 0.2f * v3;
    }
    float m[4], s[4];
#pragma unroll
    for (int h = 0; h < 4; ++h) {
        m[h] = ok0 ? evc[h] : -1e30f;
        s[h] = ok0 ? 1.f : 0.f;
    }
    for (int e = e0 + 64; e < end; e += 64) {
        int j = col[e];
        float4 as4 = *(const float4*)(a_src + 4 * (long)j);
        float ev[4] = {as4.x + adh[0], as4.y + adh[1], as4.z + adh[2], as4.w + adh[3]};
#pragma unroll
        for (int h = 0; h < 4; ++h) {
            float v = ev[h] > 0.f ? ev[h] : 0.2f * ev[h];
            float M = fmaxf(m[h], v);
            s[h] = s[h] * __expf(m[h] - M) + __expf(v - M);
            m[h] = M;
        }
    }
#pragma unroll
    for (int off = 32; off >= 1; off >>= 1) {
#pragma unroll
        for (int h = 0; h < 4; ++h) {
            float m2 = __shfl_xor(m[h], off, 64);
            float s2 = __shfl_xor(s[h], off, 64);
            float M = fmaxf(m[h], m2);
            s[h] = s[h] * __expf(m[h] - M) + s2 * __expf(m2 - M);
            m[h] = M;
        }
    }
    float inv[4];
#pragma unroll
    for (int h = 0; h < 4; ++h) inv[h] = 1.f / (s[h] + 1e-16f);

    // ---- pass B ----
    const unsigned int* xb = (const unsigned int*)xh;
    constexpr int P = NF / 2;          // packed pairs per row
    int myh = lane >> 4;               // MODE 0: h = (2*lane)/32
    // MODE 1 per-lane head bookkeeping (pairs p=lane, p=64+lane)
    int h00 = (2 * lane) / 47, h01 = (2 * lane + 1) / 47;
    int h10 = (128 + 2 * lane) / 47; if (h10 > 3) h10 = 3;
    int h11 = (129 + 2 * lane) / 47; if (h11 > 3) h11 = 3;
    bool has2 = lane < 30;
    float accA0 = 0.f, accA1 = 0.f, accB0 = 0.f, accB1 = 0.f;  // MODE0 dual-accum
    float acc00 = 0.f, acc01 = 0.f, acc10 = 0.f, acc11 = 0.f;  // MODE1

    auto run_chunk = [&](int cnt) {
        int t = 0;
        if (MODE == 0) {
            for (; t + 3 < cnt; t += 4) {
                int j0 = s_j[w][t], j1 = s_j[w][t + 1], j2 = s_j[w][t + 2], j3 = s_j[w][t + 3];
                unsigned int q0 = xb[(long)j0 * P + lane];
                unsigned int q1 = xb[(long)j1 * P + lane];
                unsigned int q2 = xb[(long)j2 * P + lane];
                unsigned int q3 = xb[(long)j3 * P + lane];
                float a0 = s_alpha[w][t][myh], a1 = s_alpha[w][t + 1][myh];
                float a2 = s_alpha[w][t + 2][myh], a3 = s_alpha[w][t + 3][myh];
                accA0 += a0 * bflo_to_f(q0); accA1 += a0 * bfhi_to_f(q0);
                accB0 += a1 * bflo_to_f(q1); accB1 += a1 * bfhi_to_f(q1);
                accA0 += a2 * bflo_to_f(q2); accA1 += a2 * bfhi_to_f(q2);
                accB0 += a3 * bflo_to_f(q3); accB1 += a3 * bfhi_to_f(q3);
            }
            for (; t < cnt; ++t) {
                int j = s_j[w][t];
                unsigned int q = xb[(long)j * P + lane];
                float a = s_alpha[w][t][myh];
                accA0 += a * bflo_to_f(q); accA1 += a * bfhi_to_f(q);
            }
        } else {
            for (; t + 3 < cnt; t += 4) {
                int j0 = s_j[w][t], j1 = s_j[w][t + 1], j2 = s_j[w][t + 2], j3 = s_j[w][t + 3];
                unsigned int q00 = xb[(long)j0 * P + lane];
                unsigned int q10 = xb[(long)j1 * P + lane];
                unsigned int q20 = xb[(long)j2 * P + lane];
                unsigned int q30 = xb[(long)j3 * P + lane];
                unsigned int q01 = has2 ? xb[(long)j0 * P + 64 + lane] : 0u;
                unsigned int q11 = has2 ? xb[(long)j1 * P + 64 + lane] : 0u;
                unsigned int q21 = has2 ? xb[(long)j2 * P + 64 + lane] : 0u;
                unsigned int q31 = has2 ? xb[(long)j3 * P + 64 + lane] : 0u;
#pragma unroll
                for (int u = 0; u < 4; ++u) {
                    unsigned int qa = (u == 0) ? q00 : (u == 1) ? q10 : (u == 2) ? q20 : q30;
                    unsigned int qb = (u == 0) ? q01 : (u == 1) ? q11 : (u == 2) ? q21 : q31;
                    acc00 += s_alpha[w][t + u][h00] * bflo_to_f(qa);
                    acc01 += s_alpha[w][t + u][h01] * bfhi_to_f(qa);
                    acc10 += s_alpha[w][t + u][h10] * bflo_to_f(qb);
                    acc11 += s_alpha[w][t + u][h11] * bfhi_to_f(qb);
                }
            }
            for (; t < cnt; ++t) {
                int j = s_j[w][t];
                unsigned int qa = xb[(long)j * P + lane];
                unsigned int qb = has2 ? xb[(long)j * P + 64 + lane] : 0u;
                acc00 += s_alpha[w][t][h00] * bflo_to_f(qa);
                acc01 += s_alpha[w][t][h01] * bfhi_to_f(qa);
                acc10 += s_alpha[w][t][h10] * bflo_to_f(qb);
                acc11 += s_alpha[w][t][h11] * bfhi_to_f(qb);
            }
        }
    };

    // chunk 0: reuse captured logits, no col/a_src reload
    {
        float al[4];
#pragma unroll
        for (int h = 0; h < 4; ++h)
            al[h] = ok0 ? __expf(evc[h] - m[h]) * inv[h] : 0.f;
        s_j[w][lane] = jcap;
        *(float4*)&s_alpha[w][lane][0] = make_float4(al[0], al[1], al[2], al[3]);
        int cnt = end - start; if (cnt > 64) cnt = 64;
        run_chunk(cnt);
    }
    // remaining chunks (deg > 64: rare)
    for (int base = start + 64; base < end; base += 64) {
        int e = base + lane;
        bool ok = e < end;
        int jv = ok ? col[e] : 0;
        float4 as4 = *(const float4*)(a_src + 4 * (long)jv);
        float asv[4] = {as4.x, as4.y, as4.z, as4.w};
        float al[4];
#pragma unroll
        for (int h = 0; h < 4; ++h) {
            float ev = asv[h] + adh[h];
            ev = ev > 0.f ? ev : 0.2f * ev;
            al[h] = ok ? __expf(ev - m[h]) * inv[h] : 0.f;
        }
        s_j[w][lane] = jv;
        *(float4*)&s_alpha[w][lane][0] = make_float4(al[0], al[1], al[2], al[3]);
        int cnt = end - base; if (cnt > 64) cnt = 64;
        run_chunk(cnt);
    }

    if constexpr (MODE == 0) {
        float acc0 = accA0 + accB0, acc1 = accA1 + accB1;
        if (active) {
            float2 bb = *(const float2*)(bias + 2 * lane);
            float2 sk = *(const float2*)(skip + (long)node * NF + 2 * lane);
            float v0 = acc0 + bb.x + sk.x;
            float v1 = acc1 + bb.y + sk.y;
            v0 = v0 > 0.f ? v0 : (__expf(v0) - 1.f);   // ELU
            v1 = v1 > 0.f ? v1 : (__expf(v1) - 1.f);
            unsigned int packed = (unsigned int)f_to_bfu(v0) | ((unsigned int)f_to_bfu(v1) << 16);
            ((unsigned int*)outp)[(long)node * P + lane] = packed;
        }
    } else {
        // head-mean via per-wave LDS staging
        s_acc[w][2 * lane] = acc00;
        s_acc[w][2 * lane + 1] = acc01;
        if (has2) {
            s_acc[w][128 + 2 * lane] = acc10;
            s_acc[w][129 + 2 * lane] = acc11;
        }
        __syncthreads();
        if (active && lane < OUTC) {
            float v = (s_acc[w][lane] + s_acc[w][lane + 47] + s_acc[w][lane + 94] +
                       s_acc[w][lane + 141]) * 0.25f +
                      bias[lane] + skip[(long)node * OUTC + lane];
            ((float*)outp)[(long)node * OUTC + lane] = v;
        }
    }
}

// ---------------------------------------------------------------------------
extern "C" void kernel_launch(void* const* d_in, const int* in_sizes, int n_in,
                              void* d_out, int out_size, void* d_ws, size_t ws_size,
                              hipStream_t stream) {
    const float* x        = (const float*)d_in[0];
    const int*   ei       = (const int*)d_in[1];
    const float* lin_w0   = (const float*)d_in[2];
    const float* att_src0 = (const float*)d_in[3];
    const float* att_dst0 = (const float*)d_in[4];
    const float* bias0    = (const float*)d_in[5];
    const float* skip_w0  = (const float*)d_in[6];
    const float* skip_b0  = (const float*)d_in[7];
    const float* lin_w1   = (const float*)d_in[8];
    const float* att_src1 = (const float*)d_in[9];
    const float* att_dst1 = (const float*)d_in[10];
    const float* bias1    = (const float*)d_in[11];
    const float* skip_w1  = (const float*)d_in[12];
    const float* skip_b1  = (const float*)d_in[13];
    const float* lin_w2   = (const float*)d_in[14];
    const float* att_src2 = (const float*)d_in[15];
    const float* att_dst2 = (const float*)d_in[16];
    const float* bias2    = (const float*)d_in[17];
    const float* skip_w2  = (const float*)d_in[18];
    const float* skip_b2  = (const float*)d_in[19];
    float* out = (float*)d_out;

    const int N = in_sizes[0] / KD;       // 50000
    const int E = in_sizes[1] / 2;        // 800000
    const int ET_ = E + N;                // with self loops
    const int NB = (N + 255) / 256;       // scan blocks (196 <= 1024)

    char* ws = (char*)d_ws;
    size_t off = 0;
    auto alloc = [&](size_t bytes) -> void* {
        void* p = ws + off;
        off = (off + bytes + 255) & ~(size_t)255;
        return p;
    };
    __bf16* xb     = (__bf16*)alloc((size_t)N * KD * 2);    // layer-0 A input (bf16)
    __bf16* xh     = (__bf16*)alloc((size_t)N * NF2 * 2);   // GAT linear output (bf16)
    __bf16* buf_bf = (__bf16*)alloc((size_t)N * HC * 2);    // ELU layer output (bf16)
    float* skip    = (float*)alloc((size_t)N * HC * 4);     // skip linear output (fp32)
    float* a_src   = (float*)alloc((size_t)N * 4 * 4);
    float* a_dst   = (float*)alloc((size_t)N * 4 * 4);
    int* deg       = (int*)alloc((size_t)N * 4);
    int* row_ptr   = (int*)alloc((size_t)(N + 1) * 4);
    int* fill      = (int*)alloc((size_t)N * 4);
    int* col       = (int*)alloc((size_t)ET_ * 4);
    int* bsums     = (int*)alloc((size_t)NB * 4);

    // ---- CSR build (dst-sorted adjacency, self-loops included) ----
    init_deg_kernel<<<(N + 255) / 256, 256, 0, stream>>>(deg, N);
    count_kernel<<<(E + 255) / 256, 256, 0, stream>>>(ei + E, deg, E);
    block_sum_kernel<<<NB, 256, 0, stream>>>(deg, bsums, N);
    scan_sums_kernel<<<1, 1024, 0, stream>>>(bsums, NB);
    write_ptr_kernel<<<NB, 256, 0, stream>>>(deg, bsums, row_ptr, fill, N);
    fill_kernel<<<(ET_ + 255) / 256, 256, 0, stream>>>(ei, fill, col, E, N);

    dim3 blk(256);
    int mblocks = (N + 127) / 128;
    dim3 g4(mblocks, 4);           // dual GEMM grids (2+2 or 3+1 column-blocks)
    int wave_blocks = (N + 3) / 4; // one wave per node, 4 waves/block

    // ---- layer 0 ----
    f2bf_kernel<<<(N * KD / 4 + 255) / 256, 256, 0, stream>>>(x, (unsigned short*)xb, N * KD / 4);
    gemm_dual_kernel<<<g4, blk, 0, stream>>>(xb, lin_w0, xh, HC, 2,
                                             skip_w0, skip_b0, skip, HC, N);
    att_kernel<HC, 32><<<wave_blocks, blk, 0, stream>>>(xh, att_src0, att_dst0, a_src, a_dst, N);
    agg_kernel<HC, 0><<<wave_blocks, blk, 0, stream>>>(xh, a_src, a_dst, skip, bias0,
                                                       row_ptr, col, buf_bf, N);
    // ---- layer 1 ----
    gemm_dual_kernel<<<g4, blk, 0, stream>>>(buf_bf, lin_w1, xh, HC, 2,
                                             skip_w1, skip_b1, skip, HC, N);
    att_kernel<HC, 32><<<wave_blocks, blk, 0, stream>>>(xh, att_src1, att_dst1, a_src, a_dst, N);
    agg_kernel<HC, 0><<<wave_blocks, blk, 0, stream>>>(xh, a_src, a_dst, skip, bias1,
                                                       row_ptr, col, buf_bf, N);
    // ---- layer 2 ----
    gemm_dual_kernel<<<g4, blk, 0, stream>>>(buf_bf, lin_w2, xh, NF2, 3,
                                             skip_w2, skip_b2, skip, OUTC, N);
    att_kernel<NF2, OUTC><<<wave_blocks, blk, 0, stream>>>(xh, att_src2, att_dst2, a_src, a_dst, N);
    agg_kernel<NF2, 1><<<wave_blocks, blk, 0, stream>>>(xh, a_src, a_dst, skip, bias2,
                                                        row_ptr, col, out, N);
}

// Round 5
// 552.940 us; speedup vs baseline: 1.6386x; 1.0670x over previous
//
#include <hip/hip_runtime.h>
#include <math.h>
#include <type_traits>

// Problem constants (fixed by reference)
#define KD 128      // K dim of every GEMM (IN = HC = 128)
#define HC 128      // H*C for layers 0/1
#define NF2 188     // H*OUT for layer 2
#define OUTC 47

typedef __attribute__((ext_vector_type(8))) __bf16 bf16x8;
typedef __attribute__((ext_vector_type(4))) float f32x4;

__device__ inline float bfhi_to_f(unsigned int u) {
    union { unsigned int u; float f; } c; c.u = u & 0xFFFF0000u; return c.f;
}
__device__ inline float bflo_to_f(unsigned int u) {
    union { unsigned int u; float f; } c; c.u = u << 16; return c.f;
}
__device__ inline unsigned short f_to_bfu(float f) {
    return __builtin_bit_cast(unsigned short, (__bf16)f);
}

// ---------------------------------------------------------------------------
// CSR build (4 dispatches)
// ---------------------------------------------------------------------------
__global__ void init_deg_kernel(int* deg, int* counter, int n) {
    int i = blockIdx.x * blockDim.x + threadIdx.x;
    if (i < n) deg[i] = 1;  // self-loop contributes 1
    if (i == 0) *counter = 0;
}

__global__ void count_kernel(const int* __restrict__ dst, int* deg, int e) {
    int i = blockIdx.x * blockDim.x + threadIdx.x;
    if (i < e) atomicAdd(&deg[dst[i]], 1);
}

// single-pass scan: per-block exclusive scan + atomic block base.
// row_ptr is NOT monotone across blocks; consumers use deg[] for segment end.
__global__ __launch_bounds__(256) void scan_base_kernel(
    const int* __restrict__ deg, int* counter,
    int* __restrict__ row_ptr, int* __restrict__ fill, int n) {
    int i = blockIdx.x * 256 + threadIdx.x;
    int v = (i < n) ? deg[i] : 0;
    int lane = threadIdx.x & 63, w = threadIdx.x >> 6;
    int incl = v;
#pragma unroll
    for (int off = 1; off < 64; off <<= 1) {
        int u = __shfl_up(incl, off, 64);
        if (lane >= off) incl += u;
    }
    __shared__ int wsum[4];
    __shared__ int base_sh;
    if (lane == 63) wsum[w] = incl;
    __syncthreads();
    if (threadIdx.x == 0)
        base_sh = atomicAdd(counter, wsum[0] + wsum[1] + wsum[2] + wsum[3]);
    int woff = 0;
    for (int k = 0; k < w; ++k) woff += wsum[k];
    __syncthreads();
    int excl = base_sh + woff + incl - v;
    if (i < n) { row_ptr[i] = excl; fill[i] = excl; }
}

__global__ void fill_kernel(const int* __restrict__ ei, int* fill, int* col, int e, int n) {
    int i = blockIdx.x * blockDim.x + threadIdx.x;
    if (i < e) {
        int d = ei[e + i];                 // dst
        int pos = atomicAdd(&fill[d], 1);
        col[pos] = ei[i];                  // src
    } else if (i < e + n) {
        int node = i - e;                  // self loop
        int pos = atomicAdd(&fill[node], 1);
        col[pos] = node;
    }
}

// ---------------------------------------------------------------------------
// Dual bf16 MFMA GEMM: from one A[M,128] (bf16 or fp32, converted in staging):
//   out0 = A @ B0            (bf16 store, no bias)   -- lin path
//   out1 = A @ B1 + bias1    (fp32 store)            -- skip path
// grid.y: [0, nb0) -> part 0, rest -> part 1. BM=128, BN=64, full K=128.
// ---------------------------------------------------------------------------
template <typename AT>
__global__ __launch_bounds__(256) void gemm_dual_kernel(
    const AT* __restrict__ A,
    const float* __restrict__ B0, __bf16* __restrict__ out0, int N0, int nb0,
    const float* __restrict__ B1, const float* __restrict__ bias1,
    float* __restrict__ out1, int N1, int M) {
    __shared__ __bf16 As[128][136];   // [m][k], +8 pad (16B-aligned rows)
    __shared__ __bf16 Bs[64][136];    // [n][k] (transposed)
    int tid = threadIdx.x;
    int m0 = blockIdx.x * 128;
    bool second = (int)blockIdx.y >= nb0;
    const float* B = second ? B1 : B0;
    int N = second ? N1 : N0;
    int n0 = (second ? (blockIdx.y - nb0) : blockIdx.y) * 64;

    // stage A: 128 rows x 128 elems, 16B LDS writes
#pragma unroll
    for (int rep = 0; rep < 8; ++rep) {
        int idx = tid + rep * 256;          // 0..2047
        int row = idx >> 4, seg = idx & 15; // 8-elem segment within row
        int gm = m0 + row;
        bf16x8 v = {};
        if (gm < M) {
            if constexpr (std::is_same<AT, float>::value) {
                const float* p = A + gm * KD + seg * 8;
                float4 f0 = *(const float4*)p;
                float4 f1 = *(const float4*)(p + 4);
                v[0] = (__bf16)f0.x; v[1] = (__bf16)f0.y; v[2] = (__bf16)f0.z; v[3] = (__bf16)f0.w;
                v[4] = (__bf16)f1.x; v[5] = (__bf16)f1.y; v[6] = (__bf16)f1.z; v[7] = (__bf16)f1.w;
            } else {
                v = *(const bf16x8*)(A + gm * KD + seg * 8);
            }
        }
        *(bf16x8*)&As[row][seg * 8] = v;
    }
    // stage B transposed via coalesced row reads + 16B LDS writes
#pragma unroll
    for (int rep = 0; rep < 4; ++rep) {
        int idx = tid + rep * 256;          // 0..1023
        int n = idx & 63, seg = idx >> 6;   // seg 0..15 (8 k's each)
        bf16x8 v = {};
        if (n0 + n < N) {
#pragma unroll
            for (int i = 0; i < 8; ++i) v[i] = (__bf16)B[(seg * 8 + i) * N + n0 + n];
        }
        *(bf16x8*)&Bs[n][seg * 8] = v;
    }
    __syncthreads();

    int w = tid >> 6, lane = tid & 63;
    int lr = lane & 15, quad = lane >> 4;
    f32x4 acc[2][4] = {};
#pragma unroll
    for (int kc = 0; kc < 128; kc += 32) {
        bf16x8 a0 = *(const bf16x8*)&As[w * 32 + lr][kc + quad * 8];
        bf16x8 a1 = *(const bf16x8*)&As[w * 32 + 16 + lr][kc + quad * 8];
        bf16x8 b0 = *(const bf16x8*)&Bs[lr][kc + quad * 8];
        bf16x8 b1 = *(const bf16x8*)&Bs[16 + lr][kc + quad * 8];
        bf16x8 b2 = *(const bf16x8*)&Bs[32 + lr][kc + quad * 8];
        bf16x8 b3 = *(const bf16x8*)&Bs[48 + lr][kc + quad * 8];
        acc[0][0] = __builtin_amdgcn_mfma_f32_16x16x32_bf16(a0, b0, acc[0][0], 0, 0, 0);
        acc[0][1] = __builtin_amdgcn_mfma_f32_16x16x32_bf16(a0, b1, acc[0][1], 0, 0, 0);
        acc[0][2] = __builtin_amdgcn_mfma_f32_16x16x32_bf16(a0, b2, acc[0][2], 0, 0, 0);
        acc[0][3] = __builtin_amdgcn_mfma_f32_16x16x32_bf16(a0, b3, acc[0][3], 0, 0, 0);
        acc[1][0] = __builtin_amdgcn_mfma_f32_16x16x32_bf16(a1, b0, acc[1][0], 0, 0, 0);
        acc[1][1] = __builtin_amdgcn_mfma_f32_16x16x32_bf16(a1, b1, acc[1][1], 0, 0, 0);
        acc[1][2] = __builtin_amdgcn_mfma_f32_16x16x32_bf16(a1, b2, acc[1][2], 0, 0, 0);
        acc[1][3] = __builtin_amdgcn_mfma_f32_16x16x32_bf16(a1, b3, acc[1][3], 0, 0, 0);
    }
    // epilogue: C/D layout col=lane&15, row=quad*4+reg
#pragma unroll
    for (int r = 0; r < 2; ++r) {
#pragma unroll
        for (int c = 0; c < 4; ++c) {
#pragma unroll
            for (int reg = 0; reg < 4; ++reg) {
                int row = m0 + w * 32 + r * 16 + quad * 4 + reg;
                int colg = n0 + c * 16 + lr;
                if (row < M && colg < N) {
                    float v = acc[r][c][reg];
                    if (second) {
                        if (bias1) v += bias1[colg];
                        out1[row * N + colg] = v;
                    } else {
                        out0[row * N + colg] = (__bf16)v;
                    }
                }
            }
        }
    }
}

// ---------------------------------------------------------------------------
// a_src[n,h] = sum_c xh[n,h*C+c]*att_s[h*C+c]; same for a_dst. One wave/node.
// ---------------------------------------------------------------------------
template <int NF, int C>
__global__ __launch_bounds__(256) void att_kernel(
    const __bf16* __restrict__ xh, const float* __restrict__ att_s,
    const float* __restrict__ att_d, float* __restrict__ a_src,
    float* __restrict__ a_dst, int n) {
    int node = (blockIdx.x * blockDim.x + threadIdx.x) >> 6;
    int lane = threadIdx.x & 63;
    if (node >= n) return;
    constexpr int NR = (NF + 63) / 64;
    float hs[4] = {0.f, 0.f, 0.f, 0.f};
    float hd[4] = {0.f, 0.f, 0.f, 0.f};
#pragma unroll
    for (int r = 0; r < NR; ++r) {
        int f = lane + 64 * r;
        if (f < NF) {
            float x = (float)xh[node * NF + f];
            float ps = x * att_s[f];
            float pd = x * att_d[f];
            int h = f / C;
            if (h == 0)      { hs[0] += ps; hd[0] += pd; }
            else if (h == 1) { hs[1] += ps; hd[1] += pd; }
            else if (h == 2) { hs[2] += ps; hd[2] += pd; }
            else             { hs[3] += ps; hd[3] += pd; }
        }
    }
#pragma unroll
    for (int off = 32; off >= 1; off >>= 1) {
#pragma unroll
        for (int h = 0; h < 4; ++h) {
            hs[h] += __shfl_xor(hs[h], off, 64);
            hd[h] += __shfl_xor(hd[h], off, 64);
        }
    }
    if (lane == 0) {
        *(float4*)(a_src + 4 * node) = make_float4(hs[0], hs[1], hs[2], hs[3]);
        *(float4*)(a_dst + 4 * node) = make_float4(hd[0], hd[1], hd[2], hd[3]);
    }
}

// ---------------------------------------------------------------------------
// Aggregation: one wave per destination node. All 32-bit indexing.
// Pass A: online softmax stats + chunk-0 logit capture.
// Pass B: owner lane publishes alphas+src to LDS; wave gathers xh rows.
// MODE 0 (NF=128): lane loads uint (2 feats, one head), out bf16 +skip+ELU.
// MODE 1 (NF=188): lane<47 loads uint2 (4 feats), head-select via cndmask,
//                  head-mean via LDS, out fp32.
// ---------------------------------------------------------------------------
template <int NF, int MODE>
__global__ __launch_bounds__(256) void agg_kernel(
    const __bf16* __restrict__ xh, const float* __restrict__ a_src,
    const float* __restrict__ a_dst, const float* __restrict__ skip,
    const float* __restrict__ bias, const int* __restrict__ row_ptr,
    const int* __restrict__ deg, const int* __restrict__ col,
    void* __restrict__ outp, int n) {
    __shared__ float s_alpha[4][64][4];
    __shared__ int s_j[4][64];
    __shared__ float s_acc[4][192];    // MODE 1 head-mean staging (16B-aligned rows)
    int w = threadIdx.x >> 6;
    int lane = threadIdx.x & 63;
    int node = (blockIdx.x << 2) + w;
    bool active = node < n;
    int node_c = active ? node : 0;
    int start = row_ptr[node_c];
    int end = start + (active ? deg[node_c] : 0);
    float4 ad4 = *(const float4*)(a_dst + 4 * node_c);
    float adh[4] = {ad4.x, ad4.y, ad4.z, ad4.w};

    // ---- pass A (+ chunk-0 capture) ----
    int e0 = start + lane;
    bool ok0 = e0 < end;
    int jcap = ok0 ? col[e0] : 0;
    float evc[4];
    {
        float4 as4 = *(const float4*)(a_src + 4 * jcap);
        float v0 = as4.x + adh[0]; evc[0] = v0 > 0.f ? v0 : 0.2f * v0;
        float v1 = as4.y + adh[1]; evc[1] = v1 > 0.f ? v1 : 0.2f * v1;
        float v2 = as4.z + adh[2]; evc[2] = v2 > 0.f ? v2 : 0.2f * v2;
        float v3 = as4.w + adh[3]; evc[3] = v3 > 0.f ? v3 : 0.2f * v3;
    }
    float m[4], s[4];
#pragma unroll
    for (int h = 0; h < 4; ++h) {
        m[h] = ok0 ? evc[h] : -1e30f;
        s[h] = ok0 ? 1.f : 0.f;
    }
    for (int e = e0 + 64; e < end; e += 64) {
        int j = col[e];
        float4 as4 = *(const float4*)(a_src + 4 * j);
        float ev[4] = {as4.x + adh[0], as4.y + adh[1], as4.z + adh[2], as4.w + adh[3]};
#pragma unroll
        for (int h = 0; h < 4; ++h) {
            float v = ev[h] > 0.f ? ev[h] : 0.2f * ev[h];
            float M = fmaxf(m[h], v);
            s[h] = s[h] * __expf(m[h] - M) + __expf(v - M);
            m[h] = M;
        }
    }
#pragma unroll
    for (int off = 32; off >= 1; off >>= 1) {
#pragma unroll
        for (int h = 0; h < 4; ++h) {
            float m2 = __shfl_xor(m[h], off, 64);
            float s2 = __shfl_xor(s[h], off, 64);
            float M = fmaxf(m[h], m2);
            s[h] = s[h] * __expf(m[h] - M) + s2 * __expf(m2 - M);
            m[h] = M;
        }
    }
    float inv[4];
#pragma unroll
    for (int h = 0; h < 4; ++h) inv[h] = 1.f / (s[h] + 1e-16f);

    // ---- pass B bookkeeping ----
    int myh = lane >> 4;                         // MODE 0: head of feats 2l,2l+1
    // MODE 1: lane<47 owns feats 4l..4l+3
    int hA = (4 * lane) / 47; if (hA > 3) hA = 3;
    int hB = (4 * lane + 3) / 47; if (hB > 3) hB = 3;
    bool sel1 = ((4 * lane + 1) / 47) != hA;
    bool sel2 = ((4 * lane + 2) / 47) != hA;
    // feat 4l+0 always head hA; feat 4l+3 always head hB
    float acc0 = 0.f, acc1 = 0.f, acc2 = 0.f, acc3 = 0.f;

    auto run_chunk = [&](int cnt) {
        int t = 0;
        if (MODE == 0) {
            const unsigned int* xb = (const unsigned int*)xh;
            for (; t + 3 < cnt; t += 4) {
                int j0 = s_j[w][t], j1 = s_j[w][t + 1], j2 = s_j[w][t + 2], j3 = s_j[w][t + 3];
                unsigned int q0 = xb[(j0 << 6) + lane];
                unsigned int q1 = xb[(j1 << 6) + lane];
                unsigned int q2 = xb[(j2 << 6) + lane];
                unsigned int q3 = xb[(j3 << 6) + lane];
                float a0 = s_alpha[w][t][myh], a1 = s_alpha[w][t + 1][myh];
                float a2 = s_alpha[w][t + 2][myh], a3 = s_alpha[w][t + 3][myh];
                acc0 += a0 * bflo_to_f(q0); acc1 += a0 * bfhi_to_f(q0);
                acc2 += a1 * bflo_to_f(q1); acc3 += a1 * bfhi_to_f(q1);
                acc0 += a2 * bflo_to_f(q2); acc1 += a2 * bfhi_to_f(q2);
                acc2 += a3 * bflo_to_f(q3); acc3 += a3 * bfhi_to_f(q3);
            }
            for (; t < cnt; ++t) {
                int j = s_j[w][t];
                unsigned int q = xb[(j << 6) + lane];
                float a = s_alpha[w][t][myh];
                acc0 += a * bflo_to_f(q); acc1 += a * bfhi_to_f(q);
            }
        } else {
            const uint2* xb2 = (const uint2*)xh;
            for (; t + 3 < cnt; t += 4) {
                int j0 = s_j[w][t], j1 = s_j[w][t + 1], j2 = s_j[w][t + 2], j3 = s_j[w][t + 3];
                uint2 q0 = xb2[j0 * 47 + lane];
                uint2 q1 = xb2[j1 * 47 + lane];
                uint2 q2 = xb2[j2 * 47 + lane];
                uint2 q3 = xb2[j3 * 47 + lane];
#pragma unroll
                for (int u = 0; u < 4; ++u) {
                    uint2 q = (u == 0) ? q0 : (u == 1) ? q1 : (u == 2) ? q2 : q3;
                    float aA = s_alpha[w][t + u][hA];
                    float aB = s_alpha[w][t + u][hB];
                    acc0 += aA * bflo_to_f(q.x);
                    acc1 += (sel1 ? aB : aA) * bfhi_to_f(q.x);
                    acc2 += (sel2 ? aB : aA) * bflo_to_f(q.y);
                    acc3 += aB * bfhi_to_f(q.y);
                }
            }
            for (; t < cnt; ++t) {
                int j = s_j[w][t];
                uint2 q = xb2[j * 47 + lane];
                float aA = s_alpha[w][t][hA];
                float aB = s_alpha[w][t][hB];
                acc0 += aA * bflo_to_f(q.x);
                acc1 += (sel1 ? aB : aA) * bfhi_to_f(q.x);
                acc2 += (sel2 ? aB : aA) * bflo_to_f(q.y);
                acc3 += aB * bfhi_to_f(q.y);
            }
        }
    };

    // chunk 0: reuse captured logits, no col/a_src reload
    {
        float al[4];
#pragma unroll
        for (int h = 0; h < 4; ++h)
            al[h] = ok0 ? __expf(evc[h] - m[h]) * inv[h] : 0.f;
        s_j[w][lane] = jcap;
        *(float4*)&s_alpha[w][lane][0] = make_float4(al[0], al[1], al[2], al[3]);
        int cnt = end - start; if (cnt > 64) cnt = 64;
        run_chunk(cnt);
    }
    // remaining chunks (deg > 64: rare)
    for (int base = start + 64; base < end; base += 64) {
        int e = base + lane;
        bool ok = e < end;
        int jv = ok ? col[e] : 0;
        float4 as4 = *(const float4*)(a_src + 4 * jv);
        float asv[4] = {as4.x, as4.y, as4.z, as4.w};
        float al[4];
#pragma unroll
        for (int h = 0; h < 4; ++h) {
            float ev = asv[h] + adh[h];
            ev = ev > 0.f ? ev : 0.2f * ev;
            al[h] = ok ? __expf(ev - m[h]) * inv[h] : 0.f;
        }
        s_j[w][lane] = jv;
        *(float4*)&s_alpha[w][lane][0] = make_float4(al[0], al[1], al[2], al[3]);
        int cnt = end - base; if (cnt > 64) cnt = 64;
        run_chunk(cnt);
    }

    if constexpr (MODE == 0) {
        float v0 = acc0 + acc2, v1 = acc1 + acc3;
        if (active) {
            float2 bb = *(const float2*)(bias + 2 * lane);
            float2 sk = *(const float2*)(skip + (node << 7) + 2 * lane);
            v0 += bb.x + sk.x;
            v1 += bb.y + sk.y;
            v0 = v0 > 0.f ? v0 : (__expf(v0) - 1.f);   // ELU
            v1 = v1 > 0.f ? v1 : (__expf(v1) - 1.f);
            unsigned int packed = (unsigned int)f_to_bfu(v0) | ((unsigned int)f_to_bfu(v1) << 16);
            ((unsigned int*)outp)[(node << 6) + lane] = packed;
        }
    } else {
        // head-mean via per-wave LDS staging
        if (lane < 47)
            *(float4*)&s_acc[w][4 * lane] = make_float4(acc0, acc1, acc2, acc3);
        __syncthreads();
        if (active && lane < OUTC) {
            float v = (s_acc[w][lane] + s_acc[w][lane + 47] + s_acc[w][lane + 94] +
                       s_acc[w][lane + 141]) * 0.25f +
                      bias[lane] + skip[node * OUTC + lane];
            ((float*)outp)[node * OUTC + lane] = v;
        }
    }
}

// ---------------------------------------------------------------------------
extern "C" void kernel_launch(void* const* d_in, const int* in_sizes, int n_in,
                              void* d_out, int out_size, void* d_ws, size_t ws_size,
                              hipStream_t stream) {
    const float* x        = (const float*)d_in[0];
    const int*   ei       = (const int*)d_in[1];
    const float* lin_w0   = (const float*)d_in[2];
    const float* att_src0 = (const float*)d_in[3];
    const float* att_dst0 = (const float*)d_in[4];
    const float* bias0    = (const float*)d_in[5];
    const float* skip_w0  = (const float*)d_in[6];
    const float* skip_b0  = (const float*)d_in[7];
    const float* lin_w1   = (const float*)d_in[8];
    const float* att_src1 = (const float*)d_in[9];
    const float* att_dst1 = (const float*)d_in[10];
    const float* bias1    = (const float*)d_in[11];
    const float* skip_w1  = (const float*)d_in[12];
    const float* skip_b1  = (const float*)d_in[13];
    const float* lin_w2   = (const float*)d_in[14];
    const float* att_src2 = (const float*)d_in[15];
    const float* att_dst2 = (const float*)d_in[16];
    const float* bias2    = (const float*)d_in[17];
    const float* skip_w2  = (const float*)d_in[18];
    const float* skip_b2  = (const float*)d_in[19];
    float* out = (float*)d_out;

    const int N = in_sizes[0] / KD;       // 50000
    const int E = in_sizes[1] / 2;        // 800000
    const int ET_ = E + N;                // with self loops

    char* ws = (char*)d_ws;
    size_t off = 0;
    auto alloc = [&](size_t bytes) -> void* {
        void* p = ws + off;
        off = (off + bytes + 255) & ~(size_t)255;
        return p;
    };
    __bf16* xh     = (__bf16*)alloc((size_t)N * NF2 * 2);   // GAT linear output (bf16)
    __bf16* buf_bf = (__bf16*)alloc((size_t)N * HC * 2);    // ELU layer output (bf16)
    float* skip    = (float*)alloc((size_t)N * HC * 4);     // skip linear output (fp32)
    float* a_src   = (float*)alloc((size_t)N * 4 * 4);
    float* a_dst   = (float*)alloc((size_t)N * 4 * 4);
    int* deg       = (int*)alloc((size_t)N * 4);
    int* row_ptr   = (int*)alloc((size_t)N * 4);
    int* fill      = (int*)alloc((size_t)N * 4);
    int* col       = (int*)alloc((size_t)ET_ * 4);
    int* counter   = (int*)alloc(256);

    // ---- CSR build (dst-sorted adjacency, self-loops included) ----
    init_deg_kernel<<<(N + 255) / 256, 256, 0, stream>>>(deg, counter, N);
    count_kernel<<<(E + 255) / 256, 256, 0, stream>>>(ei + E, deg, E);
    scan_base_kernel<<<(N + 255) / 256, 256, 0, stream>>>(deg, counter, row_ptr, fill, N);
    fill_kernel<<<(ET_ + 255) / 256, 256, 0, stream>>>(ei, fill, col, E, N);

    dim3 blk(256);
    int mblocks = (N + 127) / 128;
    dim3 g4(mblocks, 4);           // dual GEMM grids (2+2 or 3+1 column-blocks)
    int wave_blocks = (N + 3) / 4; // one wave per node, 4 waves/block

    // ---- layer 0 (A = fp32 x, converted in staging) ----
    gemm_dual_kernel<float><<<g4, blk, 0, stream>>>(x, lin_w0, xh, HC, 2,
                                                    skip_w0, skip_b0, skip, HC, N);
    att_kernel<HC, 32><<<wave_blocks, blk, 0, stream>>>(xh, att_src0, att_dst0, a_src, a_dst, N);
    agg_kernel<HC, 0><<<wave_blocks, blk, 0, stream>>>(xh, a_src, a_dst, skip, bias0,
                                                       row_ptr, deg, col, buf_bf, N);
    // ---- layer 1 ----
    gemm_dual_kernel<__bf16><<<g4, blk, 0, stream>>>(buf_bf, lin_w1, xh, HC, 2,
                                                     skip_w1, skip_b1, skip, HC, N);
    att_kernel<HC, 32><<<wave_blocks, blk, 0, stream>>>(xh, att_src1, att_dst1, a_src, a_dst, N);
    agg_kernel<HC, 0><<<wave_blocks, blk, 0, stream>>>(xh, a_src, a_dst, skip, bias1,
                                                       row_ptr, deg, col, buf_bf, N);
    // ---- layer 2 ----
    gemm_dual_kernel<__bf16><<<g4, blk, 0, stream>>>(buf_bf, lin_w2, xh, NF2, 3,
                                                     skip_w2, skip_b2, skip, OUTC, N);
    att_kernel<NF2, OUTC><<<wave_blocks, blk, 0, stream>>>(xh, att_src2, att_dst2, a_src, a_dst, N);
    agg_kernel<NF2, 1><<<wave_blocks, blk, 0, stream>>>(xh, a_src, a_dst, skip, bias2,
                                                        row_ptr, deg, col, out, N);
}

// Round 6
// 514.296 us; speedup vs baseline: 1.7617x; 1.0751x over previous
//
#include <hip/hip_runtime.h>
#include <math.h>
#include <type_traits>

// Problem constants (fixed by reference)
#define KD 128      // K dim of every GEMM (IN = HC = 128)
#define HC 128      // H*C for layers 0/1
#define NF2 188     // H*OUT for layer 2
#define NF2P 192    // padded layer-2 feature stride (6 cachelines)
#define OUTC 47

typedef __attribute__((ext_vector_type(8))) __bf16 bf16x8;
typedef __attribute__((ext_vector_type(2))) __bf16 bf16x2;
typedef __attribute__((ext_vector_type(4))) float f32x4;

#ifdef __has_builtin
#if __has_builtin(__builtin_amdgcn_fdot2_f32_bf16)
#define HAVE_FDOT2 1
#endif
#endif

__device__ inline float bfhi_to_f(unsigned int u) {
    union { unsigned int u; float f; } c; c.u = u & 0xFFFF0000u; return c.f;
}
__device__ inline float bflo_to_f(unsigned int u) {
    union { unsigned int u; float f; } c; c.u = u << 16; return c.f;
}
__device__ inline unsigned short f_to_bfu(float f) {
    return __builtin_bit_cast(unsigned short, (__bf16)f);
}
__device__ inline unsigned int pk_bf(float a, float b) {
    return (unsigned int)f_to_bfu(a) | ((unsigned int)f_to_bfu(b) << 16);
}
// acc += dot(q, ab) over 4 packed bf16 pairs
__device__ inline float dot2pair(uint2 q, uint2 ab, float acc) {
#ifdef HAVE_FDOT2
    acc = __builtin_amdgcn_fdot2_f32_bf16(__builtin_bit_cast(bf16x2, q.x),
                                          __builtin_bit_cast(bf16x2, ab.x), acc, false);
    acc = __builtin_amdgcn_fdot2_f32_bf16(__builtin_bit_cast(bf16x2, q.y),
                                          __builtin_bit_cast(bf16x2, ab.y), acc, false);
#else
    acc += bflo_to_f(q.x) * bflo_to_f(ab.x) + bfhi_to_f(q.x) * bfhi_to_f(ab.x);
    acc += bflo_to_f(q.y) * bflo_to_f(ab.y) + bfhi_to_f(q.y) * bfhi_to_f(ab.y);
#endif
    return acc;
}

// ---------------------------------------------------------------------------
// CSR build (4 dispatches)
// ---------------------------------------------------------------------------
__global__ void init_deg_kernel(int* deg, int* counter, int n) {
    int i = blockIdx.x * blockDim.x + threadIdx.x;
    if (i < n) deg[i] = 1;  // self-loop contributes 1
    if (i == 0) *counter = 0;
}

__global__ void count_kernel(const int* __restrict__ dst, int* deg, int e) {
    int i = blockIdx.x * blockDim.x + threadIdx.x;
    if (i < e) atomicAdd(&deg[dst[i]], 1);
}

// single-pass scan: per-block exclusive scan + atomic block base.
// row_ptr is NOT monotone across blocks; consumers use deg[] for segment end.
__global__ __launch_bounds__(256) void scan_base_kernel(
    const int* __restrict__ deg, int* counter,
    int* __restrict__ row_ptr, int* __restrict__ fill, int n) {
    int i = blockIdx.x * 256 + threadIdx.x;
    int v = (i < n) ? deg[i] : 0;
    int lane = threadIdx.x & 63, w = threadIdx.x >> 6;
    int incl = v;
#pragma unroll
    for (int off = 1; off < 64; off <<= 1) {
        int u = __shfl_up(incl, off, 64);
        if (lane >= off) incl += u;
    }
    __shared__ int wsum[4];
    __shared__ int base_sh;
    if (lane == 63) wsum[w] = incl;
    __syncthreads();
    if (threadIdx.x == 0)
        base_sh = atomicAdd(counter, wsum[0] + wsum[1] + wsum[2] + wsum[3]);
    int woff = 0;
    for (int k = 0; k < w; ++k) woff += wsum[k];
    __syncthreads();
    int excl = base_sh + woff + incl - v;
    if (i < n) { row_ptr[i] = excl; fill[i] = excl; }
}

__global__ void fill_kernel(const int* __restrict__ ei, int* fill, int* col, int e, int n) {
    int i = blockIdx.x * blockDim.x + threadIdx.x;
    if (i < e) {
        int d = ei[e + i];                 // dst
        int pos = atomicAdd(&fill[d], 1);
        col[pos] = ei[i];                  // src
    } else if (i < e + n) {
        int node = i - e;                  // self loop
        int pos = atomicAdd(&fill[node], 1);
        col[pos] = node;
    }
}

// ---------------------------------------------------------------------------
// Dual bf16 MFMA GEMM: from one A[M,128] (bf16 or fp32, converted in staging):
//   out0 = A @ B0 (bf16 store, no bias, row stride ldc0; tr0 -> head-interleave)
//   out1 = A @ B1 + bias1 (fp32 store)
// grid.y: [0, nb0) -> part 0, rest -> part 1. BM=128, BN=64, full K=128.
// ---------------------------------------------------------------------------
template <typename AT>
__global__ __launch_bounds__(256) void gemm_dual_kernel(
    const AT* __restrict__ A,
    const float* __restrict__ B0, __bf16* __restrict__ out0, int N0, int ldc0,
    int tr0, int nb0,
    const float* __restrict__ B1, const float* __restrict__ bias1,
    float* __restrict__ out1, int N1, int M) {
    __shared__ __bf16 As[128][136];   // [m][k], +8 pad (16B-aligned rows)
    __shared__ __bf16 Bs[64][136];    // [n][k] (transposed)
    int tid = threadIdx.x;
    int m0 = blockIdx.x * 128;
    bool second = (int)blockIdx.y >= nb0;
    const float* B = second ? B1 : B0;
    int N = second ? N1 : N0;
    int n0 = (second ? (blockIdx.y - nb0) : blockIdx.y) * 64;

    // stage A: 128 rows x 128 elems, 16B LDS writes
#pragma unroll
    for (int rep = 0; rep < 8; ++rep) {
        int idx = tid + rep * 256;          // 0..2047
        int row = idx >> 4, seg = idx & 15; // 8-elem segment within row
        int gm = m0 + row;
        bf16x8 v = {};
        if (gm < M) {
            if constexpr (std::is_same<AT, float>::value) {
                const float* p = A + gm * KD + seg * 8;
                float4 f0 = *(const float4*)p;
                float4 f1 = *(const float4*)(p + 4);
                v[0] = (__bf16)f0.x; v[1] = (__bf16)f0.y; v[2] = (__bf16)f0.z; v[3] = (__bf16)f0.w;
                v[4] = (__bf16)f1.x; v[5] = (__bf16)f1.y; v[6] = (__bf16)f1.z; v[7] = (__bf16)f1.w;
            } else {
                v = *(const bf16x8*)(A + gm * KD + seg * 8);
            }
        }
        *(bf16x8*)&As[row][seg * 8] = v;
    }
    // stage B transposed via coalesced row reads + 16B LDS writes
#pragma unroll
    for (int rep = 0; rep < 4; ++rep) {
        int idx = tid + rep * 256;          // 0..1023
        int n = idx & 63, seg = idx >> 6;   // seg 0..15 (8 k's each)
        bf16x8 v = {};
        if (n0 + n < N) {
#pragma unroll
            for (int i = 0; i < 8; ++i) v[i] = (__bf16)B[(seg * 8 + i) * N + n0 + n];
        }
        *(bf16x8*)&Bs[n][seg * 8] = v;
    }
    __syncthreads();

    int w = tid >> 6, lane = tid & 63;
    int lr = lane & 15, quad = lane >> 4;
    f32x4 acc[2][4] = {};
#pragma unroll
    for (int kc = 0; kc < 128; kc += 32) {
        bf16x8 a0 = *(const bf16x8*)&As[w * 32 + lr][kc + quad * 8];
        bf16x8 a1 = *(const bf16x8*)&As[w * 32 + 16 + lr][kc + quad * 8];
        bf16x8 b0 = *(const bf16x8*)&Bs[lr][kc + quad * 8];
        bf16x8 b1 = *(const bf16x8*)&Bs[16 + lr][kc + quad * 8];
        bf16x8 b2 = *(const bf16x8*)&Bs[32 + lr][kc + quad * 8];
        bf16x8 b3 = *(const bf16x8*)&Bs[48 + lr][kc + quad * 8];
        acc[0][0] = __builtin_amdgcn_mfma_f32_16x16x32_bf16(a0, b0, acc[0][0], 0, 0, 0);
        acc[0][1] = __builtin_amdgcn_mfma_f32_16x16x32_bf16(a0, b1, acc[0][1], 0, 0, 0);
        acc[0][2] = __builtin_amdgcn_mfma_f32_16x16x32_bf16(a0, b2, acc[0][2], 0, 0, 0);
        acc[0][3] = __builtin_amdgcn_mfma_f32_16x16x32_bf16(a0, b3, acc[0][3], 0, 0, 0);
        acc[1][0] = __builtin_amdgcn_mfma_f32_16x16x32_bf16(a1, b0, acc[1][0], 0, 0, 0);
        acc[1][1] = __builtin_amdgcn_mfma_f32_16x16x32_bf16(a1, b1, acc[1][1], 0, 0, 0);
        acc[1][2] = __builtin_amdgcn_mfma_f32_16x16x32_bf16(a1, b2, acc[1][2], 0, 0, 0);
        acc[1][3] = __builtin_amdgcn_mfma_f32_16x16x32_bf16(a1, b3, acc[1][3], 0, 0, 0);
    }
    // epilogue: C/D layout col=lane&15, row=quad*4+reg
#pragma unroll
    for (int r = 0; r < 2; ++r) {
#pragma unroll
        for (int c = 0; c < 4; ++c) {
#pragma unroll
            for (int reg = 0; reg < 4; ++reg) {
                int row = m0 + w * 32 + r * 16 + quad * 4 + reg;
                int colg = n0 + c * 16 + lr;
                if (row < M && colg < N) {
                    float v = acc[r][c][reg];
                    if (second) {
                        if (bias1) v += bias1[colg];
                        out1[row * N + colg] = v;
                    } else {
                        int idx;
                        if (tr0) {  // head-interleave: feat = oc*4 + h
                            int h = (colg * 1395) >> 16;   // colg / 47 for colg<188
                            idx = row * ldc0 + (colg - 47 * h) * 4 + h;
                        } else {
                            idx = row * ldc0 + colg;
                        }
                        out0[idx] = (__bf16)v;
                    }
                }
            }
        }
    }
}

// ---------------------------------------------------------------------------
// att for layers 0/1: a_src[n,h] = sum_c xh[n,h*32+c]*att_s[h*32+c]. One wave/node.
// ---------------------------------------------------------------------------
__global__ __launch_bounds__(256) void att_kernel(
    const __bf16* __restrict__ xh, const float* __restrict__ att_s,
    const float* __restrict__ att_d, float* __restrict__ a_src,
    float* __restrict__ a_dst, int n) {
    int node = (blockIdx.x * blockDim.x + threadIdx.x) >> 6;
    int lane = threadIdx.x & 63;
    if (node >= n) return;
    float hs[4] = {0.f, 0.f, 0.f, 0.f};
    float hd[4] = {0.f, 0.f, 0.f, 0.f};
#pragma unroll
    for (int r = 0; r < 2; ++r) {
        int f = lane + 64 * r;
        float x = (float)xh[node * HC + f];
        float ps = x * att_s[f];
        float pd = x * att_d[f];
        int h = f >> 5;
        if (h == 0)      { hs[0] += ps; hd[0] += pd; }
        else if (h == 1) { hs[1] += ps; hd[1] += pd; }
        else if (h == 2) { hs[2] += ps; hd[2] += pd; }
        else             { hs[3] += ps; hd[3] += pd; }
    }
#pragma unroll
    for (int off = 32; off >= 1; off >>= 1) {
#pragma unroll
        for (int h = 0; h < 4; ++h) {
            hs[h] += __shfl_xor(hs[h], off, 64);
            hd[h] += __shfl_xor(hd[h], off, 64);
        }
    }
    if (lane == 0) {
        *(float4*)(a_src + 4 * node) = make_float4(hs[0], hs[1], hs[2], hs[3]);
        *(float4*)(a_dst + 4 * node) = make_float4(hd[0], hd[1], hd[2], hd[3]);
    }
}

// ---------------------------------------------------------------------------
// att for layer 2 (head-interleaved xh, stride 192): feat f -> h=f&3, c=f>>2.
// Each lane owns one head class (lane&3); reduce via xor 4,8,16,32.
// ---------------------------------------------------------------------------
__global__ __launch_bounds__(256) void att2_kernel(
    const __bf16* __restrict__ xh, const float* __restrict__ att_s,
    const float* __restrict__ att_d, float* __restrict__ a_src,
    float* __restrict__ a_dst, int n) {
    int node = (blockIdx.x * blockDim.x + threadIdx.x) >> 6;
    int lane = threadIdx.x & 63;
    if (node >= n) return;
    int h = lane & 3;
    float hs = 0.f, hd = 0.f;
#pragma unroll
    for (int r = 0; r < 3; ++r) {
        int f = lane + 64 * r;
        if (f < NF2) {
            float x = (float)xh[node * NF2P + f];
            int c = f >> 2;
            hs += x * att_s[h * 47 + c];
            hd += x * att_d[h * 47 + c];
        }
    }
#pragma unroll
    for (int off = 4; off <= 32; off <<= 1) {
        hs += __shfl_xor(hs, off, 64);
        hd += __shfl_xor(hd, off, 64);
    }
    if (lane < 4) {
        a_src[node * 4 + lane] = hs;
        a_dst[node * 4 + lane] = hd;
    }
}

// ---------------------------------------------------------------------------
// Aggregation: one wave per destination node. 32-bit indexing.
// Pass A: online softmax stats + chunk-0 logit capture; max/rescale/sum reduce.
// MODE 0 (NF=128): 2 edges/iter, half-wave per edge, uint2 (4 feats)/lane;
//                  shfl(32) combine; out bf16 +bias+skip+ELU.
// MODE 1 (NF2P=192 head-interleaved): lane c<48 loads uint2 = 4 heads of
//                  channel c; packed-bf16 alphas; v_dot2 accumulate;
//                  out[c] = acc*0.25 + bias + skip (fp32), no staging.
// ---------------------------------------------------------------------------
template <int MODE>
__global__ __launch_bounds__(256) void agg_kernel(
    const __bf16* __restrict__ xh, const float* __restrict__ a_src,
    const float* __restrict__ a_dst, const float* __restrict__ skip,
    const float* __restrict__ bias, const int* __restrict__ row_ptr,
    const int* __restrict__ deg, const int* __restrict__ col,
    void* __restrict__ outp, int n) {
    __shared__ float s_af[4][64][4];   // MODE 0 alphas (f32)
    __shared__ uint2 s_ab[4][64];      // MODE 1 alphas (packed bf16: a0a1, a2a3)
    __shared__ int s_j[4][64];
    int w = threadIdx.x >> 6;
    int lane = threadIdx.x & 63;
    int node = (blockIdx.x << 2) + w;
    bool active = node < n;
    int node_c = active ? node : 0;
    int start = row_ptr[node_c];
    int end = start + (active ? deg[node_c] : 0);
    float4 ad4 = *(const float4*)(a_dst + 4 * node_c);
    float adh[4] = {ad4.x, ad4.y, ad4.z, ad4.w};

    // ---- pass A (+ chunk-0 capture) ----
    int e0 = start + lane;
    bool ok0 = e0 < end;
    int jcap = ok0 ? col[e0] : 0;
    float evc[4];
    {
        float4 as4 = *(const float4*)(a_src + 4 * jcap);
        float v0 = as4.x + adh[0]; evc[0] = v0 > 0.f ? v0 : 0.2f * v0;
        float v1 = as4.y + adh[1]; evc[1] = v1 > 0.f ? v1 : 0.2f * v1;
        float v2 = as4.z + adh[2]; evc[2] = v2 > 0.f ? v2 : 0.2f * v2;
        float v3 = as4.w + adh[3]; evc[3] = v3 > 0.f ? v3 : 0.2f * v3;
    }
    float m[4], s[4];
#pragma unroll
    for (int h = 0; h < 4; ++h) {
        m[h] = ok0 ? evc[h] : -1e30f;
        s[h] = ok0 ? 1.f : 0.f;
    }
    for (int e = e0 + 64; e < end; e += 64) {
        int j = col[e];
        float4 as4 = *(const float4*)(a_src + 4 * j);
        float ev[4] = {as4.x + adh[0], as4.y + adh[1], as4.z + adh[2], as4.w + adh[3]};
#pragma unroll
        for (int h = 0; h < 4; ++h) {
            float v = ev[h] > 0.f ? ev[h] : 0.2f * ev[h];
            float M = fmaxf(m[h], v);
            s[h] = s[h] * __expf(m[h] - M) + __expf(v - M);
            m[h] = M;
        }
    }
    // max-reduce, rescale once, sum-reduce (saves the per-step exps)
    float mloc[4];
#pragma unroll
    for (int h = 0; h < 4; ++h) mloc[h] = m[h];
#pragma unroll
    for (int off = 32; off >= 1; off >>= 1)
#pragma unroll
        for (int h = 0; h < 4; ++h) m[h] = fmaxf(m[h], __shfl_xor(m[h], off, 64));
#pragma unroll
    for (int h = 0; h < 4; ++h) s[h] *= __expf(mloc[h] - m[h]);
#pragma unroll
    for (int off = 32; off >= 1; off >>= 1)
#pragma unroll
        for (int h = 0; h < 4; ++h) s[h] += __shfl_xor(s[h], off, 64);
    float inv[4];
#pragma unroll
    for (int h = 0; h < 4; ++h) inv[h] = 1.f / (s[h] + 1e-16f);

    // ---- pass B bookkeeping ----
    // MODE 0: half-wave per edge; lane owns feats 4*fl..4*fl+3 (head fl>>3)
    int half = lane >> 5, fl = lane & 31, myh2 = fl >> 3;
    bool lv = lane < 48;  // MODE 1 active lanes
    float acc0 = 0.f, acc1 = 0.f, acc2 = 0.f, acc3 = 0.f;
    const uint2* xb2 = (const uint2*)xh;
    uint2 zz = make_uint2(0u, 0u);

    auto run_chunk = [&](int cnt) {
        int t = 0;
        if (MODE == 0) {
            for (; t + 3 < cnt; t += 4) {
                int ja = s_j[w][t + half], jb = s_j[w][t + 2 + half];
                uint2 qa = xb2[(ja << 5) + fl];
                uint2 qb = xb2[(jb << 5) + fl];
                float aa = s_af[w][t + half][myh2];
                float ab = s_af[w][t + 2 + half][myh2];
                acc0 += aa * bflo_to_f(qa.x); acc1 += aa * bfhi_to_f(qa.x);
                acc2 += aa * bflo_to_f(qa.y); acc3 += aa * bfhi_to_f(qa.y);
                acc0 += ab * bflo_to_f(qb.x); acc1 += ab * bfhi_to_f(qb.x);
                acc2 += ab * bflo_to_f(qb.y); acc3 += ab * bfhi_to_f(qb.y);
            }
            for (; t + 1 < cnt; t += 2) {
                int j = s_j[w][t + half];
                uint2 q = xb2[(j << 5) + fl];
                float a = s_af[w][t + half][myh2];
                acc0 += a * bflo_to_f(q.x); acc1 += a * bfhi_to_f(q.x);
                acc2 += a * bflo_to_f(q.y); acc3 += a * bfhi_to_f(q.y);
            }
            for (; t < cnt; ++t) {  // tail: only half 0 contributes
                int j = s_j[w][t];
                uint2 q = xb2[(j << 5) + fl];
                float a = (half == 0) ? s_af[w][t][myh2] : 0.f;
                acc0 += a * bflo_to_f(q.x); acc1 += a * bfhi_to_f(q.x);
                acc2 += a * bflo_to_f(q.y); acc3 += a * bfhi_to_f(q.y);
            }
        } else {
            for (; t + 3 < cnt; t += 4) {
                int j0 = s_j[w][t], j1 = s_j[w][t + 1];
                int j2 = s_j[w][t + 2], j3 = s_j[w][t + 3];
                uint2 q0 = lv ? xb2[j0 * 48 + lane] : zz;
                uint2 q1 = lv ? xb2[j1 * 48 + lane] : zz;
                uint2 q2 = lv ? xb2[j2 * 48 + lane] : zz;
                uint2 q3 = lv ? xb2[j3 * 48 + lane] : zz;
                acc0 = dot2pair(q0, s_ab[w][t], acc0);
                acc0 = dot2pair(q1, s_ab[w][t + 1], acc0);
                acc0 = dot2pair(q2, s_ab[w][t + 2], acc0);
                acc0 = dot2pair(q3, s_ab[w][t + 3], acc0);
            }
            for (; t < cnt; ++t) {
                int j = s_j[w][t];
                uint2 q = lv ? xb2[j * 48 + lane] : zz;
                acc0 = dot2pair(q, s_ab[w][t], acc0);
            }
        }
    };

    // chunk 0: reuse captured logits, no col/a_src reload
    {
        float al[4];
#pragma unroll
        for (int h = 0; h < 4; ++h)
            al[h] = ok0 ? __expf(evc[h] - m[h]) * inv[h] : 0.f;
        s_j[w][lane] = jcap;
        if constexpr (MODE == 0)
            *(float4*)&s_af[w][lane][0] = make_float4(al[0], al[1], al[2], al[3]);
        else
            s_ab[w][lane] = make_uint2(pk_bf(al[0], al[1]), pk_bf(al[2], al[3]));
        int cnt = end - start; if (cnt > 64) cnt = 64;
        run_chunk(cnt);
    }
    // remaining chunks (deg > 64: rare)
    for (int base = start + 64; base < end; base += 64) {
        int e = base + lane;
        bool ok = e < end;
        int jv = ok ? col[e] : 0;
        float4 as4 = *(const float4*)(a_src + 4 * jv);
        float asv[4] = {as4.x, as4.y, as4.z, as4.w};
        float al[4];
#pragma unroll
        for (int h = 0; h < 4; ++h) {
            float ev = asv[h] + adh[h];
            ev = ev > 0.f ? ev : 0.2f * ev;
            al[h] = ok ? __expf(ev - m[h]) * inv[h] : 0.f;
        }
        s_j[w][lane] = jv;
        if constexpr (MODE == 0)
            *(float4*)&s_af[w][lane][0] = make_float4(al[0], al[1], al[2], al[3]);
        else
            s_ab[w][lane] = make_uint2(pk_bf(al[0], al[1]), pk_bf(al[2], al[3]));
        int cnt = end - base; if (cnt > 64) cnt = 64;
        run_chunk(cnt);
    }

    if constexpr (MODE == 0) {
        // combine half-waves (lane L and L+32 own the same 4 feats)
        acc0 += __shfl_xor(acc0, 32, 64);
        acc1 += __shfl_xor(acc1, 32, 64);
        acc2 += __shfl_xor(acc2, 32, 64);
        acc3 += __shfl_xor(acc3, 32, 64);
        if (active && half == 0) {
            float4 bb = *(const float4*)(bias + 4 * fl);
            float4 sk = *(const float4*)(skip + (node << 7) + 4 * fl);
            float v0 = acc0 + bb.x + sk.x;
            float v1 = acc1 + bb.y + sk.y;
            float v2 = acc2 + bb.z + sk.z;
            float v3 = acc3 + bb.w + sk.w;
            v0 = v0 > 0.f ? v0 : (__expf(v0) - 1.f);   // ELU
            v1 = v1 > 0.f ? v1 : (__expf(v1) - 1.f);
            v2 = v2 > 0.f ? v2 : (__expf(v2) - 1.f);
            v3 = v3 > 0.f ? v3 : (__expf(v3) - 1.f);
            uint2 o = make_uint2(pk_bf(v0, v1), pk_bf(v2, v3));
            ((uint2*)outp)[(node << 5) + fl] = o;
        }
    } else {
        if (active && lane < OUTC) {
            float v = acc0 * 0.25f + bias[lane] + skip[node * OUTC + lane];
            ((float*)outp)[node * OUTC + lane] = v;
        }
    }
}

// ---------------------------------------------------------------------------
extern "C" void kernel_launch(void* const* d_in, const int* in_sizes, int n_in,
                              void* d_out, int out_size, void* d_ws, size_t ws_size,
                              hipStream_t stream) {
    const float* x        = (const float*)d_in[0];
    const int*   ei       = (const int*)d_in[1];
    const float* lin_w0   = (const float*)d_in[2];
    const float* att_src0 = (const float*)d_in[3];
    const float* att_dst0 = (const float*)d_in[4];
    const float* bias0    = (const float*)d_in[5];
    const float* skip_w0  = (const float*)d_in[6];
    const float* skip_b0  = (const float*)d_in[7];
    const float* lin_w1   = (const float*)d_in[8];
    const float* att_src1 = (const float*)d_in[9];
    const float* att_dst1 = (const float*)d_in[10];
    const float* bias1    = (const float*)d_in[11];
    const float* skip_w1  = (const float*)d_in[12];
    const float* skip_b1  = (const float*)d_in[13];
    const float* lin_w2   = (const float*)d_in[14];
    const float* att_src2 = (const float*)d_in[15];
    const float* att_dst2 = (const float*)d_in[16];
    const float* bias2    = (const float*)d_in[17];
    const float* skip_w2  = (const float*)d_in[18];
    const float* skip_b2  = (const float*)d_in[19];
    float* out = (float*)d_out;

    const int N = in_sizes[0] / KD;       // 50000
    const int E = in_sizes[1] / 2;        // 800000
    const int ET_ = E + N;                // with self loops

    char* ws = (char*)d_ws;
    size_t off = 0;
    auto alloc = [&](size_t bytes) -> void* {
        void* p = ws + off;
        off = (off + bytes + 255) & ~(size_t)255;
        return p;
    };
    __bf16* xh     = (__bf16*)alloc((size_t)N * NF2P * 2 + 256); // GAT linear output
    __bf16* buf_bf = (__bf16*)alloc((size_t)N * HC * 2);    // ELU layer output (bf16)
    float* skip    = (float*)alloc((size_t)N * HC * 4);     // skip linear output (fp32)
    float* a_src   = (float*)alloc((size_t)N * 4 * 4);
    float* a_dst   = (float*)alloc((size_t)N * 4 * 4);
    int* deg       = (int*)alloc((size_t)N * 4);
    int* row_ptr   = (int*)alloc((size_t)N * 4);
    int* fill      = (int*)alloc((size_t)N * 4);
    int* col       = (int*)alloc((size_t)ET_ * 4);
    int* counter   = (int*)alloc(256);

    // ---- CSR build (dst-sorted adjacency, self-loops included) ----
    init_deg_kernel<<<(N + 255) / 256, 256, 0, stream>>>(deg, counter, N);
    count_kernel<<<(E + 255) / 256, 256, 0, stream>>>(ei + E, deg, E);
    scan_base_kernel<<<(N + 255) / 256, 256, 0, stream>>>(deg, counter, row_ptr, fill, N);
    fill_kernel<<<(ET_ + 255) / 256, 256, 0, stream>>>(ei, fill, col, E, N);

    dim3 blk(256);
    int mblocks = (N + 127) / 128;
    dim3 g4(mblocks, 4);           // dual GEMM grids (2+2 or 3+1 column-blocks)
    int wave_blocks = (N + 3) / 4; // one wave per node, 4 waves/block

    // ---- layer 0 (A = fp32 x, converted in staging) ----
    gemm_dual_kernel<float><<<g4, blk, 0, stream>>>(x, lin_w0, xh, HC, HC, 0, 2,
                                                    skip_w0, skip_b0, skip, HC, N);
    att_kernel<<<wave_blocks, blk, 0, stream>>>(xh, att_src0, att_dst0, a_src, a_dst, N);
    agg_kernel<0><<<wave_blocks, blk, 0, stream>>>(xh, a_src, a_dst, skip, bias0,
                                                   row_ptr, deg, col, buf_bf, N);
    // ---- layer 1 ----
    gemm_dual_kernel<__bf16><<<g4, blk, 0, stream>>>(buf_bf, lin_w1, xh, HC, HC, 0, 2,
                                                     skip_w1, skip_b1, skip, HC, N);
    att_kernel<<<wave_blocks, blk, 0, stream>>>(xh, att_src1, att_dst1, a_src, a_dst, N);
    agg_kernel<0><<<wave_blocks, blk, 0, stream>>>(xh, a_src, a_dst, skip, bias1,
                                                   row_ptr, deg, col, buf_bf, N);
    // ---- layer 2 (xh stored head-interleaved, stride 192) ----
    gemm_dual_kernel<__bf16><<<g4, blk, 0, stream>>>(buf_bf, lin_w2, xh, NF2, NF2P, 1, 3,
                                                     skip_w2, skip_b2, skip, OUTC, N);
    att2_kernel<<<wave_blocks, blk, 0, stream>>>(xh, att_src2, att_dst2, a_src, a_dst, N);
    agg_kernel<1><<<wave_blocks, blk, 0, stream>>>(xh, a_src, a_dst, skip, bias2,
                                                   row_ptr, deg, col, out, N);
}

// Round 7
// 493.392 us; speedup vs baseline: 1.8364x; 1.0424x over previous
//
#include <hip/hip_runtime.h>
#include <math.h>
#include <type_traits>

// Problem constants (fixed by reference)
#define KD 128      // K dim of every GEMM (IN = HC = 128)
#define HC 128      // H*C for layers 0/1
#define NF2 188     // H*OUT for layer 2
#define NF2P 192    // padded layer-2 feature stride (6 cachelines)
#define OUTC 47

typedef __attribute__((ext_vector_type(8))) __bf16 bf16x8;
typedef __attribute__((ext_vector_type(2))) __bf16 bf16x2;
typedef __attribute__((ext_vector_type(4))) float f32x4;

#ifdef __has_builtin
#if __has_builtin(__builtin_amdgcn_fdot2_f32_bf16)
#define HAVE_FDOT2 1
#endif
#endif

__device__ inline float bfhi_to_f(unsigned int u) {
    union { unsigned int u; float f; } c; c.u = u & 0xFFFF0000u; return c.f;
}
__device__ inline float bflo_to_f(unsigned int u) {
    union { unsigned int u; float f; } c; c.u = u << 16; return c.f;
}
__device__ inline unsigned short f_to_bfu(float f) {
    return __builtin_bit_cast(unsigned short, (__bf16)f);
}
__device__ inline unsigned int pk_bf(float a, float b) {
    return (unsigned int)f_to_bfu(a) | ((unsigned int)f_to_bfu(b) << 16);
}
// acc += dot(q, ab) over 4 packed bf16 pairs
__device__ inline float dot2pair(uint2 q, uint2 ab, float acc) {
#ifdef HAVE_FDOT2
    acc = __builtin_amdgcn_fdot2_f32_bf16(__builtin_bit_cast(bf16x2, q.x),
                                          __builtin_bit_cast(bf16x2, ab.x), acc, false);
    acc = __builtin_amdgcn_fdot2_f32_bf16(__builtin_bit_cast(bf16x2, q.y),
                                          __builtin_bit_cast(bf16x2, ab.y), acc, false);
#else
    acc += bflo_to_f(q.x) * bflo_to_f(ab.x) + bfhi_to_f(q.x) * bfhi_to_f(ab.x);
    acc += bflo_to_f(q.y) * bflo_to_f(ab.y) + bfhi_to_f(q.y) * bfhi_to_f(ab.y);
#endif
    return acc;
}

// ---------------------------------------------------------------------------
// CSR build (4 dispatches). Self-loops written deterministically in scan.
// ---------------------------------------------------------------------------
__global__ void init_deg_kernel(int* deg, int* counter, int n) {
    int i = blockIdx.x * blockDim.x + threadIdx.x;
    if (i < n) deg[i] = 1;  // self-loop contributes 1
    if (i == 0) *counter = 0;
}

// 4 edges per thread: 4 independent atomic chains in flight
__global__ void count_kernel(const int* __restrict__ dst, int* deg, int e) {
    int t = blockIdx.x * blockDim.x + threadIdx.x;
    int base = t * 4;
    if (base + 3 < e) {
        int4 d = *(const int4*)(dst + base);
        atomicAdd(&deg[d.x], 1);
        atomicAdd(&deg[d.y], 1);
        atomicAdd(&deg[d.z], 1);
        atomicAdd(&deg[d.w], 1);
    } else {
        for (int k = base; k < e; ++k) atomicAdd(&deg[dst[k]], 1);
    }
}

// single-pass scan: per-block exclusive scan + atomic block base.
// row_ptr is NOT monotone across blocks; consumers use deg[] for segment end.
// Also writes the self-loop entry at the head of each segment.
__global__ __launch_bounds__(256) void scan_base_kernel(
    const int* __restrict__ deg, int* counter,
    int* __restrict__ row_ptr, int* __restrict__ fill, int* __restrict__ col, int n) {
    int i = blockIdx.x * 256 + threadIdx.x;
    int v = (i < n) ? deg[i] : 0;
    int lane = threadIdx.x & 63, w = threadIdx.x >> 6;
    int incl = v;
#pragma unroll
    for (int off = 1; off < 64; off <<= 1) {
        int u = __shfl_up(incl, off, 64);
        if (lane >= off) incl += u;
    }
    __shared__ int wsum[4];
    __shared__ int base_sh;
    if (lane == 63) wsum[w] = incl;
    __syncthreads();
    if (threadIdx.x == 0)
        base_sh = atomicAdd(counter, wsum[0] + wsum[1] + wsum[2] + wsum[3]);
    int woff = 0;
    for (int k = 0; k < w; ++k) woff += wsum[k];
    __syncthreads();
    int excl = base_sh + woff + incl - v;
    if (i < n) {
        row_ptr[i] = excl;
        col[excl] = i;        // self-loop at segment head
        fill[i] = excl + 1;   // edges fill after it
    }
}

// 4 edges per thread, vectorized src/dst loads
__global__ void fill_kernel(const int* __restrict__ ei, int* fill, int* col, int e) {
    int t = blockIdx.x * blockDim.x + threadIdx.x;
    int base = t * 4;
    if (base + 3 < e) {
        int4 s = *(const int4*)(ei + base);
        int4 d = *(const int4*)(ei + e + base);
        int p0 = atomicAdd(&fill[d.x], 1);
        int p1 = atomicAdd(&fill[d.y], 1);
        int p2 = atomicAdd(&fill[d.z], 1);
        int p3 = atomicAdd(&fill[d.w], 1);
        col[p0] = s.x; col[p1] = s.y; col[p2] = s.z; col[p3] = s.w;
    } else {
        for (int k = base; k < e; ++k) {
            int pos = atomicAdd(&fill[ei[e + k]], 1);
            col[pos] = ei[k];
        }
    }
}

// ---------------------------------------------------------------------------
// Dual bf16 MFMA GEMM: from one A[M,128] (bf16 or fp32, converted in staging):
//   out0 = A @ B0 (bf16 store, no bias, row stride ldc0; tr0 -> head-interleave)
//   out1 = A @ B1 + bias1 (fp32 store)
// grid.y: [0, nb0) -> part 0, rest -> part 1. BM=128, BN=64, full K=128.
// ---------------------------------------------------------------------------
template <typename AT>
__global__ __launch_bounds__(256) void gemm_dual_kernel(
    const AT* __restrict__ A,
    const float* __restrict__ B0, __bf16* __restrict__ out0, int N0, int ldc0,
    int tr0, int nb0,
    const float* __restrict__ B1, const float* __restrict__ bias1,
    float* __restrict__ out1, int N1, int M) {
    __shared__ __bf16 As[128][136];   // [m][k], +8 pad (16B-aligned rows)
    __shared__ __bf16 Bs[64][136];    // [n][k] (transposed)
    int tid = threadIdx.x;
    int m0 = blockIdx.x * 128;
    bool second = (int)blockIdx.y >= nb0;
    const float* B = second ? B1 : B0;
    int N = second ? N1 : N0;
    int n0 = (second ? (blockIdx.y - nb0) : blockIdx.y) * 64;

    // stage A: 128 rows x 128 elems, 16B LDS writes
#pragma unroll
    for (int rep = 0; rep < 8; ++rep) {
        int idx = tid + rep * 256;          // 0..2047
        int row = idx >> 4, seg = idx & 15; // 8-elem segment within row
        int gm = m0 + row;
        bf16x8 v = {};
        if (gm < M) {
            if constexpr (std::is_same<AT, float>::value) {
                const float* p = A + gm * KD + seg * 8;
                float4 f0 = *(const float4*)p;
                float4 f1 = *(const float4*)(p + 4);
                v[0] = (__bf16)f0.x; v[1] = (__bf16)f0.y; v[2] = (__bf16)f0.z; v[3] = (__bf16)f0.w;
                v[4] = (__bf16)f1.x; v[5] = (__bf16)f1.y; v[6] = (__bf16)f1.z; v[7] = (__bf16)f1.w;
            } else {
                v = *(const bf16x8*)(A + gm * KD + seg * 8);
            }
        }
        *(bf16x8*)&As[row][seg * 8] = v;
    }
    // stage B transposed via coalesced row reads + 16B LDS writes
#pragma unroll
    for (int rep = 0; rep < 4; ++rep) {
        int idx = tid + rep * 256;          // 0..1023
        int n = idx & 63, seg = idx >> 6;   // seg 0..15 (8 k's each)
        bf16x8 v = {};
        if (n0 + n < N) {
#pragma unroll
            for (int i = 0; i < 8; ++i) v[i] = (__bf16)B[(seg * 8 + i) * N + n0 + n];
        }
        *(bf16x8*)&Bs[n][seg * 8] = v;
    }
    __syncthreads();

    int w = tid >> 6, lane = tid & 63;
    int lr = lane & 15, quad = lane >> 4;
    f32x4 acc[2][4] = {};
#pragma unroll
    for (int kc = 0; kc < 128; kc += 32) {
        bf16x8 a0 = *(const bf16x8*)&As[w * 32 + lr][kc + quad * 8];
        bf16x8 a1 = *(const bf16x8*)&As[w * 32 + 16 + lr][kc + quad * 8];
        bf16x8 b0 = *(const bf16x8*)&Bs[lr][kc + quad * 8];
        bf16x8 b1 = *(const bf16x8*)&Bs[16 + lr][kc + quad * 8];
        bf16x8 b2 = *(const bf16x8*)&Bs[32 + lr][kc + quad * 8];
        bf16x8 b3 = *(const bf16x8*)&Bs[48 + lr][kc + quad * 8];
        acc[0][0] = __builtin_amdgcn_mfma_f32_16x16x32_bf16(a0, b0, acc[0][0], 0, 0, 0);
        acc[0][1] = __builtin_amdgcn_mfma_f32_16x16x32_bf16(a0, b1, acc[0][1], 0, 0, 0);
        acc[0][2] = __builtin_amdgcn_mfma_f32_16x16x32_bf16(a0, b2, acc[0][2], 0, 0, 0);
        acc[0][3] = __builtin_amdgcn_mfma_f32_16x16x32_bf16(a0, b3, acc[0][3], 0, 0, 0);
        acc[1][0] = __builtin_amdgcn_mfma_f32_16x16x32_bf16(a1, b0, acc[1][0], 0, 0, 0);
        acc[1][1] = __builtin_amdgcn_mfma_f32_16x16x32_bf16(a1, b1, acc[1][1], 0, 0, 0);
        acc[1][2] = __builtin_amdgcn_mfma_f32_16x16x32_bf16(a1, b2, acc[1][2], 0, 0, 0);
        acc[1][3] = __builtin_amdgcn_mfma_f32_16x16x32_bf16(a1, b3, acc[1][3], 0, 0, 0);
    }
    // epilogue: C/D layout col=lane&15, row=quad*4+reg
#pragma unroll
    for (int r = 0; r < 2; ++r) {
#pragma unroll
        for (int c = 0; c < 4; ++c) {
#pragma unroll
            for (int reg = 0; reg < 4; ++reg) {
                int row = m0 + w * 32 + r * 16 + quad * 4 + reg;
                int colg = n0 + c * 16 + lr;
                if (row < M && colg < N) {
                    float v = acc[r][c][reg];
                    if (second) {
                        if (bias1) v += bias1[colg];
                        out1[row * N + colg] = v;
                    } else {
                        int idx;
                        if (tr0) {  // head-interleave: feat = oc*4 + h
                            int h = (colg * 1395) >> 16;   // colg / 47 for colg<188
                            idx = row * ldc0 + (colg - 47 * h) * 4 + h;
                        } else {
                            idx = row * ldc0 + colg;
                        }
                        out0[idx] = (__bf16)v;
                    }
                }
            }
        }
    }
}

// ---------------------------------------------------------------------------
// att for layers 0/1: a_src[n,h] = sum_c xh[n,h*32+c]*att_s[h*32+c]. One wave/node.
// ---------------------------------------------------------------------------
__global__ __launch_bounds__(256) void att_kernel(
    const __bf16* __restrict__ xh, const float* __restrict__ att_s,
    const float* __restrict__ att_d, float* __restrict__ a_src,
    float* __restrict__ a_dst, int n) {
    int node = (blockIdx.x * blockDim.x + threadIdx.x) >> 6;
    int lane = threadIdx.x & 63;
    if (node >= n) return;
    float hs[4] = {0.f, 0.f, 0.f, 0.f};
    float hd[4] = {0.f, 0.f, 0.f, 0.f};
#pragma unroll
    for (int r = 0; r < 2; ++r) {
        int f = lane + 64 * r;
        float x = (float)xh[node * HC + f];
        float ps = x * att_s[f];
        float pd = x * att_d[f];
        int h = f >> 5;
        if (h == 0)      { hs[0] += ps; hd[0] += pd; }
        else if (h == 1) { hs[1] += ps; hd[1] += pd; }
        else if (h == 2) { hs[2] += ps; hd[2] += pd; }
        else             { hs[3] += ps; hd[3] += pd; }
    }
#pragma unroll
    for (int off = 32; off >= 1; off >>= 1) {
#pragma unroll
        for (int h = 0; h < 4; ++h) {
            hs[h] += __shfl_xor(hs[h], off, 64);
            hd[h] += __shfl_xor(hd[h], off, 64);
        }
    }
    if (lane == 0) {
        *(float4*)(a_src + 4 * node) = make_float4(hs[0], hs[1], hs[2], hs[3]);
        *(float4*)(a_dst + 4 * node) = make_float4(hd[0], hd[1], hd[2], hd[3]);
    }
}

// ---------------------------------------------------------------------------
// att for layer 2 (head-interleaved xh, stride 192): feat f -> h=f&3, c=f>>2.
// ---------------------------------------------------------------------------
__global__ __launch_bounds__(256) void att2_kernel(
    const __bf16* __restrict__ xh, const float* __restrict__ att_s,
    const float* __restrict__ att_d, float* __restrict__ a_src,
    float* __restrict__ a_dst, int n) {
    int node = (blockIdx.x * blockDim.x + threadIdx.x) >> 6;
    int lane = threadIdx.x & 63;
    if (node >= n) return;
    int h = lane & 3;
    float hs = 0.f, hd = 0.f;
#pragma unroll
    for (int r = 0; r < 3; ++r) {
        int f = lane + 64 * r;
        if (f < NF2) {
            float x = (float)xh[node * NF2P + f];
            int c = f >> 2;
            hs += x * att_s[h * 47 + c];
            hd += x * att_d[h * 47 + c];
        }
    }
#pragma unroll
    for (int off = 4; off <= 32; off <<= 1) {
        hs += __shfl_xor(hs, off, 64);
        hd += __shfl_xor(hd, off, 64);
    }
    if (lane < 4) {
        a_src[node * 4 + lane] = hs;
        a_dst[node * 4 + lane] = hd;
    }
}

// ---------------------------------------------------------------------------
// Aggregation: one wave per destination node. 32-bit indexing.
// MODE 0 (NF=128): 8 edges/iter, half-wave per edge, uint2 (4 feats)/lane.
// MODE 1 (NF2P=192 head-interleaved): 8 edges/iter, lane c<48 loads uint2 =
//                  4 heads of channel c; packed-bf16 alphas; dot2 accumulate.
// ---------------------------------------------------------------------------
template <int MODE>
__global__ __launch_bounds__(256) void agg_kernel(
    const __bf16* __restrict__ xh, const float* __restrict__ a_src,
    const float* __restrict__ a_dst, const float* __restrict__ skip,
    const float* __restrict__ bias, const int* __restrict__ row_ptr,
    const int* __restrict__ deg, const int* __restrict__ col,
    void* __restrict__ outp, int n) {
    __shared__ float s_af[4][64][4];   // MODE 0 alphas (f32)
    __shared__ uint2 s_ab[4][64];      // MODE 1 alphas (packed bf16: a0a1, a2a3)
    __shared__ int s_j[4][64];
    int w = threadIdx.x >> 6;
    int lane = threadIdx.x & 63;
    int node = (blockIdx.x << 2) + w;
    bool active = node < n;
    int node_c = active ? node : 0;
    int start = row_ptr[node_c];
    int end = start + (active ? deg[node_c] : 0);
    float4 ad4 = *(const float4*)(a_dst + 4 * node_c);
    float adh[4] = {ad4.x, ad4.y, ad4.z, ad4.w};

    // ---- pass A (+ chunk-0 capture) ----
    int e0 = start + lane;
    bool ok0 = e0 < end;
    int jcap = ok0 ? col[e0] : 0;
    float evc[4];
    {
        float4 as4 = *(const float4*)(a_src + 4 * jcap);
        float v0 = as4.x + adh[0]; evc[0] = v0 > 0.f ? v0 : 0.2f * v0;
        float v1 = as4.y + adh[1]; evc[1] = v1 > 0.f ? v1 : 0.2f * v1;
        float v2 = as4.z + adh[2]; evc[2] = v2 > 0.f ? v2 : 0.2f * v2;
        float v3 = as4.w + adh[3]; evc[3] = v3 > 0.f ? v3 : 0.2f * v3;
    }
    float m[4], s[4];
#pragma unroll
    for (int h = 0; h < 4; ++h) {
        m[h] = ok0 ? evc[h] : -1e30f;
        s[h] = ok0 ? 1.f : 0.f;
    }
    for (int e = e0 + 64; e < end; e += 64) {
        int j = col[e];
        float4 as4 = *(const float4*)(a_src + 4 * j);
        float ev[4] = {as4.x + adh[0], as4.y + adh[1], as4.z + adh[2], as4.w + adh[3]};
#pragma unroll
        for (int h = 0; h < 4; ++h) {
            float v = ev[h] > 0.f ? ev[h] : 0.2f * ev[h];
            float M = fmaxf(m[h], v);
            s[h] = s[h] * __expf(m[h] - M) + __expf(v - M);
            m[h] = M;
        }
    }
    // max-reduce, rescale once, sum-reduce
    float mloc[4];
#pragma unroll
    for (int h = 0; h < 4; ++h) mloc[h] = m[h];
#pragma unroll
    for (int off = 32; off >= 1; off >>= 1)
#pragma unroll
        for (int h = 0; h < 4; ++h) m[h] = fmaxf(m[h], __shfl_xor(m[h], off, 64));
#pragma unroll
    for (int h = 0; h < 4; ++h) s[h] *= __expf(mloc[h] - m[h]);
#pragma unroll
    for (int off = 32; off >= 1; off >>= 1)
#pragma unroll
        for (int h = 0; h < 4; ++h) s[h] += __shfl_xor(s[h], off, 64);
    float inv[4];
#pragma unroll
    for (int h = 0; h < 4; ++h) inv[h] = 1.f / (s[h] + 1e-16f);

    // ---- pass B bookkeeping ----
    int half = lane >> 5, fl = lane & 31, myh2 = fl >> 3;
    bool lv = lane < 48;  // MODE 1 active lanes
    float acc0 = 0.f, acc1 = 0.f, acc2 = 0.f, acc3 = 0.f;
    const uint2* xb2 = (const uint2*)xh;
    uint2 zz = make_uint2(0u, 0u);

    auto run_chunk = [&](int cnt) {
        int t = 0;
        if (MODE == 0) {
            for (; t + 7 < cnt; t += 8) {
                int ja = s_j[w][t + half], jb = s_j[w][t + 2 + half];
                int jc = s_j[w][t + 4 + half], jd = s_j[w][t + 6 + half];
                uint2 qa = xb2[(ja << 5) + fl];
                uint2 qb = xb2[(jb << 5) + fl];
                uint2 qc = xb2[(jc << 5) + fl];
                uint2 qd = xb2[(jd << 5) + fl];
                float aa = s_af[w][t + half][myh2];
                float ab = s_af[w][t + 2 + half][myh2];
                float ac = s_af[w][t + 4 + half][myh2];
                float ad = s_af[w][t + 6 + half][myh2];
                acc0 += aa * bflo_to_f(qa.x); acc1 += aa * bfhi_to_f(qa.x);
                acc2 += aa * bflo_to_f(qa.y); acc3 += aa * bfhi_to_f(qa.y);
                acc0 += ab * bflo_to_f(qb.x); acc1 += ab * bfhi_to_f(qb.x);
                acc2 += ab * bflo_to_f(qb.y); acc3 += ab * bfhi_to_f(qb.y);
                acc0 += ac * bflo_to_f(qc.x); acc1 += ac * bfhi_to_f(qc.x);
                acc2 += ac * bflo_to_f(qc.y); acc3 += ac * bfhi_to_f(qc.y);
                acc0 += ad * bflo_to_f(qd.x); acc1 += ad * bfhi_to_f(qd.x);
                acc2 += ad * bflo_to_f(qd.y); acc3 += ad * bfhi_to_f(qd.y);
            }
            for (; t + 3 < cnt; t += 4) {
                int ja = s_j[w][t + half], jb = s_j[w][t + 2 + half];
                uint2 qa = xb2[(ja << 5) + fl];
                uint2 qb = xb2[(jb << 5) + fl];
                float aa = s_af[w][t + half][myh2];
                float ab = s_af[w][t + 2 + half][myh2];
                acc0 += aa * bflo_to_f(qa.x); acc1 += aa * bfhi_to_f(qa.x);
                acc2 += aa * bflo_to_f(qa.y); acc3 += aa * bfhi_to_f(qa.y);
                acc0 += ab * bflo_to_f(qb.x); acc1 += ab * bfhi_to_f(qb.x);
                acc2 += ab * bflo_to_f(qb.y); acc3 += ab * bfhi_to_f(qb.y);
            }
            for (; t + 1 < cnt; t += 2) {
                int j = s_j[w][t + half];
                uint2 q = xb2[(j << 5) + fl];
                float a = s_af[w][t + half][myh2];
                acc0 += a * bflo_to_f(q.x); acc1 += a * bfhi_to_f(q.x);
                acc2 += a * bflo_to_f(q.y); acc3 += a * bfhi_to_f(q.y);
            }
            for (; t < cnt; ++t) {  // tail: only half 0 contributes
                int j = s_j[w][t];
                uint2 q = xb2[(j << 5) + fl];
                float a = (half == 0) ? s_af[w][t][myh2] : 0.f;
                acc0 += a * bflo_to_f(q.x); acc1 += a * bfhi_to_f(q.x);
                acc2 += a * bflo_to_f(q.y); acc3 += a * bfhi_to_f(q.y);
            }
        } else {
            for (; t + 7 < cnt; t += 8) {
                uint2 q0 = lv ? xb2[s_j[w][t] * 48 + lane] : zz;
                uint2 q1 = lv ? xb2[s_j[w][t + 1] * 48 + lane] : zz;
                uint2 q2 = lv ? xb2[s_j[w][t + 2] * 48 + lane] : zz;
                uint2 q3 = lv ? xb2[s_j[w][t + 3] * 48 + lane] : zz;
                uint2 q4 = lv ? xb2[s_j[w][t + 4] * 48 + lane] : zz;
                uint2 q5 = lv ? xb2[s_j[w][t + 5] * 48 + lane] : zz;
                uint2 q6 = lv ? xb2[s_j[w][t + 6] * 48 + lane] : zz;
                uint2 q7 = lv ? xb2[s_j[w][t + 7] * 48 + lane] : zz;
                acc0 = dot2pair(q0, s_ab[w][t], acc0);
                acc0 = dot2pair(q1, s_ab[w][t + 1], acc0);
                acc0 = dot2pair(q2, s_ab[w][t + 2], acc0);
                acc0 = dot2pair(q3, s_ab[w][t + 3], acc0);
                acc0 = dot2pair(q4, s_ab[w][t + 4], acc0);
                acc0 = dot2pair(q5, s_ab[w][t + 5], acc0);
                acc0 = dot2pair(q6, s_ab[w][t + 6], acc0);
                acc0 = dot2pair(q7, s_ab[w][t + 7], acc0);
            }
            for (; t + 3 < cnt; t += 4) {
                uint2 q0 = lv ? xb2[s_j[w][t] * 48 + lane] : zz;
                uint2 q1 = lv ? xb2[s_j[w][t + 1] * 48 + lane] : zz;
                uint2 q2 = lv ? xb2[s_j[w][t + 2] * 48 + lane] : zz;
                uint2 q3 = lv ? xb2[s_j[w][t + 3] * 48 + lane] : zz;
                acc0 = dot2pair(q0, s_ab[w][t], acc0);
                acc0 = dot2pair(q1, s_ab[w][t + 1], acc0);
                acc0 = dot2pair(q2, s_ab[w][t + 2], acc0);
                acc0 = dot2pair(q3, s_ab[w][t + 3], acc0);
            }
            for (; t < cnt; ++t) {
                uint2 q = lv ? xb2[s_j[w][t] * 48 + lane] : zz;
                acc0 = dot2pair(q, s_ab[w][t], acc0);
            }
        }
    };

    // chunk 0: reuse captured logits, no col/a_src reload
    {
        float al[4];
#pragma unroll
        for (int h = 0; h < 4; ++h)
            al[h] = ok0 ? __expf(evc[h] - m[h]) * inv[h] : 0.f;
        s_j[w][lane] = jcap;
        if constexpr (MODE == 0)
            *(float4*)&s_af[w][lane][0] = make_float4(al[0], al[1], al[2], al[3]);
        else
            s_ab[w][lane] = make_uint2(pk_bf(al[0], al[1]), pk_bf(al[2], al[3]));
        int cnt = end - start; if (cnt > 64) cnt = 64;
        run_chunk(cnt);
    }
    // remaining chunks (deg > 64: rare)
    for (int base = start + 64; base < end; base += 64) {
        int e = base + lane;
        bool ok = e < end;
        int jv = ok ? col[e] : 0;
        float4 as4 = *(const float4*)(a_src + 4 * jv);
        float asv[4] = {as4.x, as4.y, as4.z, as4.w};
        float al[4];
#pragma unroll
        for (int h = 0; h < 4; ++h) {
            float ev = asv[h] + adh[h];
            ev = ev > 0.f ? ev : 0.2f * ev;
            al[h] = ok ? __expf(ev - m[h]) * inv[h] : 0.f;
        }
        s_j[w][lane] = jv;
        if constexpr (MODE == 0)
            *(float4*)&s_af[w][lane][0] = make_float4(al[0], al[1], al[2], al[3]);
        else
            s_ab[w][lane] = make_uint2(pk_bf(al[0], al[1]), pk_bf(al[2], al[3]));
        int cnt = end - base; if (cnt > 64) cnt = 64;
        run_chunk(cnt);
    }

    if constexpr (MODE == 0) {
        // combine half-waves (lane L and L+32 own the same 4 feats)
        acc0 += __shfl_xor(acc0, 32, 64);
        acc1 += __shfl_xor(acc1, 32, 64);
        acc2 += __shfl_xor(acc2, 32, 64);
        acc3 += __shfl_xor(acc3, 32, 64);
        if (active && half == 0) {
            float4 bb = *(const float4*)(bias + 4 * fl);
            float4 sk = *(const float4*)(skip + (node << 7) + 4 * fl);
            float v0 = acc0 + bb.x + sk.x;
            float v1 = acc1 + bb.y + sk.y;
            float v2 = acc2 + bb.z + sk.z;
            float v3 = acc3 + bb.w + sk.w;
            v0 = v0 > 0.f ? v0 : (__expf(v0) - 1.f);   // ELU
            v1 = v1 > 0.f ? v1 : (__expf(v1) - 1.f);
            v2 = v2 > 0.f ? v2 : (__expf(v2) - 1.f);
            v3 = v3 > 0.f ? v3 : (__expf(v3) - 1.f);
            uint2 o = make_uint2(pk_bf(v0, v1), pk_bf(v2, v3));
            ((uint2*)outp)[(node << 5) + fl] = o;
        }
    } else {
        if (active && lane < OUTC) {
            float v = acc0 * 0.25f + bias[lane] + skip[node * OUTC + lane];
            ((float*)outp)[node * OUTC + lane] = v;
        }
    }
}

// ---------------------------------------------------------------------------
extern "C" void kernel_launch(void* const* d_in, const int* in_sizes, int n_in,
                              void* d_out, int out_size, void* d_ws, size_t ws_size,
                              hipStream_t stream) {
    const float* x        = (const float*)d_in[0];
    const int*   ei       = (const int*)d_in[1];
    const float* lin_w0   = (const float*)d_in[2];
    const float* att_src0 = (const float*)d_in[3];
    const float* att_dst0 = (const float*)d_in[4];
    const float* bias0    = (const float*)d_in[5];
    const float* skip_w0  = (const float*)d_in[6];
    const float* skip_b0  = (const float*)d_in[7];
    const float* lin_w1   = (const float*)d_in[8];
    const float* att_src1 = (const float*)d_in[9];
    const float* att_dst1 = (const float*)d_in[10];
    const float* bias1    = (const float*)d_in[11];
    const float* skip_w1  = (const float*)d_in[12];
    const float* skip_b1  = (const float*)d_in[13];
    const float* lin_w2   = (const float*)d_in[14];
    const float* att_src2 = (const float*)d_in[15];
    const float* att_dst2 = (const float*)d_in[16];
    const float* bias2    = (const float*)d_in[17];
    const float* skip_w2  = (const float*)d_in[18];
    const float* skip_b2  = (const float*)d_in[19];
    float* out = (float*)d_out;

    const int N = in_sizes[0] / KD;       // 50000
    const int E = in_sizes[1] / 2;        // 800000
    const int ET_ = E + N;                // with self loops

    char* ws = (char*)d_ws;
    size_t off = 0;
    auto alloc = [&](size_t bytes) -> void* {
        void* p = ws + off;
        off = (off + bytes + 255) & ~(size_t)255;
        return p;
    };
    __bf16* xh     = (__bf16*)alloc((size_t)N * NF2P * 2 + 256); // GAT linear output
    __bf16* buf_bf = (__bf16*)alloc((size_t)N * HC * 2);    // ELU layer output (bf16)
    float* skip    = (float*)alloc((size_t)N * HC * 4);     // skip linear output (fp32)
    float* a_src   = (float*)alloc((size_t)N * 4 * 4);
    float* a_dst   = (float*)alloc((size_t)N * 4 * 4);
    int* deg       = (int*)alloc((size_t)N * 4);
    int* row_ptr   = (int*)alloc((size_t)N * 4);
    int* fill      = (int*)alloc((size_t)N * 4);
    int* col       = (int*)alloc((size_t)ET_ * 4);
    int* counter   = (int*)alloc(256);

    // ---- CSR build (dst-sorted adjacency, self-loops included) ----
    init_deg_kernel<<<(N + 255) / 256, 256, 0, stream>>>(deg, counter, N);
    count_kernel<<<(E / 4 + 255) / 256, 256, 0, stream>>>(ei + E, deg, E);
    scan_base_kernel<<<(N + 255) / 256, 256, 0, stream>>>(deg, counter, row_ptr, fill, col, N);
    fill_kernel<<<(E / 4 + 255) / 256, 256, 0, stream>>>(ei, fill, col, E);

    dim3 blk(256);
    int mblocks = (N + 127) / 128;
    dim3 g4(mblocks, 4);           // dual GEMM grids (2+2 or 3+1 column-blocks)
    int wave_blocks = (N + 3) / 4; // one wave per node, 4 waves/block

    // ---- layer 0 (A = fp32 x, converted in staging) ----
    gemm_dual_kernel<float><<<g4, blk, 0, stream>>>(x, lin_w0, xh, HC, HC, 0, 2,
                                                    skip_w0, skip_b0, skip, HC, N);
    att_kernel<<<wave_blocks, blk, 0, stream>>>(xh, att_src0, att_dst0, a_src, a_dst, N);
    agg_kernel<0><<<wave_blocks, blk, 0, stream>>>(xh, a_src, a_dst, skip, bias0,
                                                   row_ptr, deg, col, buf_bf, N);
    // ---- layer 1 ----
    gemm_dual_kernel<__bf16><<<g4, blk, 0, stream>>>(buf_bf, lin_w1, xh, HC, HC, 0, 2,
                                                     skip_w1, skip_b1, skip, HC, N);
    att_kernel<<<wave_blocks, blk, 0, stream>>>(xh, att_src1, att_dst1, a_src, a_dst, N);
    agg_kernel<0><<<wave_blocks, blk, 0, stream>>>(xh, a_src, a_dst, skip, bias1,
                                                   row_ptr, deg, col, buf_bf, N);
    // ---- layer 2 (xh stored head-interleaved, stride 192) ----
    gemm_dual_kernel<__bf16><<<g4, blk, 0, stream>>>(buf_bf, lin_w2, xh, NF2, NF2P, 1, 3,
                                                     skip_w2, skip_b2, skip, OUTC, N);
    att2_kernel<<<wave_blocks, blk, 0, stream>>>(xh, att_src2, att_dst2, a_src, a_dst, N);
    agg_kernel<1><<<wave_blocks, blk, 0, stream>>>(xh, a_src, a_dst, skip, bias2,
                                                   row_ptr, deg, col, out, N);
}

// Round 8
// 454.530 us; speedup vs baseline: 1.9934x; 1.0855x over previous
//
#include <hip/hip_runtime.h>
#include <math.h>
#include <type_traits>

// Problem constants (fixed by reference)
#define KD 128      // K dim of every GEMM (IN = HC = 128)
#define HC 128      // H*C for layers 0/1
#define NF2 188     // H*OUT for layer 2
#define NF2P 192    // padded layer-2 feature stride (6 cachelines)
#define OUTC 47

typedef __attribute__((ext_vector_type(8))) __bf16 bf16x8;
typedef __attribute__((ext_vector_type(2))) __bf16 bf16x2;
typedef __attribute__((ext_vector_type(4))) float f32x4;

#ifdef __has_builtin
#if __has_builtin(__builtin_amdgcn_fdot2_f32_bf16)
#define HAVE_FDOT2 1
#endif
#endif

__device__ inline float bfhi_to_f(unsigned int u) {
    union { unsigned int u; float f; } c; c.u = u & 0xFFFF0000u; return c.f;
}
__device__ inline float bflo_to_f(unsigned int u) {
    union { unsigned int u; float f; } c; c.u = u << 16; return c.f;
}
__device__ inline unsigned short f_to_bfu(float f) {
    return __builtin_bit_cast(unsigned short, (__bf16)f);
}
__device__ inline unsigned int pk_bf(float a, float b) {
    return (unsigned int)f_to_bfu(a) | ((unsigned int)f_to_bfu(b) << 16);
}
// acc += dot(q, ab) over 4 packed bf16 pairs
__device__ inline float dot2pair(uint2 q, uint2 ab, float acc) {
#ifdef HAVE_FDOT2
    acc = __builtin_amdgcn_fdot2_f32_bf16(__builtin_bit_cast(bf16x2, q.x),
                                          __builtin_bit_cast(bf16x2, ab.x), acc, false);
    acc = __builtin_amdgcn_fdot2_f32_bf16(__builtin_bit_cast(bf16x2, q.y),
                                          __builtin_bit_cast(bf16x2, ab.y), acc, false);
#else
    acc += bflo_to_f(q.x) * bflo_to_f(ab.x) + bfhi_to_f(q.x) * bfhi_to_f(ab.x);
    acc += bflo_to_f(q.y) * bflo_to_f(ab.y) + bfhi_to_f(q.y) * bfhi_to_f(ab.y);
#endif
    return acc;
}

// ---------------------------------------------------------------------------
// CSR build (4 dispatches). Self-loops written deterministically in scan.
// ---------------------------------------------------------------------------
__global__ void init_deg_kernel(int* deg, int* counter, int n) {
    int i = blockIdx.x * blockDim.x + threadIdx.x;
    if (i < n) deg[i] = 1;  // self-loop contributes 1
    if (i == 0) *counter = 0;
}

// 8 edges per thread: 8 independent atomic chains in flight
__global__ void count_kernel(const int* __restrict__ dst, int* deg, int e) {
    int t = blockIdx.x * blockDim.x + threadIdx.x;
    int base = t * 8;
    if (base + 7 < e) {
        int4 d0 = *(const int4*)(dst + base);
        int4 d1 = *(const int4*)(dst + base + 4);
        atomicAdd(&deg[d0.x], 1); atomicAdd(&deg[d0.y], 1);
        atomicAdd(&deg[d0.z], 1); atomicAdd(&deg[d0.w], 1);
        atomicAdd(&deg[d1.x], 1); atomicAdd(&deg[d1.y], 1);
        atomicAdd(&deg[d1.z], 1); atomicAdd(&deg[d1.w], 1);
    } else {
        for (int k = base; k < e; ++k) atomicAdd(&deg[dst[k]], 1);
    }
}

// single-pass scan: per-block exclusive scan + atomic block base.
// row_ptr is NOT monotone across blocks; consumers use deg[] for segment end.
// Also writes the self-loop entry at the head of each segment.
__global__ __launch_bounds__(256) void scan_base_kernel(
    const int* __restrict__ deg, int* counter,
    int* __restrict__ row_ptr, int* __restrict__ fill, int* __restrict__ col, int n) {
    int i = blockIdx.x * 256 + threadIdx.x;
    int v = (i < n) ? deg[i] : 0;
    int lane = threadIdx.x & 63, w = threadIdx.x >> 6;
    int incl = v;
#pragma unroll
    for (int off = 1; off < 64; off <<= 1) {
        int u = __shfl_up(incl, off, 64);
        if (lane >= off) incl += u;
    }
    __shared__ int wsum[4];
    __shared__ int base_sh;
    if (lane == 63) wsum[w] = incl;
    __syncthreads();
    if (threadIdx.x == 0)
        base_sh = atomicAdd(counter, wsum[0] + wsum[1] + wsum[2] + wsum[3]);
    int woff = 0;
    for (int k = 0; k < w; ++k) woff += wsum[k];
    __syncthreads();
    int excl = base_sh + woff + incl - v;
    if (i < n) {
        row_ptr[i] = excl;
        col[excl] = i;        // self-loop at segment head
        fill[i] = excl + 1;   // edges fill after it
    }
}

// 8 edges per thread, vectorized src/dst loads
__global__ void fill_kernel(const int* __restrict__ ei, int* fill, int* col, int e) {
    int t = blockIdx.x * blockDim.x + threadIdx.x;
    int base = t * 8;
    if (base + 7 < e) {
        int4 s0 = *(const int4*)(ei + base);
        int4 s1 = *(const int4*)(ei + base + 4);
        int4 d0 = *(const int4*)(ei + e + base);
        int4 d1 = *(const int4*)(ei + e + base + 4);
        int p0 = atomicAdd(&fill[d0.x], 1);
        int p1 = atomicAdd(&fill[d0.y], 1);
        int p2 = atomicAdd(&fill[d0.z], 1);
        int p3 = atomicAdd(&fill[d0.w], 1);
        int p4 = atomicAdd(&fill[d1.x], 1);
        int p5 = atomicAdd(&fill[d1.y], 1);
        int p6 = atomicAdd(&fill[d1.z], 1);
        int p7 = atomicAdd(&fill[d1.w], 1);
        col[p0] = s0.x; col[p1] = s0.y; col[p2] = s0.z; col[p3] = s0.w;
        col[p4] = s1.x; col[p5] = s1.y; col[p6] = s1.z; col[p7] = s1.w;
    } else {
        for (int k = base; k < e; ++k) {
            int pos = atomicAdd(&fill[ei[e + k]], 1);
            col[pos] = ei[k];
        }
    }
}

// ---------------------------------------------------------------------------
// Fused bf16 MFMA GEMM: A staged ONCE per block (BM=64), then loop over all
// column tiles in-kernel:
//   tiles [0, NLIN)        : out0 = A @ B0 (bf16, stride ldc0, TR->head-ilv)
//   tiles [NLIN, NLIN+NSK) : out1 = A @ B1 + bias1 (fp32)
// A-traffic is read exactly once (vs once per column tile with a 2-D grid).
// ---------------------------------------------------------------------------
template <typename AT, int NLIN, int NSK, int TR>
__global__ __launch_bounds__(256) void gemm_fused_kernel(
    const AT* __restrict__ A,
    const float* __restrict__ B0, __bf16* __restrict__ out0, int N0, int ldc0,
    const float* __restrict__ B1, const float* __restrict__ bias1,
    float* __restrict__ out1, int N1, int M) {
    __shared__ __bf16 As[64][136];    // [m][k], +8 pad (16B-aligned rows)
    __shared__ __bf16 Bs[64][136];    // [n][k] (transposed)
    int tid = threadIdx.x;
    int m0 = blockIdx.x * 64;

    // stage A: 64 rows x 128 elems, 16B LDS writes (read once!)
#pragma unroll
    for (int rep = 0; rep < 4; ++rep) {
        int idx = tid + rep * 256;          // 0..1023
        int row = idx >> 4, seg = idx & 15; // 8-elem segment within row
        int gm = m0 + row;
        bf16x8 v = {};
        if (gm < M) {
            if constexpr (std::is_same<AT, float>::value) {
                const float* p = A + gm * KD + seg * 8;
                float4 f0 = *(const float4*)p;
                float4 f1 = *(const float4*)(p + 4);
                v[0] = (__bf16)f0.x; v[1] = (__bf16)f0.y; v[2] = (__bf16)f0.z; v[3] = (__bf16)f0.w;
                v[4] = (__bf16)f1.x; v[5] = (__bf16)f1.y; v[6] = (__bf16)f1.z; v[7] = (__bf16)f1.w;
            } else {
                v = *(const bf16x8*)(A + gm * KD + seg * 8);
            }
        }
        *(bf16x8*)&As[row][seg * 8] = v;
    }
    __syncthreads();

    int w = tid >> 6, lane = tid & 63;
    int lr = lane & 15, quad = lane >> 4;

#pragma unroll
    for (int t = 0; t < NLIN + NSK; ++t) {
        bool second = t >= NLIN;
        const float* B = second ? B1 : B0;
        int N = second ? N1 : N0;
        int n0 = (second ? (t - NLIN) : t) * 64;
        if (t) __syncthreads();   // all waves done reading previous Bs
        // stage B transposed via coalesced row reads + 16B LDS writes
#pragma unroll
        for (int rep = 0; rep < 4; ++rep) {
            int idx = tid + rep * 256;          // 0..1023
            int n = idx & 63, seg = idx >> 6;   // seg 0..15 (8 k's each)
            bf16x8 v = {};
            if (n0 + n < N) {
#pragma unroll
                for (int i = 0; i < 8; ++i) v[i] = (__bf16)B[(seg * 8 + i) * N + n0 + n];
            }
            *(bf16x8*)&Bs[n][seg * 8] = v;
        }
        __syncthreads();

        f32x4 acc[4] = {};
#pragma unroll
        for (int kc = 0; kc < 128; kc += 32) {
            bf16x8 a0 = *(const bf16x8*)&As[w * 16 + lr][kc + quad * 8];
            bf16x8 b0 = *(const bf16x8*)&Bs[lr][kc + quad * 8];
            bf16x8 b1 = *(const bf16x8*)&Bs[16 + lr][kc + quad * 8];
            bf16x8 b2 = *(const bf16x8*)&Bs[32 + lr][kc + quad * 8];
            bf16x8 b3 = *(const bf16x8*)&Bs[48 + lr][kc + quad * 8];
            acc[0] = __builtin_amdgcn_mfma_f32_16x16x32_bf16(a0, b0, acc[0], 0, 0, 0);
            acc[1] = __builtin_amdgcn_mfma_f32_16x16x32_bf16(a0, b1, acc[1], 0, 0, 0);
            acc[2] = __builtin_amdgcn_mfma_f32_16x16x32_bf16(a0, b2, acc[2], 0, 0, 0);
            acc[3] = __builtin_amdgcn_mfma_f32_16x16x32_bf16(a0, b3, acc[3], 0, 0, 0);
        }
        // epilogue: C/D layout col=lane&15, row=quad*4+reg
#pragma unroll
        for (int c = 0; c < 4; ++c) {
#pragma unroll
            for (int reg = 0; reg < 4; ++reg) {
                int row = m0 + w * 16 + quad * 4 + reg;
                int colg = n0 + c * 16 + lr;
                if (row < M && colg < N) {
                    float v = acc[c][reg];
                    if (second) {
                        if (bias1) v += bias1[colg];
                        out1[row * N + colg] = v;
                    } else {
                        int idx;
                        if (TR) {  // head-interleave: feat = oc*4 + h
                            int h = (colg * 1395) >> 16;   // colg / 47 for colg<188
                            idx = row * ldc0 + (colg - 47 * h) * 4 + h;
                        } else {
                            idx = row * ldc0 + colg;
                        }
                        out0[idx] = (__bf16)v;
                    }
                }
            }
        }
    }
}

// ---------------------------------------------------------------------------
// att for layers 0/1: a_src[n,h] = sum_c xh[n,h*32+c]*att_s[h*32+c]. One wave/node.
// ---------------------------------------------------------------------------
__global__ __launch_bounds__(256) void att_kernel(
    const __bf16* __restrict__ xh, const float* __restrict__ att_s,
    const float* __restrict__ att_d, float* __restrict__ a_src,
    float* __restrict__ a_dst, int n) {
    int node = (blockIdx.x * blockDim.x + threadIdx.x) >> 6;
    int lane = threadIdx.x & 63;
    if (node >= n) return;
    float hs[4] = {0.f, 0.f, 0.f, 0.f};
    float hd[4] = {0.f, 0.f, 0.f, 0.f};
#pragma unroll
    for (int r = 0; r < 2; ++r) {
        int f = lane + 64 * r;
        float x = (float)xh[node * HC + f];
        float ps = x * att_s[f];
        float pd = x * att_d[f];
        int h = f >> 5;
        if (h == 0)      { hs[0] += ps; hd[0] += pd; }
        else if (h == 1) { hs[1] += ps; hd[1] += pd; }
        else if (h == 2) { hs[2] += ps; hd[2] += pd; }
        else             { hs[3] += ps; hd[3] += pd; }
    }
#pragma unroll
    for (int off = 32; off >= 1; off >>= 1) {
#pragma unroll
        for (int h = 0; h < 4; ++h) {
            hs[h] += __shfl_xor(hs[h], off, 64);
            hd[h] += __shfl_xor(hd[h], off, 64);
        }
    }
    if (lane == 0) {
        *(float4*)(a_src + 4 * node) = make_float4(hs[0], hs[1], hs[2], hs[3]);
        *(float4*)(a_dst + 4 * node) = make_float4(hd[0], hd[1], hd[2], hd[3]);
    }
}

// ---------------------------------------------------------------------------
// att for layer 2 (head-interleaved xh, stride 192): feat f -> h=f&3, c=f>>2.
// ---------------------------------------------------------------------------
__global__ __launch_bounds__(256) void att2_kernel(
    const __bf16* __restrict__ xh, const float* __restrict__ att_s,
    const float* __restrict__ att_d, float* __restrict__ a_src,
    float* __restrict__ a_dst, int n) {
    int node = (blockIdx.x * blockDim.x + threadIdx.x) >> 6;
    int lane = threadIdx.x & 63;
    if (node >= n) return;
    int h = lane & 3;
    float hs = 0.f, hd = 0.f;
#pragma unroll
    for (int r = 0; r < 3; ++r) {
        int f = lane + 64 * r;
        if (f < NF2) {
            float x = (float)xh[node * NF2P + f];
            int c = f >> 2;
            hs += x * att_s[h * 47 + c];
            hd += x * att_d[h * 47 + c];
        }
    }
#pragma unroll
    for (int off = 4; off <= 32; off <<= 1) {
        hs += __shfl_xor(hs, off, 64);
        hd += __shfl_xor(hd, off, 64);
    }
    if (lane < 4) {
        a_src[node * 4 + lane] = hs;
        a_dst[node * 4 + lane] = hd;
    }
}

// ---------------------------------------------------------------------------
// Aggregation: one wave per destination node. 32-bit indexing.
// MODE 0 (NF=128): 8 edges/iter, half-wave per edge, uint2 (4 feats)/lane.
// MODE 1 (NF2P=192 head-interleaved): 8 edges/iter, lane c<48 loads uint2 =
//                  4 heads of channel c; packed-bf16 alphas; dot2 accumulate.
// ---------------------------------------------------------------------------
template <int MODE>
__global__ __launch_bounds__(256) void agg_kernel(
    const __bf16* __restrict__ xh, const float* __restrict__ a_src,
    const float* __restrict__ a_dst, const float* __restrict__ skip,
    const float* __restrict__ bias, const int* __restrict__ row_ptr,
    const int* __restrict__ deg, const int* __restrict__ col,
    void* __restrict__ outp, int n) {
    __shared__ float s_af[4][64][4];   // MODE 0 alphas (f32)
    __shared__ uint2 s_ab[4][64];      // MODE 1 alphas (packed bf16: a0a1, a2a3)
    __shared__ int s_j[4][64];
    int w = threadIdx.x >> 6;
    int lane = threadIdx.x & 63;
    int node = (blockIdx.x << 2) + w;
    bool active = node < n;
    int node_c = active ? node : 0;
    int start = row_ptr[node_c];
    int end = start + (active ? deg[node_c] : 0);
    float4 ad4 = *(const float4*)(a_dst + 4 * node_c);
    float adh[4] = {ad4.x, ad4.y, ad4.z, ad4.w};

    // ---- pass A (+ chunk-0 capture) ----
    int e0 = start + lane;
    bool ok0 = e0 < end;
    int jcap = ok0 ? col[e0] : 0;
    float evc[4];
    {
        float4 as4 = *(const float4*)(a_src + 4 * jcap);
        float v0 = as4.x + adh[0]; evc[0] = v0 > 0.f ? v0 : 0.2f * v0;
        float v1 = as4.y + adh[1]; evc[1] = v1 > 0.f ? v1 : 0.2f * v1;
        float v2 = as4.z + adh[2]; evc[2] = v2 > 0.f ? v2 : 0.2f * v2;
        float v3 = as4.w + adh[3]; evc[3] = v3 > 0.f ? v3 : 0.2f * v3;
    }
    float m[4], s[4];
#pragma unroll
    for (int h = 0; h < 4; ++h) {
        m[h] = ok0 ? evc[h] : -1e30f;
        s[h] = ok0 ? 1.f : 0.f;
    }
    for (int e = e0 + 64; e < end; e += 64) {
        int j = col[e];
        float4 as4 = *(const float4*)(a_src + 4 * j);
        float ev[4] = {as4.x + adh[0], as4.y + adh[1], as4.z + adh[2], as4.w + adh[3]};
#pragma unroll
        for (int h = 0; h < 4; ++h) {
            float v = ev[h] > 0.f ? ev[h] : 0.2f * ev[h];
            float M = fmaxf(m[h], v);
            s[h] = s[h] * __expf(m[h] - M) + __expf(v - M);
            m[h] = M;
        }
    }
    // max-reduce, rescale once, sum-reduce
    float mloc[4];
#pragma unroll
    for (int h = 0; h < 4; ++h) mloc[h] = m[h];
#pragma unroll
    for (int off = 32; off >= 1; off >>= 1)
#pragma unroll
        for (int h = 0; h < 4; ++h) m[h] = fmaxf(m[h], __shfl_xor(m[h], off, 64));
#pragma unroll
    for (int h = 0; h < 4; ++h) s[h] *= __expf(mloc[h] - m[h]);
#pragma unroll
    for (int off = 32; off >= 1; off >>= 1)
#pragma unroll
        for (int h = 0; h < 4; ++h) s[h] += __shfl_xor(s[h], off, 64);
    float inv[4];
#pragma unroll
    for (int h = 0; h < 4; ++h) inv[h] = 1.f / (s[h] + 1e-16f);

    // ---- pass B bookkeeping ----
    int half = lane >> 5, fl = lane & 31, myh2 = fl >> 3;
    bool lv = lane < 48;  // MODE 1 active lanes
    float acc0 = 0.f, acc1 = 0.f, acc2 = 0.f, acc3 = 0.f;
    const uint2* xb2 = (const uint2*)xh;
    uint2 zz = make_uint2(0u, 0u);

    auto run_chunk = [&](int cnt) {
        int t = 0;
        if (MODE == 0) {
            for (; t + 7 < cnt; t += 8) {
                int ja = s_j[w][t + half], jb = s_j[w][t + 2 + half];
                int jc = s_j[w][t + 4 + half], jd = s_j[w][t + 6 + half];
                uint2 qa = xb2[(ja << 5) + fl];
                uint2 qb = xb2[(jb << 5) + fl];
                uint2 qc = xb2[(jc << 5) + fl];
                uint2 qd = xb2[(jd << 5) + fl];
                float aa = s_af[w][t + half][myh2];
                float ab = s_af[w][t + 2 + half][myh2];
                float ac = s_af[w][t + 4 + half][myh2];
                float ad = s_af[w][t + 6 + half][myh2];
                acc0 += aa * bflo_to_f(qa.x); acc1 += aa * bfhi_to_f(qa.x);
                acc2 += aa * bflo_to_f(qa.y); acc3 += aa * bfhi_to_f(qa.y);
                acc0 += ab * bflo_to_f(qb.x); acc1 += ab * bfhi_to_f(qb.x);
                acc2 += ab * bflo_to_f(qb.y); acc3 += ab * bfhi_to_f(qb.y);
                acc0 += ac * bflo_to_f(qc.x); acc1 += ac * bfhi_to_f(qc.x);
                acc2 += ac * bflo_to_f(qc.y); acc3 += ac * bfhi_to_f(qc.y);
                acc0 += ad * bflo_to_f(qd.x); acc1 += ad * bfhi_to_f(qd.x);
                acc2 += ad * bflo_to_f(qd.y); acc3 += ad * bfhi_to_f(qd.y);
            }
            for (; t + 3 < cnt; t += 4) {
                int ja = s_j[w][t + half], jb = s_j[w][t + 2 + half];
                uint2 qa = xb2[(ja << 5) + fl];
                uint2 qb = xb2[(jb << 5) + fl];
                float aa = s_af[w][t + half][myh2];
                float ab = s_af[w][t + 2 + half][myh2];
                acc0 += aa * bflo_to_f(qa.x); acc1 += aa * bfhi_to_f(qa.x);
                acc2 += aa * bflo_to_f(qa.y); acc3 += aa * bfhi_to_f(qa.y);
                acc0 += ab * bflo_to_f(qb.x); acc1 += ab * bfhi_to_f(qb.x);
                acc2 += ab * bflo_to_f(qb.y); acc3 += ab * bfhi_to_f(qb.y);
            }
            for (; t + 1 < cnt; t += 2) {
                int j = s_j[w][t + half];
                uint2 q = xb2[(j << 5) + fl];
                float a = s_af[w][t + half][myh2];
                acc0 += a * bflo_to_f(q.x); acc1 += a * bfhi_to_f(q.x);
                acc2 += a * bflo_to_f(q.y); acc3 += a * bfhi_to_f(q.y);
            }
            for (; t < cnt; ++t) {  // tail: only half 0 contributes
                int j = s_j[w][t];
                uint2 q = xb2[(j << 5) + fl];
                float a = (half == 0) ? s_af[w][t][myh2] : 0.f;
                acc0 += a * bflo_to_f(q.x); acc1 += a * bfhi_to_f(q.x);
                acc2 += a * bflo_to_f(q.y); acc3 += a * bfhi_to_f(q.y);
            }
        } else {
            for (; t + 7 < cnt; t += 8) {
                uint2 q0 = lv ? xb2[s_j[w][t] * 48 + lane] : zz;
                uint2 q1 = lv ? xb2[s_j[w][t + 1] * 48 + lane] : zz;
                uint2 q2 = lv ? xb2[s_j[w][t + 2] * 48 + lane] : zz;
                uint2 q3 = lv ? xb2[s_j[w][t + 3] * 48 + lane] : zz;
                uint2 q4 = lv ? xb2[s_j[w][t + 4] * 48 + lane] : zz;
                uint2 q5 = lv ? xb2[s_j[w][t + 5] * 48 + lane] : zz;
                uint2 q6 = lv ? xb2[s_j[w][t + 6] * 48 + lane] : zz;
                uint2 q7 = lv ? xb2[s_j[w][t + 7] * 48 + lane] : zz;
                acc0 = dot2pair(q0, s_ab[w][t], acc0);
                acc0 = dot2pair(q1, s_ab[w][t + 1], acc0);
                acc0 = dot2pair(q2, s_ab[w][t + 2], acc0);
                acc0 = dot2pair(q3, s_ab[w][t + 3], acc0);
                acc0 = dot2pair(q4, s_ab[w][t + 4], acc0);
                acc0 = dot2pair(q5, s_ab[w][t + 5], acc0);
                acc0 = dot2pair(q6, s_ab[w][t + 6], acc0);
                acc0 = dot2pair(q7, s_ab[w][t + 7], acc0);
            }
            for (; t + 3 < cnt; t += 4) {
                uint2 q0 = lv ? xb2[s_j[w][t] * 48 + lane] : zz;
                uint2 q1 = lv ? xb2[s_j[w][t + 1] * 48 + lane] : zz;
                uint2 q2 = lv ? xb2[s_j[w][t + 2] * 48 + lane] : zz;
                uint2 q3 = lv ? xb2[s_j[w][t + 3] * 48 + lane] : zz;
                acc0 = dot2pair(q0, s_ab[w][t], acc0);
                acc0 = dot2pair(q1, s_ab[w][t + 1], acc0);
                acc0 = dot2pair(q2, s_ab[w][t + 2], acc0);
                acc0 = dot2pair(q3, s_ab[w][t + 3], acc0);
            }
            for (; t < cnt; ++t) {
                uint2 q = lv ? xb2[s_j[w][t] * 48 + lane] : zz;
                acc0 = dot2pair(q, s_ab[w][t], acc0);
            }
        }
    };

    // chunk 0: reuse captured logits, no col/a_src reload
    {
        float al[4];
#pragma unroll
        for (int h = 0; h < 4; ++h)
            al[h] = ok0 ? __expf(evc[h] - m[h]) * inv[h] : 0.f;
        s_j[w][lane] = jcap;
        if constexpr (MODE == 0)
            *(float4*)&s_af[w][lane][0] = make_float4(al[0], al[1], al[2], al[3]);
        else
            s_ab[w][lane] = make_uint2(pk_bf(al[0], al[1]), pk_bf(al[2], al[3]));
        int cnt = end - start; if (cnt > 64) cnt = 64;
        run_chunk(cnt);
    }
    // remaining chunks (deg > 64: rare)
    for (int base = start + 64; base < end; base += 64) {
        int e = base + lane;
        bool ok = e < end;
        int jv = ok ? col[e] : 0;
        float4 as4 = *(const float4*)(a_src + 4 * jv);
        float asv[4] = {as4.x, as4.y, as4.z, as4.w};
        float al[4];
#pragma unroll
        for (int h = 0; h < 4; ++h) {
            float ev = asv[h] + adh[h];
            ev = ev > 0.f ? ev : 0.2f * ev;
            al[h] = ok ? __expf(ev - m[h]) * inv[h] : 0.f;
        }
        s_j[w][lane] = jv;
        if constexpr (MODE == 0)
            *(float4*)&s_af[w][lane][0] = make_float4(al[0], al[1], al[2], al[3]);
        else
            s_ab[w][lane] = make_uint2(pk_bf(al[0], al[1]), pk_bf(al[2], al[3]));
        int cnt = end - base; if (cnt > 64) cnt = 64;
        run_chunk(cnt);
    }

    if constexpr (MODE == 0) {
        // combine half-waves (lane L and L+32 own the same 4 feats)
        acc0 += __shfl_xor(acc0, 32, 64);
        acc1 += __shfl_xor(acc1, 32, 64);
        acc2 += __shfl_xor(acc2, 32, 64);
        acc3 += __shfl_xor(acc3, 32, 64);
        if (active && half == 0) {
            float4 bb = *(const float4*)(bias + 4 * fl);
            float4 sk = *(const float4*)(skip + (node << 7) + 4 * fl);
            float v0 = acc0 + bb.x + sk.x;
            float v1 = acc1 + bb.y + sk.y;
            float v2 = acc2 + bb.z + sk.z;
            float v3 = acc3 + bb.w + sk.w;
            v0 = v0 > 0.f ? v0 : (__expf(v0) - 1.f);   // ELU
            v1 = v1 > 0.f ? v1 : (__expf(v1) - 1.f);
            v2 = v2 > 0.f ? v2 : (__expf(v2) - 1.f);
            v3 = v3 > 0.f ? v3 : (__expf(v3) - 1.f);
            uint2 o = make_uint2(pk_bf(v0, v1), pk_bf(v2, v3));
            ((uint2*)outp)[(node << 5) + fl] = o;
        }
    } else {
        if (active && lane < OUTC) {
            float v = acc0 * 0.25f + bias[lane] + skip[node * OUTC + lane];
            ((float*)outp)[node * OUTC + lane] = v;
        }
    }
}

// ---------------------------------------------------------------------------
extern "C" void kernel_launch(void* const* d_in, const int* in_sizes, int n_in,
                              void* d_out, int out_size, void* d_ws, size_t ws_size,
                              hipStream_t stream) {
    const float* x        = (const float*)d_in[0];
    const int*   ei       = (const int*)d_in[1];
    const float* lin_w0   = (const float*)d_in[2];
    const float* att_src0 = (const float*)d_in[3];
    const float* att_dst0 = (const float*)d_in[4];
    const float* bias0    = (const float*)d_in[5];
    const float* skip_w0  = (const float*)d_in[6];
    const float* skip_b0  = (const float*)d_in[7];
    const float* lin_w1   = (const float*)d_in[8];
    const float* att_src1 = (const float*)d_in[9];
    const float* att_dst1 = (const float*)d_in[10];
    const float* bias1    = (const float*)d_in[11];
    const float* skip_w1  = (const float*)d_in[12];
    const float* skip_b1  = (const float*)d_in[13];
    const float* lin_w2   = (const float*)d_in[14];
    const float* att_src2 = (const float*)d_in[15];
    const float* att_dst2 = (const float*)d_in[16];
    const float* bias2    = (const float*)d_in[17];
    const float* skip_w2  = (const float*)d_in[18];
    const float* skip_b2  = (const float*)d_in[19];
    float* out = (float*)d_out;

    const int N = in_sizes[0] / KD;       // 50000
    const int E = in_sizes[1] / 2;        // 800000
    const int ET_ = E + N;                // with self loops

    char* ws = (char*)d_ws;
    size_t off = 0;
    auto alloc = [&](size_t bytes) -> void* {
        void* p = ws + off;
        off = (off + bytes + 255) & ~(size_t)255;
        return p;
    };
    __bf16* xh     = (__bf16*)alloc((size_t)N * NF2P * 2 + 256); // GAT linear output
    __bf16* buf_bf = (__bf16*)alloc((size_t)N * HC * 2);    // ELU layer output (bf16)
    float* skip    = (float*)alloc((size_t)N * HC * 4);     // skip linear output (fp32)
    float* a_src   = (float*)alloc((size_t)N * 4 * 4);
    float* a_dst   = (float*)alloc((size_t)N * 4 * 4);
    int* deg       = (int*)alloc((size_t)N * 4);
    int* row_ptr   = (int*)alloc((size_t)N * 4);
    int* fill      = (int*)alloc((size_t)N * 4);
    int* col       = (int*)alloc((size_t)ET_ * 4);
    int* counter   = (int*)alloc(256);

    // ---- CSR build (dst-sorted adjacency, self-loops included) ----
    init_deg_kernel<<<(N + 255) / 256, 256, 0, stream>>>(deg, counter, N);
    count_kernel<<<(E / 8 + 255) / 256, 256, 0, stream>>>(ei + E, deg, E);
    scan_base_kernel<<<(N + 255) / 256, 256, 0, stream>>>(deg, counter, row_ptr, fill, col, N);
    fill_kernel<<<(E / 8 + 255) / 256, 256, 0, stream>>>(ei, fill, col, E);

    dim3 blk(256);
    int mblocks = (N + 63) / 64;   // BM=64
    int wave_blocks = (N + 3) / 4; // one wave per node, 4 waves/block

    // ---- layer 0 (A = fp32 x, converted in staging) ----
    gemm_fused_kernel<float, 2, 2, 0><<<mblocks, blk, 0, stream>>>(
        x, lin_w0, xh, HC, HC, skip_w0, skip_b0, skip, HC, N);
    att_kernel<<<wave_blocks, blk, 0, stream>>>(xh, att_src0, att_dst0, a_src, a_dst, N);
    agg_kernel<0><<<wave_blocks, blk, 0, stream>>>(xh, a_src, a_dst, skip, bias0,
                                                   row_ptr, deg, col, buf_bf, N);
    // ---- layer 1 ----
    gemm_fused_kernel<__bf16, 2, 2, 0><<<mblocks, blk, 0, stream>>>(
        buf_bf, lin_w1, xh, HC, HC, skip_w1, skip_b1, skip, HC, N);
    att_kernel<<<wave_blocks, blk, 0, stream>>>(xh, att_src1, att_dst1, a_src, a_dst, N);
    agg_kernel<0><<<wave_blocks, blk, 0, stream>>>(xh, a_src, a_dst, skip, bias1,
                                                   row_ptr, deg, col, buf_bf, N);
    // ---- layer 2 (xh stored head-interleaved, stride 192) ----
    gemm_fused_kernel<__bf16, 3, 1, 1><<<mblocks, blk, 0, stream>>>(
        buf_bf, lin_w2, xh, NF2, NF2P, skip_w2, skip_b2, skip, OUTC, N);
    att2_kernel<<<wave_blocks, blk, 0, stream>>>(xh, att_src2, att_dst2, a_src, a_dst, N);
    agg_kernel<1><<<wave_blocks, blk, 0, stream>>>(xh, a_src, a_dst, skip, bias2,
                                                   row_ptr, deg, col, out, N);
}

// Round 9
// 410.642 us; speedup vs baseline: 2.2064x; 1.1069x over previous
//
#include <hip/hip_runtime.h>
#include <math.h>
#include <type_traits>

// Problem constants (fixed by reference)
#define KD 128      // K dim of every GEMM (IN = HC = 128)
#define HC 128      // H*C for layers 0/1
#define NF2 188     // H*OUT for layer 2
#define NF2P 192    // padded layer-2 feature stride (6 cachelines)
#define OUTC 47

typedef __attribute__((ext_vector_type(8))) __bf16 bf16x8;
typedef __attribute__((ext_vector_type(2))) __bf16 bf16x2;
typedef __attribute__((ext_vector_type(4))) float f32x4;

#ifdef __has_builtin
#if __has_builtin(__builtin_amdgcn_fdot2_f32_bf16)
#define HAVE_FDOT2 1
#endif
#endif

__device__ inline float bfhi_to_f(unsigned int u) {
    union { unsigned int u; float f; } c; c.u = u & 0xFFFF0000u; return c.f;
}
__device__ inline float bflo_to_f(unsigned int u) {
    union { unsigned int u; float f; } c; c.u = u << 16; return c.f;
}
__device__ inline unsigned short f_to_bfu(float f) {
    return __builtin_bit_cast(unsigned short, (__bf16)f);
}
__device__ inline unsigned int pk_bf(float a, float b) {
    return (unsigned int)f_to_bfu(a) | ((unsigned int)f_to_bfu(b) << 16);
}
// acc += dot(q, ab) over 4 packed bf16 pairs
__device__ inline float dot2pair(uint2 q, uint2 ab, float acc) {
#ifdef HAVE_FDOT2
    acc = __builtin_amdgcn_fdot2_f32_bf16(__builtin_bit_cast(bf16x2, q.x),
                                          __builtin_bit_cast(bf16x2, ab.x), acc, false);
    acc = __builtin_amdgcn_fdot2_f32_bf16(__builtin_bit_cast(bf16x2, q.y),
                                          __builtin_bit_cast(bf16x2, ab.y), acc, false);
#else
    acc += bflo_to_f(q.x) * bflo_to_f(ab.x) + bfhi_to_f(q.x) * bfhi_to_f(ab.x);
    acc += bflo_to_f(q.y) * bflo_to_f(ab.y) + bfhi_to_f(q.y) * bfhi_to_f(ab.y);
#endif
    return acc;
}

// ---------------------------------------------------------------------------
// CSR build: memset(deg,counter) -> count -> scan(+selfloop,+writeback) -> fill
// ---------------------------------------------------------------------------
// 8 edges per thread: 8 independent atomic chains in flight
__global__ void count_kernel(const int* __restrict__ dst, int* deg, int e) {
    int t = blockIdx.x * blockDim.x + threadIdx.x;
    int base = t * 8;
    if (base + 7 < e) {
        int4 d0 = *(const int4*)(dst + base);
        int4 d1 = *(const int4*)(dst + base + 4);
        atomicAdd(&deg[d0.x], 1); atomicAdd(&deg[d0.y], 1);
        atomicAdd(&deg[d0.z], 1); atomicAdd(&deg[d0.w], 1);
        atomicAdd(&deg[d1.x], 1); atomicAdd(&deg[d1.y], 1);
        atomicAdd(&deg[d1.z], 1); atomicAdd(&deg[d1.w], 1);
    } else {
        for (int k = base; k < e; ++k) atomicAdd(&deg[dst[k]], 1);
    }
}

// single-pass scan: per-block exclusive scan + atomic block base.
// deg comes in WITHOUT self-loop (from count); we add +1 here, write the
// self-loop entry at the segment head, and write back deg (incl. self-loop).
// row_ptr is NOT monotone across blocks; consumers use deg[] for segment end.
__global__ __launch_bounds__(256) void scan_base_kernel(
    int* __restrict__ deg, int* counter,
    int* __restrict__ row_ptr, int* __restrict__ fill, int* __restrict__ col, int n) {
    int i = blockIdx.x * 256 + threadIdx.x;
    int v = (i < n) ? (deg[i] + 1) : 0;
    int lane = threadIdx.x & 63, w = threadIdx.x >> 6;
    int incl = v;
#pragma unroll
    for (int off = 1; off < 64; off <<= 1) {
        int u = __shfl_up(incl, off, 64);
        if (lane >= off) incl += u;
    }
    __shared__ int wsum[4];
    __shared__ int base_sh;
    if (lane == 63) wsum[w] = incl;
    __syncthreads();
    if (threadIdx.x == 0)
        base_sh = atomicAdd(counter, wsum[0] + wsum[1] + wsum[2] + wsum[3]);
    int woff = 0;
    for (int k = 0; k < w; ++k) woff += wsum[k];
    __syncthreads();
    int excl = base_sh + woff + incl - v;
    if (i < n) {
        row_ptr[i] = excl;
        col[excl] = i;        // self-loop at segment head
        fill[i] = excl + 1;   // edges fill after it
        deg[i] = v;           // write back incl. self-loop
    }
}

// 8 edges per thread, vectorized src/dst loads
__global__ void fill_kernel(const int* __restrict__ ei, int* fill, int* col, int e) {
    int t = blockIdx.x * blockDim.x + threadIdx.x;
    int base = t * 8;
    if (base + 7 < e) {
        int4 s0 = *(const int4*)(ei + base);
        int4 s1 = *(const int4*)(ei + base + 4);
        int4 d0 = *(const int4*)(ei + e + base);
        int4 d1 = *(const int4*)(ei + e + base + 4);
        int p0 = atomicAdd(&fill[d0.x], 1);
        int p1 = atomicAdd(&fill[d0.y], 1);
        int p2 = atomicAdd(&fill[d0.z], 1);
        int p3 = atomicAdd(&fill[d0.w], 1);
        int p4 = atomicAdd(&fill[d1.x], 1);
        int p5 = atomicAdd(&fill[d1.y], 1);
        int p6 = atomicAdd(&fill[d1.z], 1);
        int p7 = atomicAdd(&fill[d1.w], 1);
        col[p0] = s0.x; col[p1] = s0.y; col[p2] = s0.z; col[p3] = s0.w;
        col[p4] = s1.x; col[p5] = s1.y; col[p6] = s1.z; col[p7] = s1.w;
    } else {
        for (int k = base; k < e; ++k) {
            int pos = atomicAdd(&fill[ei[e + k]], 1);
            col[pos] = ei[k];
        }
    }
}

// ---------------------------------------------------------------------------
// Fused bf16 MFMA GEMM: A staged ONCE per block (BM=64), then loop over all
// column tiles in-kernel:
//   tiles [0, NLIN)        : out0 = A @ B0 (bf16, stride ldc0, TR->head-ilv)
//   tiles [NLIN, NLIN+NSK) : out1 = A @ B1 + bias1 (SKT store)
// ---------------------------------------------------------------------------
template <typename AT, typename SKT, int NLIN, int NSK, int TR>
__global__ __launch_bounds__(256) void gemm_fused_kernel(
    const AT* __restrict__ A,
    const float* __restrict__ B0, __bf16* __restrict__ out0, int N0, int ldc0,
    const float* __restrict__ B1, const float* __restrict__ bias1,
    SKT* __restrict__ out1, int N1, int M) {
    __shared__ __bf16 As[64][136];    // [m][k], +8 pad (16B-aligned rows)
    __shared__ __bf16 Bs[64][136];    // [n][k] (transposed)
    int tid = threadIdx.x;
    int m0 = blockIdx.x * 64;

    // stage A: 64 rows x 128 elems, 16B LDS writes (read once!)
#pragma unroll
    for (int rep = 0; rep < 4; ++rep) {
        int idx = tid + rep * 256;          // 0..1023
        int row = idx >> 4, seg = idx & 15; // 8-elem segment within row
        int gm = m0 + row;
        bf16x8 v = {};
        if (gm < M) {
            if constexpr (std::is_same<AT, float>::value) {
                const float* p = A + gm * KD + seg * 8;
                float4 f0 = *(const float4*)p;
                float4 f1 = *(const float4*)(p + 4);
                v[0] = (__bf16)f0.x; v[1] = (__bf16)f0.y; v[2] = (__bf16)f0.z; v[3] = (__bf16)f0.w;
                v[4] = (__bf16)f1.x; v[5] = (__bf16)f1.y; v[6] = (__bf16)f1.z; v[7] = (__bf16)f1.w;
            } else {
                v = *(const bf16x8*)(A + gm * KD + seg * 8);
            }
        }
        *(bf16x8*)&As[row][seg * 8] = v;
    }
    __syncthreads();

    int w = tid >> 6, lane = tid & 63;
    int lr = lane & 15, quad = lane >> 4;

#pragma unroll
    for (int t = 0; t < NLIN + NSK; ++t) {
        bool second = t >= NLIN;
        const float* B = second ? B1 : B0;
        int N = second ? N1 : N0;
        int n0 = (second ? (t - NLIN) : t) * 64;
        if (t) __syncthreads();   // all waves done reading previous Bs
        // stage B transposed via coalesced row reads + 16B LDS writes
#pragma unroll
        for (int rep = 0; rep < 4; ++rep) {
            int idx = tid + rep * 256;          // 0..1023
            int n = idx & 63, seg = idx >> 6;   // seg 0..15 (8 k's each)
            bf16x8 v = {};
            if (n0 + n < N) {
#pragma unroll
                for (int i = 0; i < 8; ++i) v[i] = (__bf16)B[(seg * 8 + i) * N + n0 + n];
            }
            *(bf16x8*)&Bs[n][seg * 8] = v;
        }
        __syncthreads();

        f32x4 acc[4] = {};
#pragma unroll
        for (int kc = 0; kc < 128; kc += 32) {
            bf16x8 a0 = *(const bf16x8*)&As[w * 16 + lr][kc + quad * 8];
            bf16x8 b0 = *(const bf16x8*)&Bs[lr][kc + quad * 8];
            bf16x8 b1 = *(const bf16x8*)&Bs[16 + lr][kc + quad * 8];
            bf16x8 b2 = *(const bf16x8*)&Bs[32 + lr][kc + quad * 8];
            bf16x8 b3 = *(const bf16x8*)&Bs[48 + lr][kc + quad * 8];
            acc[0] = __builtin_amdgcn_mfma_f32_16x16x32_bf16(a0, b0, acc[0], 0, 0, 0);
            acc[1] = __builtin_amdgcn_mfma_f32_16x16x32_bf16(a0, b1, acc[1], 0, 0, 0);
            acc[2] = __builtin_amdgcn_mfma_f32_16x16x32_bf16(a0, b2, acc[2], 0, 0, 0);
            acc[3] = __builtin_amdgcn_mfma_f32_16x16x32_bf16(a0, b3, acc[3], 0, 0, 0);
        }
        // epilogue: C/D layout col=lane&15, row=quad*4+reg
#pragma unroll
        for (int c = 0; c < 4; ++c) {
#pragma unroll
            for (int reg = 0; reg < 4; ++reg) {
                int row = m0 + w * 16 + quad * 4 + reg;
                int colg = n0 + c * 16 + lr;
                if (row < M && colg < N) {
                    float v = acc[c][reg];
                    if (second) {
                        if (bias1) v += bias1[colg];
                        out1[row * N + colg] = (SKT)v;
                    } else {
                        int idx;
                        if (TR) {  // head-interleave: feat = oc*4 + h
                            int h = (colg * 1395) >> 16;   // colg / 47 for colg<188
                            idx = row * ldc0 + (colg - 47 * h) * 4 + h;
                        } else {
                            idx = row * ldc0 + colg;
                        }
                        out0[idx] = (__bf16)v;
                    }
                }
            }
        }
    }
}

// ---------------------------------------------------------------------------
// att for layers 0/1: 16 lanes per node (4 nodes/wave). Lane owns 8 feats =
// one head-quarter (head = l16>>2) -> single accumulator; 2-round reduce.
// ---------------------------------------------------------------------------
__global__ __launch_bounds__(256) void att_kernel(
    const __bf16* __restrict__ xh, const float* __restrict__ att_s,
    const float* __restrict__ att_d, float* __restrict__ a_src,
    float* __restrict__ a_dst, int n) {
    int tid = blockIdx.x * 256 + threadIdx.x;
    int node = tid >> 4;
    int l16 = threadIdx.x & 15;
    if (node >= n) return;
    uint4 q = ((const uint4*)xh)[node * 16 + l16];   // 8 bf16 feats
    int f0 = l16 * 8;
    float4 as0 = *(const float4*)(att_s + f0);
    float4 as1 = *(const float4*)(att_s + f0 + 4);
    float4 ad0 = *(const float4*)(att_d + f0);
    float4 ad1 = *(const float4*)(att_d + f0 + 4);
    float x0 = bflo_to_f(q.x), x1 = bfhi_to_f(q.x);
    float x2 = bflo_to_f(q.y), x3 = bfhi_to_f(q.y);
    float x4 = bflo_to_f(q.z), x5 = bfhi_to_f(q.z);
    float x6 = bflo_to_f(q.w), x7 = bfhi_to_f(q.w);
    float hs = x0 * as0.x + x1 * as0.y + x2 * as0.z + x3 * as0.w
             + x4 * as1.x + x5 * as1.y + x6 * as1.z + x7 * as1.w;
    float hd = x0 * ad0.x + x1 * ad0.y + x2 * ad0.z + x3 * ad0.w
             + x4 * ad1.x + x5 * ad1.y + x6 * ad1.z + x7 * ad1.w;
    hs += __shfl_xor(hs, 1, 64); hs += __shfl_xor(hs, 2, 64);
    hd += __shfl_xor(hd, 1, 64); hd += __shfl_xor(hd, 2, 64);
    if ((l16 & 3) == 0) {
        int h = l16 >> 2;
        a_src[node * 4 + h] = hs;
        a_dst[node * 4 + h] = hd;
    }
}

// ---------------------------------------------------------------------------
// att for layer 2 (head-interleaved xh, stride 192): feat f -> h=f&3, c=f>>2.
// ---------------------------------------------------------------------------
__global__ __launch_bounds__(256) void att2_kernel(
    const __bf16* __restrict__ xh, const float* __restrict__ att_s,
    const float* __restrict__ att_d, float* __restrict__ a_src,
    float* __restrict__ a_dst, int n) {
    int node = (blockIdx.x * blockDim.x + threadIdx.x) >> 6;
    int lane = threadIdx.x & 63;
    if (node >= n) return;
    int h = lane & 3;
    float hs = 0.f, hd = 0.f;
#pragma unroll
    for (int r = 0; r < 3; ++r) {
        int f = lane + 64 * r;
        if (f < NF2) {
            float x = (float)xh[node * NF2P + f];
            int c = f >> 2;
            hs += x * att_s[h * 47 + c];
            hd += x * att_d[h * 47 + c];
        }
    }
#pragma unroll
    for (int off = 4; off <= 32; off <<= 1) {
        hs += __shfl_xor(hs, off, 64);
        hd += __shfl_xor(hd, off, 64);
    }
    if (lane < 4) {
        a_src[node * 4 + lane] = hs;
        a_dst[node * 4 + lane] = hd;
    }
}

// ---------------------------------------------------------------------------
// Aggregation: one wave per destination node. 32-bit indexing.
// MODE 0 (NF=128): 8 edges/iter, half-wave per edge, uint2 (4 feats)/lane.
//                  skip is bf16 (packed uint2).
// MODE 1 (NF2P=192 head-interleaved): 8 edges/iter, lane c<48 loads uint2 =
//                  4 heads of channel c; packed-bf16 alphas; dot2 accumulate.
//                  skip is fp32.
// ---------------------------------------------------------------------------
template <int MODE>
__global__ __launch_bounds__(256) void agg_kernel(
    const __bf16* __restrict__ xh, const float* __restrict__ a_src,
    const float* __restrict__ a_dst, const void* __restrict__ skipp,
    const float* __restrict__ bias, const int* __restrict__ row_ptr,
    const int* __restrict__ deg, const int* __restrict__ col,
    void* __restrict__ outp, int n) {
    __shared__ float s_af[4][64][4];   // MODE 0 alphas (f32)
    __shared__ uint2 s_ab[4][64];      // MODE 1 alphas (packed bf16: a0a1, a2a3)
    __shared__ int s_j[4][64];
    int w = threadIdx.x >> 6;
    int lane = threadIdx.x & 63;
    int node = (blockIdx.x << 2) + w;
    bool active = node < n;
    int node_c = active ? node : 0;
    int start = row_ptr[node_c];
    int end = start + (active ? deg[node_c] : 0);
    float4 ad4 = *(const float4*)(a_dst + 4 * node_c);
    float adh[4] = {ad4.x, ad4.y, ad4.z, ad4.w};

    // ---- pass A (+ chunk-0 capture) ----
    int e0 = start + lane;
    bool ok0 = e0 < end;
    int jcap = ok0 ? col[e0] : 0;
    float evc[4];
    {
        float4 as4 = *(const float4*)(a_src + 4 * jcap);
        float v0 = as4.x + adh[0]; evc[0] = v0 > 0.f ? v0 : 0.2f * v0;
        float v1 = as4.y + adh[1]; evc[1] = v1 > 0.f ? v1 : 0.2f * v1;
        float v2 = as4.z + adh[2]; evc[2] = v2 > 0.f ? v2 : 0.2f * v2;
        float v3 = as4.w + adh[3]; evc[3] = v3 > 0.f ? v3 : 0.2f * v3;
    }
    float m[4], s[4];
#pragma unroll
    for (int h = 0; h < 4; ++h) {
        m[h] = ok0 ? evc[h] : -1e30f;
        s[h] = ok0 ? 1.f : 0.f;
    }
    for (int e = e0 + 64; e < end; e += 64) {
        int j = col[e];
        float4 as4 = *(const float4*)(a_src + 4 * j);
        float ev[4] = {as4.x + adh[0], as4.y + adh[1], as4.z + adh[2], as4.w + adh[3]};
#pragma unroll
        for (int h = 0; h < 4; ++h) {
            float v = ev[h] > 0.f ? ev[h] : 0.2f * ev[h];
            float M = fmaxf(m[h], v);
            s[h] = s[h] * __expf(m[h] - M) + __expf(v - M);
            m[h] = M;
        }
    }
    // max-reduce, rescale once, sum-reduce
    float mloc[4];
#pragma unroll
    for (int h = 0; h < 4; ++h) mloc[h] = m[h];
#pragma unroll
    for (int off = 32; off >= 1; off >>= 1)
#pragma unroll
        for (int h = 0; h < 4; ++h) m[h] = fmaxf(m[h], __shfl_xor(m[h], off, 64));
#pragma unroll
    for (int h = 0; h < 4; ++h) s[h] *= __expf(mloc[h] - m[h]);
#pragma unroll
    for (int off = 32; off >= 1; off >>= 1)
#pragma unroll
        for (int h = 0; h < 4; ++h) s[h] += __shfl_xor(s[h], off, 64);
    float inv[4];
#pragma unroll
    for (int h = 0; h < 4; ++h) inv[h] = 1.f / (s[h] + 1e-16f);

    // ---- pass B bookkeeping ----
    int half = lane >> 5, fl = lane & 31, myh2 = fl >> 3;
    bool lv = lane < 48;  // MODE 1 active lanes
    float acc0 = 0.f, acc1 = 0.f, acc2 = 0.f, acc3 = 0.f;
    const uint2* xb2 = (const uint2*)xh;
    uint2 zz = make_uint2(0u, 0u);

    auto run_chunk = [&](int cnt) {
        int t = 0;
        if (MODE == 0) {
            for (; t + 7 < cnt; t += 8) {
                int ja = s_j[w][t + half], jb = s_j[w][t + 2 + half];
                int jc = s_j[w][t + 4 + half], jd = s_j[w][t + 6 + half];
                uint2 qa = xb2[(ja << 5) + fl];
                uint2 qb = xb2[(jb << 5) + fl];
                uint2 qc = xb2[(jc << 5) + fl];
                uint2 qd = xb2[(jd << 5) + fl];
                float aa = s_af[w][t + half][myh2];
                float ab = s_af[w][t + 2 + half][myh2];
                float ac = s_af[w][t + 4 + half][myh2];
                float ad = s_af[w][t + 6 + half][myh2];
                acc0 += aa * bflo_to_f(qa.x); acc1 += aa * bfhi_to_f(qa.x);
                acc2 += aa * bflo_to_f(qa.y); acc3 += aa * bfhi_to_f(qa.y);
                acc0 += ab * bflo_to_f(qb.x); acc1 += ab * bfhi_to_f(qb.x);
                acc2 += ab * bflo_to_f(qb.y); acc3 += ab * bfhi_to_f(qb.y);
                acc0 += ac * bflo_to_f(qc.x); acc1 += ac * bfhi_to_f(qc.x);
                acc2 += ac * bflo_to_f(qc.y); acc3 += ac * bfhi_to_f(qc.y);
                acc0 += ad * bflo_to_f(qd.x); acc1 += ad * bfhi_to_f(qd.x);
                acc2 += ad * bflo_to_f(qd.y); acc3 += ad * bfhi_to_f(qd.y);
            }
            for (; t + 3 < cnt; t += 4) {
                int ja = s_j[w][t + half], jb = s_j[w][t + 2 + half];
                uint2 qa = xb2[(ja << 5) + fl];
                uint2 qb = xb2[(jb << 5) + fl];
                float aa = s_af[w][t + half][myh2];
                float ab = s_af[w][t + 2 + half][myh2];
                acc0 += aa * bflo_to_f(qa.x); acc1 += aa * bfhi_to_f(qa.x);
                acc2 += aa * bflo_to_f(qa.y); acc3 += aa * bfhi_to_f(qa.y);
                acc0 += ab * bflo_to_f(qb.x); acc1 += ab * bfhi_to_f(qb.x);
                acc2 += ab * bflo_to_f(qb.y); acc3 += ab * bfhi_to_f(qb.y);
            }
            for (; t + 1 < cnt; t += 2) {
                int j = s_j[w][t + half];
                uint2 q = xb2[(j << 5) + fl];
                float a = s_af[w][t + half][myh2];
                acc0 += a * bflo_to_f(q.x); acc1 += a * bfhi_to_f(q.x);
                acc2 += a * bflo_to_f(q.y); acc3 += a * bfhi_to_f(q.y);
            }
            for (; t < cnt; ++t) {  // tail: only half 0 contributes
                int j = s_j[w][t];
                uint2 q = xb2[(j << 5) + fl];
                float a = (half == 0) ? s_af[w][t][myh2] : 0.f;
                acc0 += a * bflo_to_f(q.x); acc1 += a * bfhi_to_f(q.x);
                acc2 += a * bflo_to_f(q.y); acc3 += a * bfhi_to_f(q.y);
            }
        } else {
            for (; t + 7 < cnt; t += 8) {
                uint2 q0 = lv ? xb2[s_j[w][t] * 48 + lane] : zz;
                uint2 q1 = lv ? xb2[s_j[w][t + 1] * 48 + lane] : zz;
                uint2 q2 = lv ? xb2[s_j[w][t + 2] * 48 + lane] : zz;
                uint2 q3 = lv ? xb2[s_j[w][t + 3] * 48 + lane] : zz;
                uint2 q4 = lv ? xb2[s_j[w][t + 4] * 48 + lane] : zz;
                uint2 q5 = lv ? xb2[s_j[w][t + 5] * 48 + lane] : zz;
                uint2 q6 = lv ? xb2[s_j[w][t + 6] * 48 + lane] : zz;
                uint2 q7 = lv ? xb2[s_j[w][t + 7] * 48 + lane] : zz;
                acc0 = dot2pair(q0, s_ab[w][t], acc0);
                acc0 = dot2pair(q1, s_ab[w][t + 1], acc0);
                acc0 = dot2pair(q2, s_ab[w][t + 2], acc0);
                acc0 = dot2pair(q3, s_ab[w][t + 3], acc0);
                acc0 = dot2pair(q4, s_ab[w][t + 4], acc0);
                acc0 = dot2pair(q5, s_ab[w][t + 5], acc0);
                acc0 = dot2pair(q6, s_ab[w][t + 6], acc0);
                acc0 = dot2pair(q7, s_ab[w][t + 7], acc0);
            }
            for (; t + 3 < cnt; t += 4) {
                uint2 q0 = lv ? xb2[s_j[w][t] * 48 + lane] : zz;
                uint2 q1 = lv ? xb2[s_j[w][t + 1] * 48 + lane] : zz;
                uint2 q2 = lv ? xb2[s_j[w][t + 2] * 48 + lane] : zz;
                uint2 q3 = lv ? xb2[s_j[w][t + 3] * 48 + lane] : zz;
                acc0 = dot2pair(q0, s_ab[w][t], acc0);
                acc0 = dot2pair(q1, s_ab[w][t + 1], acc0);
                acc0 = dot2pair(q2, s_ab[w][t + 2], acc0);
                acc0 = dot2pair(q3, s_ab[w][t + 3], acc0);
            }
            for (; t < cnt; ++t) {
                uint2 q = lv ? xb2[s_j[w][t] * 48 + lane] : zz;
                acc0 = dot2pair(q, s_ab[w][t], acc0);
            }
        }
    };

    // chunk 0: reuse captured logits, no col/a_src reload
    {
        float al[4];
#pragma unroll
        for (int h = 0; h < 4; ++h)
            al[h] = ok0 ? __expf(evc[h] - m[h]) * inv[h] : 0.f;
        s_j[w][lane] = jcap;
        if constexpr (MODE == 0)
            *(float4*)&s_af[w][lane][0] = make_float4(al[0], al[1], al[2], al[3]);
        else
            s_ab[w][lane] = make_uint2(pk_bf(al[0], al[1]), pk_bf(al[2], al[3]));
        int cnt = end - start; if (cnt > 64) cnt = 64;
        run_chunk(cnt);
    }
    // remaining chunks (deg > 64: rare)
    for (int base = start + 64; base < end; base += 64) {
        int e = base + lane;
        bool ok = e < end;
        int jv = ok ? col[e] : 0;
        float4 as4 = *(const float4*)(a_src + 4 * jv);
        float asv[4] = {as4.x, as4.y, as4.z, as4.w};
        float al[4];
#pragma unroll
        for (int h = 0; h < 4; ++h) {
            float ev = asv[h] + adh[h];
            ev = ev > 0.f ? ev : 0.2f * ev;
            al[h] = ok ? __expf(ev - m[h]) * inv[h] : 0.f;
        }
        s_j[w][lane] = jv;
        if constexpr (MODE == 0)
            *(float4*)&s_af[w][lane][0] = make_float4(al[0], al[1], al[2], al[3]);
        else
            s_ab[w][lane] = make_uint2(pk_bf(al[0], al[1]), pk_bf(al[2], al[3]));
        int cnt = end - base; if (cnt > 64) cnt = 64;
        run_chunk(cnt);
    }

    if constexpr (MODE == 0) {
        // combine half-waves (lane L and L+32 own the same 4 feats)
        acc0 += __shfl_xor(acc0, 32, 64);
        acc1 += __shfl_xor(acc1, 32, 64);
        acc2 += __shfl_xor(acc2, 32, 64);
        acc3 += __shfl_xor(acc3, 32, 64);
        if (active && half == 0) {
            float4 bb = *(const float4*)(bias + 4 * fl);
            uint2 skq = ((const uint2*)skipp)[(node << 5) + fl];
            float v0 = acc0 + bb.x + bflo_to_f(skq.x);
            float v1 = acc1 + bb.y + bfhi_to_f(skq.x);
            float v2 = acc2 + bb.z + bflo_to_f(skq.y);
            float v3 = acc3 + bb.w + bfhi_to_f(skq.y);
            v0 = v0 > 0.f ? v0 : (__expf(v0) - 1.f);   // ELU
            v1 = v1 > 0.f ? v1 : (__expf(v1) - 1.f);
            v2 = v2 > 0.f ? v2 : (__expf(v2) - 1.f);
            v3 = v3 > 0.f ? v3 : (__expf(v3) - 1.f);
            uint2 o = make_uint2(pk_bf(v0, v1), pk_bf(v2, v3));
            ((uint2*)outp)[(node << 5) + fl] = o;
        }
    } else {
        if (active && lane < OUTC) {
            const float* skip = (const float*)skipp;
            float v = acc0 * 0.25f + bias[lane] + skip[node * OUTC + lane];
            ((float*)outp)[node * OUTC + lane] = v;
        }
    }
}

// ---------------------------------------------------------------------------
extern "C" void kernel_launch(void* const* d_in, const int* in_sizes, int n_in,
                              void* d_out, int out_size, void* d_ws, size_t ws_size,
                              hipStream_t stream) {
    const float* x        = (const float*)d_in[0];
    const int*   ei       = (const int*)d_in[1];
    const float* lin_w0   = (const float*)d_in[2];
    const float* att_src0 = (const float*)d_in[3];
    const float* att_dst0 = (const float*)d_in[4];
    const float* bias0    = (const float*)d_in[5];
    const float* skip_w0  = (const float*)d_in[6];
    const float* skip_b0  = (const float*)d_in[7];
    const float* lin_w1   = (const float*)d_in[8];
    const float* att_src1 = (const float*)d_in[9];
    const float* att_dst1 = (const float*)d_in[10];
    const float* bias1    = (const float*)d_in[11];
    const float* skip_w1  = (const float*)d_in[12];
    const float* skip_b1  = (const float*)d_in[13];
    const float* lin_w2   = (const float*)d_in[14];
    const float* att_src2 = (const float*)d_in[15];
    const float* att_dst2 = (const float*)d_in[16];
    const float* bias2    = (const float*)d_in[17];
    const float* skip_w2  = (const float*)d_in[18];
    const float* skip_b2  = (const float*)d_in[19];
    float* out = (float*)d_out;

    const int N = in_sizes[0] / KD;       // 50000
    const int E = in_sizes[1] / 2;        // 800000
    const int ET_ = E + N;                // with self loops

    char* ws = (char*)d_ws;
    size_t off = 0;
    auto alloc = [&](size_t bytes) -> void* {
        void* p = ws + off;
        off = (off + bytes + 255) & ~(size_t)255;
        return p;
    };
    __bf16* xh      = (__bf16*)alloc((size_t)N * NF2P * 2 + 256); // GAT linear output
    __bf16* buf_bf  = (__bf16*)alloc((size_t)N * HC * 2);   // ELU layer output (bf16)
    void*   skipbuf = alloc((size_t)N * HC * 4);            // skip: bf16 L0/1, fp32 L2
    float* a_src    = (float*)alloc((size_t)N * 4 * 4);
    float* a_dst    = (float*)alloc((size_t)N * 4 * 4);
    int* deg        = (int*)alloc((size_t)N * 4);
    int* row_ptr    = (int*)alloc((size_t)N * 4);
    int* fill       = (int*)alloc((size_t)N * 4);
    int* col        = (int*)alloc((size_t)ET_ * 4);
    int* counter    = (int*)alloc(256);

    // ---- CSR build (dst-sorted adjacency, self-loops included) ----
    hipMemsetAsync(deg, 0, (size_t)N * 4, stream);
    hipMemsetAsync(counter, 0, 4, stream);
    count_kernel<<<(E / 8 + 255) / 256, 256, 0, stream>>>(ei + E, deg, E);
    scan_base_kernel<<<(N + 255) / 256, 256, 0, stream>>>(deg, counter, row_ptr, fill, col, N);
    fill_kernel<<<(E / 8 + 255) / 256, 256, 0, stream>>>(ei, fill, col, E);

    dim3 blk(256);
    int mblocks = (N + 63) / 64;          // BM=64
    int wave_blocks = (N + 3) / 4;        // one wave per node, 4 waves/block
    int att_blocks = (N * 16 + 255) / 256; // 16 threads per node

    // ---- layer 0 (A = fp32 x, converted in staging; skip bf16) ----
    gemm_fused_kernel<float, __bf16, 2, 2, 0><<<mblocks, blk, 0, stream>>>(
        x, lin_w0, xh, HC, HC, skip_w0, skip_b0, (__bf16*)skipbuf, HC, N);
    att_kernel<<<att_blocks, blk, 0, stream>>>(xh, att_src0, att_dst0, a_src, a_dst, N);
    agg_kernel<0><<<wave_blocks, blk, 0, stream>>>(xh, a_src, a_dst, skipbuf, bias0,
                                                   row_ptr, deg, col, buf_bf, N);
    // ---- layer 1 (skip bf16) ----
    gemm_fused_kernel<__bf16, __bf16, 2, 2, 0><<<mblocks, blk, 0, stream>>>(
        buf_bf, lin_w1, xh, HC, HC, skip_w1, skip_b1, (__bf16*)skipbuf, HC, N);
    att_kernel<<<att_blocks, blk, 0, stream>>>(xh, att_src1, att_dst1, a_src, a_dst, N);
    agg_kernel<0><<<wave_blocks, blk, 0, stream>>>(xh, a_src, a_dst, skipbuf, bias1,
                                                   row_ptr, deg, col, buf_bf, N);
    // ---- layer 2 (xh head-interleaved stride 192; skip fp32) ----
    gemm_fused_kernel<__bf16, float, 3, 1, 1><<<mblocks, blk, 0, stream>>>(
        buf_bf, lin_w2, xh, NF2, NF2P, skip_w2, skip_b2, (float*)skipbuf, OUTC, N);
    att2_kernel<<<wave_blocks, blk, 0, stream>>>(xh, att_src2, att_dst2, a_src, a_dst, N);
    agg_kernel<1><<<wave_blocks, blk, 0, stream>>>(xh, a_src, a_dst, skipbuf, bias2,
                                                   row_ptr, deg, col, out, N);
}